// Round 1
// baseline (1462.615 us; speedup 1.0000x reference)
//
#include <hip/hip_runtime.h>
#include <math.h>

#define Bq 8
#define Nn 1024
#define Cc 256
#define Hh 8
#define HDd 32
#define Ll 225
#define LHD (Ll*HDd)
#define SCALE 0.17677669529663687f

// ---------------- K1: QKV projection (tiled SGEMM) ----------------
// x [B*N, 256] @ qkv_w^T [256, 768] -> q,k,v each [B,H,N,32]
__global__ __launch_bounds__(256) void qkv_gemm(const float* __restrict__ x,
                                                const float* __restrict__ w,
                                                float* __restrict__ q,
                                                float* __restrict__ k,
                                                float* __restrict__ v) {
    __shared__ float As[16][65];
    __shared__ float Bs[16][65];
    const int tix = threadIdx.x;
    const int tx = tix & 15, ty = tix >> 4;
    const int row0 = blockIdx.y * 64;
    const int col0 = blockIdx.x * 64;
    float acc[4][4] = {};
    for (int k0 = 0; k0 < Cc; k0 += 16) {
#pragma unroll
        for (int r = 0; r < 4; ++r) {
            int idx = tix + r * 256;       // 0..1023
            int m = idx >> 4, kk = idx & 15;
            As[kk][m] = x[(size_t)(row0 + m) * Cc + k0 + kk];
            Bs[kk][m] = w[(size_t)(col0 + m) * Cc + k0 + kk];
        }
        __syncthreads();
#pragma unroll
        for (int kk = 0; kk < 16; ++kk) {
            float a[4], b[4];
#pragma unroll
            for (int i = 0; i < 4; ++i) a[i] = As[kk][ty * 4 + i];
#pragma unroll
            for (int j = 0; j < 4; ++j) b[j] = Bs[kk][tx * 4 + j];
#pragma unroll
            for (int i = 0; i < 4; ++i)
#pragma unroll
                for (int j = 0; j < 4; ++j) acc[i][j] = fmaf(a[i], b[j], acc[i][j]);
        }
        __syncthreads();
    }
#pragma unroll
    for (int i = 0; i < 4; ++i) {
        int row = row0 + ty * 4 + i;
        int b = row >> 10, n = row & 1023;
#pragma unroll
        for (int j = 0; j < 4; ++j) {
            int oc = col0 + tx * 4 + j;
            int which = oc >> 8;
            int h = (oc >> 5) & 7;
            int d = oc & 31;
            float* dst = (which == 0) ? q : ((which == 1) ? k : v);
            dst[(((size_t)b * Hh + h) * Nn + n) * HDd + d] = acc[i][j];
        }
    }
}

// ---------------- K2: transpose rp_bucket ----------------
__global__ void transpose_bucket(const int* __restrict__ rp, int* __restrict__ bt) {
    __shared__ int t[32][33];
    int it = blockIdx.x * 32, jt = blockIdx.y * 32;
    t[threadIdx.y][threadIdx.x] = rp[(size_t)(jt + threadIdx.y) * Nn + it + threadIdx.x];
    __syncthreads();
    bt[(size_t)(it + threadIdx.y) * Nn + jt + threadIdx.x] = t[threadIdx.x][threadIdx.y];
}

// ---------------- K3: tq[bh_local, j, l] = scale * k[bh,j,:] . rpe_q[h,l,:] ----------------
__global__ __launch_bounds__(256) void tq_kernel(const float* __restrict__ k,
                                                 const float* __restrict__ rpeq,
                                                 float* __restrict__ tq, int bh0) {
    __shared__ float tab[Ll * 33];
    __shared__ float krow[16][33];
    int blk = blockIdx.x;
    int bh_local = blk >> 6;
    int j0 = (blk & 63) << 4;
    int bh = bh0 + bh_local;
    int h = bh & 7;
    int tid = threadIdx.x;
    for (int idx = tid; idx < LHD; idx += 256)
        tab[(idx >> 5) * 33 + (idx & 31)] = rpeq[(size_t)h * LHD + idx];
    for (int idx = tid; idx < 16 * 32; idx += 256) {
        int r = idx >> 5, c = idx & 31;
        krow[r][c] = k[((size_t)bh * Nn + j0 + r) * HDd + c];
    }
    __syncthreads();
    for (int idx = tid; idx < 16 * Ll; idx += 256) {
        int r = idx / Ll, l = idx % Ll;
        float acc = 0.f;
#pragma unroll
        for (int d = 0; d < 32; ++d) acc = fmaf(krow[r][d], tab[l * 33 + d], acc);
        tq[((size_t)bh_local * Nn + j0 + r) * Ll + l] = acc * SCALE;
    }
}

// ---------------- K4: fused attention (one wave per query row) ----------------
__global__ __launch_bounds__(256) void attn_kernel(const float* __restrict__ q,
                                                   const float* __restrict__ k,
                                                   const float* __restrict__ v,
                                                   const float* __restrict__ tq,
                                                   const float* __restrict__ rpek,
                                                   const float* __restrict__ rpev,
                                                   const int* __restrict__ rp,
                                                   const int* __restrict__ bt,
                                                   float* __restrict__ ctx, int bh0) {
    __shared__ float rv[Ll][33];
    __shared__ float tkl[4][226];
    __shared__ float kt[64][33];
    __shared__ float vt[64][33];
    __shared__ float qs[4][32];
    int blk = blockIdx.x;
    int bh_local = blk >> 8;
    int n0 = (blk & 255) << 2;
    int bh = bh0 + bh_local;
    int h = bh & 7;
    int tid = threadIdx.x, lane = tid & 63, w = tid >> 6;

    for (int idx = tid; idx < LHD; idx += 256)
        rv[idx >> 5][idx & 31] = rpev[(size_t)h * LHD + idx];
    if (tid < 128)
        qs[tid >> 5][tid & 31] = q[((size_t)bh * Nn + n0 + (tid >> 5)) * HDd + (tid & 31)];
    __syncthreads();

    const int i = n0 + w;
    // tk row for this wave's query (into LDS)
    for (int l = lane; l < Ll; l += 64) {
        float acc = 0.f;
#pragma unroll
        for (int d = 0; d < 32; ++d) acc = fmaf(qs[w][d], rpek[(size_t)h * LHD + l * 32 + d], acc);
        tkl[w][l] = acc;
    }
    float qr[32];
#pragma unroll
    for (int d = 0; d < 32; ++d) qr[d] = qs[w][d];

    float m = -INFINITY, Z = 0.f;
    float o[32];
#pragma unroll
    for (int d = 0; d < 32; ++d) o[d] = 0.f;
    const size_t rowi = (size_t)i * Nn;

    for (int c = 0; c < 16; ++c) {
        int j0 = c << 6;
        __syncthreads();
        for (int idx = tid; idx < 2048; idx += 256) {
            int r = idx >> 5, col = idx & 31;
            kt[r][col] = k[((size_t)bh * Nn + j0 + r) * HDd + col];
            vt[r][col] = v[((size_t)bh * Nn + j0 + r) * HDd + col];
        }
        __syncthreads();
        int j = j0 + lane;
        float s = 0.f;
#pragma unroll
        for (int d = 0; d < 32; ++d) s = fmaf(qr[d], kt[lane][d], s);
        int bij = rp[rowi + j];
        int bji = bt[rowi + j];
        s += tkl[w][bij];
        s += tq[((size_t)bh_local * Nn + j) * Ll + bji];
        float mn = fmaxf(m, s);
        float rsc = expf(m - mn);
        float p = expf(s - mn);
        Z = Z * rsc + p;
#pragma unroll
        for (int d = 0; d < 32; ++d) o[d] = fmaf(p, vt[lane][d] + rv[bij][d], o[d] * rsc);
        m = mn;
    }
    // cross-lane combine
    float M = m;
#pragma unroll
    for (int off = 32; off; off >>= 1) M = fmaxf(M, __shfl_xor(M, off));
    float f = expf(m - M);
    Z *= f;
#pragma unroll
    for (int d = 0; d < 32; ++d) o[d] *= f;
#pragma unroll
    for (int off = 32; off; off >>= 1) Z += __shfl_xor(Z, off);
#pragma unroll
    for (int d = 0; d < 32; ++d) {
#pragma unroll
        for (int off = 32; off; off >>= 1) o[d] += __shfl_xor(o[d], off);
    }
    if (lane == 0) {
        float inv = 1.0f / Z;
#pragma unroll
        for (int d = 0; d < 32; ++d)
            ctx[((size_t)bh * Nn + i) * HDd + d] = o[d] * inv;
    }
}

// ---------------- K5a: partial mean over tokens ----------------
__global__ __launch_bounds__(256) void reduce_partial(const float* __restrict__ ctx,
                                                      const float* __restrict__ x,
                                                      float* __restrict__ pcm,
                                                      float* __restrict__ pxm) {
    int b = blockIdx.x >> 4, s = blockIdx.x & 15;
    int c = threadIdx.x;
    int h = c >> 5, d = c & 31;
    float sc = 0.f, sx = 0.f;
    for (int n = s * 64; n < s * 64 + 64; ++n) {
        sc += ctx[(((size_t)b * Hh + h) * Nn + n) * HDd + d];
        sx += x[((size_t)b * Nn + n) * Cc + c];
    }
    pcm[(size_t)blockIdx.x * 256 + c] = sc;
    pxm[(size_t)blockIdx.x * 256 + c] = sx;
}

// ---------------- K5b: final proj(mean) + residual-mean + fc ----------------
__global__ __launch_bounds__(256) void final_kernel(const float* __restrict__ pcm,
                                                    const float* __restrict__ pxm,
                                                    const float* __restrict__ pw,
                                                    const float* __restrict__ pb,
                                                    const float* __restrict__ fcw,
                                                    const float* __restrict__ fcb,
                                                    float* __restrict__ out) {
    __shared__ float cm[256], xm[256], mrow[256];
    int b = blockIdx.x;
    int c = threadIdx.x;
    float sc = 0.f, sx = 0.f;
    for (int s2 = 0; s2 < 16; ++s2) {
        sc += pcm[((size_t)b * 16 + s2) * 256 + c];
        sx += pxm[((size_t)b * 16 + s2) * 256 + c];
    }
    cm[c] = sc * (1.f / 1024.f);
    xm[c] = sx * (1.f / 1024.f);
    __syncthreads();
    float acc = pb[c] + xm[c];
    for (int c2 = 0; c2 < 256; ++c2) acc = fmaf(cm[c2], pw[(size_t)c * 256 + c2], acc);
    mrow[c] = acc;
    __syncthreads();
    if (c < 15) {
        float a2 = fcb[c];
        for (int c2 = 0; c2 < 256; ++c2) a2 = fmaf(mrow[c2], fcw[(size_t)c * 256 + c2], a2);
        out[b * 15 + c] = a2;
    }
}

extern "C" void kernel_launch(void* const* d_in, const int* in_sizes, int n_in,
                              void* d_out, int out_size, void* d_ws, size_t ws_size,
                              hipStream_t stream) {
    const float* x     = (const float*)d_in[0];
    const float* qkv_w = (const float*)d_in[1];
    const float* pw    = (const float*)d_in[2];
    const float* pb    = (const float*)d_in[3];
    const float* fcw   = (const float*)d_in[4];
    const float* fcb   = (const float*)d_in[5];
    const float* rpek  = (const float*)d_in[6];
    const float* rpeq  = (const float*)d_in[7];
    const float* rpev  = (const float*)d_in[8];
    const int*   rp    = (const int*)d_in[9];
    float* out = (float*)d_out;

    const size_t QW = (size_t)Bq * Hh * Nn * HDd;   // 2,097,152 words
    float* wsf = (float*)d_ws;
    float* q   = wsf;
    float* kk  = q + QW;
    float* vv  = kk + QW;
    float* ctx = vv + QW;
    float* pcm = ctx + QW;
    float* pxm = pcm + 32768;
    int*   bt  = (int*)(pxm + 32768);
    float* tqb = (float*)(bt + (size_t)Nn * Nn);

    const size_t fixed_bytes = ((char*)tqb - (char*)d_ws);
    const size_t tq_words_per_batch = (size_t)Hh * Nn * Ll;   // 1,843,200
    int nb = 8;
    while (nb > 1 && fixed_bytes + (size_t)nb * tq_words_per_batch * 4 > ws_size) nb >>= 1;

    qkv_gemm<<<dim3(12, 128), 256, 0, stream>>>(x, qkv_w, q, kk, vv);
    transpose_bucket<<<dim3(32, 32), dim3(32, 32), 0, stream>>>(rp, bt);

    for (int b0 = 0; b0 < Bq; b0 += nb) {
        int bh0 = b0 * Hh;
        int nbh = nb * Hh;
        tq_kernel<<<nbh * 64, 256, 0, stream>>>(kk, rpeq, tqb, bh0);
        attn_kernel<<<nbh * 256, 256, 0, stream>>>(q, kk, vv, tqb, rpek, rpev, rp, bt, ctx, bh0);
    }

    reduce_partial<<<128, 256, 0, stream>>>(ctx, x, pcm, pxm);
    final_kernel<<<8, 256, 0, stream>>>(pcm, pxm, pw, pb, fcw, fcb, out);
}

// Round 3
// 779.880 us; speedup vs baseline: 1.8754x; 1.8754x over previous
//
#include <hip/hip_runtime.h>
#include <math.h>

#define Bq 8
#define Nn 1024
#define Cc 256
#define Hh 8
#define HDd 32
#define Ll 225
#define SCALE 0.17677669529663687f
#define LOG2E 1.44269504088896f
#define THRm 6.0f

typedef __fp16 f16;
typedef __fp16 half8 __attribute__((ext_vector_type(8)));
typedef __fp16 half2t __attribute__((ext_vector_type(2)));
typedef float float4v __attribute__((ext_vector_type(4)));

// ---------------- K1: QKV projection (tiled SGEMM, f32) ----------------
__global__ __launch_bounds__(256) void qkv_gemm(const float* __restrict__ x,
                                                const float* __restrict__ w,
                                                float* __restrict__ q,
                                                float* __restrict__ k,
                                                float* __restrict__ v) {
    __shared__ float As[16][65];
    __shared__ float Bs[16][65];
    const int tix = threadIdx.x;
    const int tx = tix & 15, ty = tix >> 4;
    const int row0 = blockIdx.y * 64;
    const int col0 = blockIdx.x * 64;
    float acc[4][4] = {};
    for (int k0 = 0; k0 < Cc; k0 += 16) {
#pragma unroll
        for (int r = 0; r < 4; ++r) {
            int idx = tix + r * 256;
            int m = idx >> 4, kk = idx & 15;
            As[kk][m] = x[(size_t)(row0 + m) * Cc + k0 + kk];
            Bs[kk][m] = w[(size_t)(col0 + m) * Cc + k0 + kk];
        }
        __syncthreads();
#pragma unroll
        for (int kk = 0; kk < 16; ++kk) {
            float a[4], b[4];
#pragma unroll
            for (int i = 0; i < 4; ++i) a[i] = As[kk][ty * 4 + i];
#pragma unroll
            for (int j = 0; j < 4; ++j) b[j] = Bs[kk][tx * 4 + j];
#pragma unroll
            for (int i = 0; i < 4; ++i)
#pragma unroll
                for (int j = 0; j < 4; ++j) acc[i][j] = fmaf(a[i], b[j], acc[i][j]);
        }
        __syncthreads();
    }
#pragma unroll
    for (int i = 0; i < 4; ++i) {
        int row = row0 + ty * 4 + i;
        int b = row >> 10, n = row & 1023;
#pragma unroll
        for (int j = 0; j < 4; ++j) {
            int oc = col0 + tx * 4 + j;
            int which = oc >> 8;
            int h = (oc >> 5) & 7;
            int d = oc & 31;
            float* dst = (which == 0) ? q : ((which == 1) ? k : v);
            dst[(((size_t)b * Hh + h) * Nn + n) * HDd + d] = acc[i][j];
        }
    }
}

// ---------------- K2: fused iRPE attention, MFMA f16 ----------------
// LDS layout (bytes):
//  sQ  f16[64][40]   @0       5120
//  sK  f16[64][40]   @5120    5120
//  sVT f16[32][72]   @10240   4608
//  sRQ f16[240][40]  @14848   19200   (rpek, then rq'=SCALE*rpeq)
//  sTQ f16[64][226]  @34048   28928   (tq tile; reused as rvT f16[32][264])
//  sTK f16[64][226]  @62976   28928
//  sA  f32[64][228]  @91904   58368
//  sP  f16[4][16][72]@150272  9216
//  sF  f32[64]       @159488  256     total 159744
#define SMEM_BYTES 159744

__device__ __forceinline__ int iclamp7(int x) {
    return x < -7 ? -7 : (x > 7 ? 7 : x);
}

__global__ __launch_bounds__(256, 1) void attn_mfma(
    const float* __restrict__ q, const float* __restrict__ k, const float* __restrict__ v,
    const float* __restrict__ rpek, const float* __restrict__ rpeq, const float* __restrict__ rpev,
    float* __restrict__ ctx)
{
    extern __shared__ char smem[];
    f16*   sQ  = (f16*)(smem);
    f16*   sK  = (f16*)(smem + 5120);
    f16*   sVT = (f16*)(smem + 10240);
    f16*   sRQ = (f16*)(smem + 14848);
    f16*   sTQ = (f16*)(smem + 34048);
    f16*   sTK = (f16*)(smem + 62976);
    float* sA  = (float*)(smem + 91904);
    f16*   sP  = (f16*)(smem + 150272);
    float* sF  = (float*)(smem + 159488);

    const int tid = threadIdx.x;
    const int lane = tid & 63;
    const int w = tid >> 6;
    const int li = lane & 15;
    const int g = lane >> 4;
    const int blk = blockIdx.x;
    const int bh = blk >> 4;
    const int h = bh & 7;
    const int i0 = (blk & 15) << 6;
    const int i_local = w * 16 + li;
    const int i_glob = i0 + i_local;
    const int ri = i_glob >> 5, ci = i_glob & 31;
    const int ciA = ci - 4 * g;
    const int jrb = 4 * g;

    // zero sA
    {
        float4v zz = {0.f, 0.f, 0.f, 0.f};
        for (int idx = tid; idx < 64 * 228 / 4; idx += 256)
            *(float4v*)(sA + idx * 4) = zz;
    }
    // stage sQ (f32 -> f16)
    {
        int row = tid >> 2, d0 = (tid & 3) * 8;
        const float4v* src = (const float4v*)(q + ((size_t)bh * Nn + i0 + row) * HDd + d0);
        float4v x0 = src[0], x1 = src[1];
        union { half8 v8; half2t hh[4]; } u;
        u.hh[0] = __builtin_amdgcn_cvt_pkrtz(x0[0], x0[1]);
        u.hh[1] = __builtin_amdgcn_cvt_pkrtz(x0[2], x0[3]);
        u.hh[2] = __builtin_amdgcn_cvt_pkrtz(x1[0], x1[1]);
        u.hh[3] = __builtin_amdgcn_cvt_pkrtz(x1[2], x1[3]);
        *(half8*)(sQ + row * 40 + d0) = u.v8;
    }
    // stage sRQ = rpek[h] (zero-pad rows 225..239)
    for (int idx = tid; idx < 960; idx += 256) {
        int row = idx >> 2, d0 = (idx & 3) * 8;
        union { half8 v8; half2t hh[4]; } u;
        if (row < Ll) {
            const float4v* src = (const float4v*)(rpek + ((size_t)h * Ll + row) * HDd + d0);
            float4v x0 = src[0], x1 = src[1];
            u.hh[0] = __builtin_amdgcn_cvt_pkrtz(x0[0], x0[1]);
            u.hh[1] = __builtin_amdgcn_cvt_pkrtz(x0[2], x0[3]);
            u.hh[2] = __builtin_amdgcn_cvt_pkrtz(x1[0], x1[1]);
            u.hh[3] = __builtin_amdgcn_cvt_pkrtz(x1[2], x1[3]);
        } else {
            half2t z2; z2[0] = (f16)0.f; z2[1] = (f16)0.f;
            u.hh[0] = z2; u.hh[1] = z2; u.hh[2] = z2; u.hh[3] = z2;
        }
        *(half8*)(sRQ + row * 40 + d0) = u.v8;
    }
    __syncthreads();

    // Q fragments
    half8 aQ[4];
#pragma unroll
    for (int mt = 0; mt < 4; ++mt)
        aQ[mt] = *(const half8*)(sQ + (mt * 16 + li) * 40 + 8 * g);
    half8 bQ = *(const half8*)(sQ + i_local * 40 + 8 * g);

    // tk_tile = Q · rpek^T  -> sTK[i][l]
#pragma unroll
    for (int kk = 0; kk < 4; ++kk) {
        int nt = w + 4 * kk;
        if (nt <= 14) {
            half8 bR = *(const half8*)(sRQ + (nt * 16 + li) * 40 + 8 * g);
            int l = nt * 16 + li;
#pragma unroll
            for (int mt = 0; mt < 4; ++mt) {
                float4v c = {0.f, 0.f, 0.f, 0.f};
                c = __builtin_amdgcn_mfma_f32_16x16x32_f16(aQ[mt], bR, c, 0, 0, 0);
                if (l < Ll) {
#pragma unroll
                    for (int r = 0; r < 4; ++r)
                        sTK[(mt * 16 + jrb + r) * 226 + l] = (f16)c[r];
                }
            }
        }
    }
    __syncthreads();
    // restage sRQ = SCALE * rpeq[h]
    for (int idx = tid; idx < 960; idx += 256) {
        int row = idx >> 2, d0 = (idx & 3) * 8;
        union { half8 v8; half2t hh[4]; } u;
        if (row < Ll) {
            const float4v* src = (const float4v*)(rpeq + ((size_t)h * Ll + row) * HDd + d0);
            float4v x0 = src[0], x1 = src[1];
            u.hh[0] = __builtin_amdgcn_cvt_pkrtz(x0[0] * SCALE, x0[1] * SCALE);
            u.hh[1] = __builtin_amdgcn_cvt_pkrtz(x0[2] * SCALE, x0[3] * SCALE);
            u.hh[2] = __builtin_amdgcn_cvt_pkrtz(x1[0] * SCALE, x1[1] * SCALE);
            u.hh[3] = __builtin_amdgcn_cvt_pkrtz(x1[2] * SCALE, x1[3] * SCALE);
        } else {
            half2t z2; z2[0] = (f16)0.f; z2[1] = (f16)0.f;
            u.hh[0] = z2; u.hh[1] = z2; u.hh[2] = z2; u.hh[3] = z2;
        }
        *(half8*)(sRQ + row * 40 + d0) = u.v8;
    }
    __syncthreads();

    float4v o0 = {0.f, 0.f, 0.f, 0.f}, o1 = {0.f, 0.f, 0.f, 0.f};
    float z = 0.f, m_run = -3.0e38f;

    for (int jt = 0; jt < 16; ++jt) {
        const int j0 = jt << 6;
        __syncthreads();  // protect sK/sVT/sTQ from previous-iteration readers
        {
            int row = tid >> 2, d0 = (tid & 3) * 8;
            const float4v* src = (const float4v*)(k + ((size_t)bh * Nn + j0 + row) * HDd + d0);
            float4v x0 = src[0], x1 = src[1];
            union { half8 v8; half2t hh[4]; } u;
            u.hh[0] = __builtin_amdgcn_cvt_pkrtz(x0[0], x0[1]);
            u.hh[1] = __builtin_amdgcn_cvt_pkrtz(x0[2], x0[3]);
            u.hh[2] = __builtin_amdgcn_cvt_pkrtz(x1[0], x1[1]);
            u.hh[3] = __builtin_amdgcn_cvt_pkrtz(x1[2], x1[3]);
            *(half8*)(sK + row * 40 + d0) = u.v8;
            const float4v* sv = (const float4v*)(v + ((size_t)bh * Nn + j0 + row) * HDd + d0);
            float4v y0 = sv[0], y1 = sv[1];
            sVT[(d0 + 0) * 72 + row] = (f16)y0[0];
            sVT[(d0 + 1) * 72 + row] = (f16)y0[1];
            sVT[(d0 + 2) * 72 + row] = (f16)y0[2];
            sVT[(d0 + 3) * 72 + row] = (f16)y0[3];
            sVT[(d0 + 4) * 72 + row] = (f16)y1[0];
            sVT[(d0 + 5) * 72 + row] = (f16)y1[1];
            sVT[(d0 + 6) * 72 + row] = (f16)y1[2];
            sVT[(d0 + 7) * 72 + row] = (f16)y1[3];
        }
        __syncthreads();

        half8 aK[4];
#pragma unroll
        for (int mt = 0; mt < 4; ++mt)
            aK[mt] = *(const half8*)(sK + (mt * 16 + li) * 40 + 8 * g);

        // S^T = K · Q^T  (S^T[j][i])
        float4v sacc[4];
#pragma unroll
        for (int mt = 0; mt < 4; ++mt) {
            float4v c = {0.f, 0.f, 0.f, 0.f};
            sacc[mt] = __builtin_amdgcn_mfma_f32_16x16x32_f16(aK[mt], bQ, c, 0, 0, 0);
        }
        // tq_tile = K · rq'^T -> sTQ[j][l]
#pragma unroll
        for (int kk = 0; kk < 4; ++kk) {
            int nt = w + 4 * kk;
            if (nt <= 14) {
                half8 bR = *(const half8*)(sRQ + (nt * 16 + li) * 40 + 8 * g);
                int l = nt * 16 + li;
#pragma unroll
                for (int mt = 0; mt < 4; ++mt) {
                    float4v c = {0.f, 0.f, 0.f, 0.f};
                    c = __builtin_amdgcn_mfma_f32_16x16x32_f16(aK[mt], bR, c, 0, 0, 0);
                    if (l < Ll) {
#pragma unroll
                        for (int r = 0; r < 4; ++r)
                            sTQ[(mt * 16 + jrb + r) * 226 + l] = (f16)c[r];
                    }
                }
            }
        }
        __syncthreads();

        // bias + online softmax
        const int drA = iclamp7(ri - jt * 2);
        const int drB = iclamp7(ri - jt * 2 - 1);
        int bsv[4][4];
        float mloc = -3.0e38f;
#pragma unroll
        for (int mt = 0; mt < 4; ++mt) {
            const int dr = (mt < 2) ? drA : drB;
            const int cbase = ciA - ((mt & 1) << 4);
#pragma unroll
            for (int r = 0; r < 4; ++r) {
                int dc = iclamp7(cbase - r);
                int b = dr * 15 + dc + 112;
                bsv[mt][r] = b;
                float tkv = (float)sTK[i_local * 226 + b];
                float tqv = (float)sTQ[(mt * 16 + jrb + r) * 226 + (224 - b)];
                float s = sacc[mt][r] + tkv + tqv;
                sacc[mt][r] = s;
                mloc = fmaxf(mloc, s);
            }
        }
        mloc = fmaxf(mloc, __shfl_xor(mloc, 16));
        mloc = fmaxf(mloc, __shfl_xor(mloc, 32));
        float f = 1.0f;
        if (mloc > m_run + THRm) {
            f = exp2f((m_run - mloc) * LOG2E);
            m_run = mloc;
        }
        z *= f;
        o0 *= f; o1 *= f;
        if (__any(f != 1.0f)) {
            if (g == 0) sF[w * 16 + li] = f;
#pragma unroll
            for (int rr = 0; rr < 16; ++rr) {
                float ff = sF[w * 16 + rr];
                for (int c2 = lane; c2 < 228; c2 += 64)
                    sA[(w * 16 + rr) * 228 + c2] *= ff;
            }
        }
        // exp + A-scatter + pack P
#pragma unroll
        for (int mt = 0; mt < 4; ++mt) {
#pragma unroll
            for (int r = 0; r < 4; ++r) {
                float p = exp2f((sacc[mt][r] - m_run) * LOG2E);
                z += p;
                atomicAdd(&sA[i_local * 228 + bsv[mt][r]], p);
                sacc[mt][r] = p;
            }
            half2t q0 = __builtin_amdgcn_cvt_pkrtz(sacc[mt][0], sacc[mt][1]);
            half2t q1 = __builtin_amdgcn_cvt_pkrtz(sacc[mt][2], sacc[mt][3]);
            *(half2t*)(sP + w * 1152 + li * 72 + mt * 16 + jrb)     = q0;
            *(half2t*)(sP + w * 1152 + li * 72 + mt * 16 + jrb + 2) = q1;
        }
        // PV: O^T += V^T · P^T
#pragma unroll
        for (int ks = 0; ks < 2; ++ks) {
            half8 bP  = *(const half8*)(sP + w * 1152 + li * 72 + ks * 32 + 8 * g);
            half8 aV0 = *(const half8*)(sVT + li * 72 + ks * 32 + 8 * g);
            half8 aV1 = *(const half8*)(sVT + (16 + li) * 72 + ks * 32 + 8 * g);
            o0 = __builtin_amdgcn_mfma_f32_16x16x32_f16(aV0, bP, o0, 0, 0, 0);
            o1 = __builtin_amdgcn_mfma_f32_16x16x32_f16(aV1, bP, o1, 0, 0, 0);
        }
    }

    // epilogue: rv-term via MFMA, normalize, write
    __syncthreads();
    {   // stage rvT into sTQ area: rvT[32][264], zero-padded l>=225
        int d = tid & 31;
        int lc = tid >> 5;
        for (int c = 0; c < 33; ++c) {
            int l = lc * 33 + c;
            float val = (l < Ll) ? rpev[((size_t)h * Ll + l) * HDd + d] : 0.f;
            sTQ[d * 264 + l] = (f16)val;
        }
    }
    __syncthreads();
    float zz = z + __shfl_xor(z, 16);
    zz += __shfl_xor(zz, 32);
    float rz = 1.0f / zz;
    o0 *= rz; o1 *= rz;
    const f16* sRVT = sTQ;
#pragma unroll
    for (int ks = 0; ks < 8; ++ks) {
        union { half8 v8; half2t hh[4]; } u;
        if (ks < 7) {
            float4v a0 = *(const float4v*)(sA + i_local * 228 + ks * 32 + 8 * g);
            float4v a1 = *(const float4v*)(sA + i_local * 228 + ks * 32 + 8 * g + 4);
            u.hh[0] = __builtin_amdgcn_cvt_pkrtz(a0[0] * rz, a0[1] * rz);
            u.hh[1] = __builtin_amdgcn_cvt_pkrtz(a0[2] * rz, a0[3] * rz);
            u.hh[2] = __builtin_amdgcn_cvt_pkrtz(a1[0] * rz, a1[1] * rz);
            u.hh[3] = __builtin_amdgcn_cvt_pkrtz(a1[2] * rz, a1[3] * rz);
        } else {
            half2t z2; z2[0] = (f16)0.f; z2[1] = (f16)0.f;
            u.hh[0] = z2; u.hh[1] = z2; u.hh[2] = z2; u.hh[3] = z2;
            if (g == 0) {
                float4v a0 = *(const float4v*)(sA + i_local * 228 + 224);
                u.hh[0] = __builtin_amdgcn_cvt_pkrtz(a0[0] * rz, a0[1] * rz);
                u.hh[1] = __builtin_amdgcn_cvt_pkrtz(a0[2] * rz, a0[3] * rz);
            }
        }
        half8 aR0 = *(const half8*)(sRVT + li * 264 + ks * 32 + 8 * g);
        half8 aR1 = *(const half8*)(sRVT + (16 + li) * 264 + ks * 32 + 8 * g);
        o0 = __builtin_amdgcn_mfma_f32_16x16x32_f16(aR0, u.v8, o0, 0, 0, 0);
        o1 = __builtin_amdgcn_mfma_f32_16x16x32_f16(aR1, u.v8, o1, 0, 0, 0);
    }
    // ctx layout: [bh][d][n]
    float* cbase = ctx + (size_t)bh * 32 * 1024 + i0 + i_local;
#pragma unroll
    for (int r = 0; r < 4; ++r) {
        cbase[(size_t)(jrb + r) * 1024]      = o0[r];
        cbase[(size_t)(16 + jrb + r) * 1024] = o1[r];
    }
}

// ---------------- K3: partial mean over tokens ----------------
__global__ __launch_bounds__(256) void reduce_partial(const float* __restrict__ ctx,
                                                      const float* __restrict__ x,
                                                      float* __restrict__ pcm,
                                                      float* __restrict__ pxm) {
    int b = blockIdx.x >> 4, s = blockIdx.x & 15;
    int c = threadIdx.x;
    const float* crow = ctx + ((size_t)(b * 8 + (c >> 5)) * 32 + (c & 31)) * 1024 + s * 64;
    float sc = 0.f, sx = 0.f;
    for (int n = 0; n < 64; ++n) {
        sc += crow[n];
        sx += x[((size_t)b * Nn + s * 64 + n) * Cc + c];
    }
    pcm[(size_t)blockIdx.x * 256 + c] = sc;
    pxm[(size_t)blockIdx.x * 256 + c] = sx;
}

// ---------------- K4: final proj(mean) + residual-mean + fc ----------------
__global__ __launch_bounds__(256) void final_kernel(const float* __restrict__ pcm,
                                                    const float* __restrict__ pxm,
                                                    const float* __restrict__ pw,
                                                    const float* __restrict__ pb,
                                                    const float* __restrict__ fcw,
                                                    const float* __restrict__ fcb,
                                                    float* __restrict__ out) {
    __shared__ float cm[256], xm[256], mrow[256];
    int b = blockIdx.x;
    int c = threadIdx.x;
    float sc = 0.f, sx = 0.f;
    for (int s2 = 0; s2 < 16; ++s2) {
        sc += pcm[((size_t)b * 16 + s2) * 256 + c];
        sx += pxm[((size_t)b * 16 + s2) * 256 + c];
    }
    cm[c] = sc * (1.f / 1024.f);
    xm[c] = sx * (1.f / 1024.f);
    __syncthreads();
    float acc = pb[c] + xm[c];
    for (int c2 = 0; c2 < 256; ++c2) acc = fmaf(cm[c2], pw[(size_t)c * 256 + c2], acc);
    mrow[c] = acc;
    __syncthreads();
    if (c < 15) {
        float a2 = fcb[c];
        for (int c2 = 0; c2 < 256; ++c2) a2 = fmaf(mrow[c2], fcw[(size_t)c * 256 + c2], a2);
        out[b * 15 + c] = a2;
    }
}

extern "C" void kernel_launch(void* const* d_in, const int* in_sizes, int n_in,
                              void* d_out, int out_size, void* d_ws, size_t ws_size,
                              hipStream_t stream) {
    const float* x     = (const float*)d_in[0];
    const float* qkv_w = (const float*)d_in[1];
    const float* pw    = (const float*)d_in[2];
    const float* pb    = (const float*)d_in[3];
    const float* fcw   = (const float*)d_in[4];
    const float* fcb   = (const float*)d_in[5];
    const float* rpek  = (const float*)d_in[6];
    const float* rpeq  = (const float*)d_in[7];
    const float* rpev  = (const float*)d_in[8];
    float* out = (float*)d_out;

    const size_t QW = (size_t)Bq * Hh * Nn * HDd;  // 2,097,152
    float* wsf = (float*)d_ws;
    float* q   = wsf;
    float* kk  = q + QW;
    float* vv  = kk + QW;
    float* ctx = vv + QW;
    float* pcm = ctx + QW;
    float* pxm = pcm + 32768;

    hipFuncSetAttribute((const void*)attn_mfma,
                        hipFuncAttributeMaxDynamicSharedMemorySize, SMEM_BYTES);

    qkv_gemm<<<dim3(12, 128), 256, 0, stream>>>(x, qkv_w, q, kk, vv);
    attn_mfma<<<1024, 256, SMEM_BYTES, stream>>>(q, kk, vv, rpek, rpeq, rpev, ctx);
    reduce_partial<<<128, 256, 0, stream>>>(ctx, x, pcm, pxm);
    final_kernel<<<8, 256, 0, stream>>>(pcm, pxm, pw, pb, fcw, fcb, out);
}

// Round 4
// 547.967 us; speedup vs baseline: 2.6692x; 1.4232x over previous
//
#include <hip/hip_runtime.h>
#include <math.h>

#define Bq 8
#define Nn 1024
#define Cc 256
#define Hh 8
#define HDd 32
#define Ll 225
#define SCALE 0.17677669529663687f
#define LOG2E 1.44269504088896f
#define THRr 8.0f

typedef __fp16 f16;
typedef __fp16 half8 __attribute__((ext_vector_type(8)));
typedef __fp16 half4 __attribute__((ext_vector_type(4)));
typedef __fp16 half2t __attribute__((ext_vector_type(2)));
typedef float float4v __attribute__((ext_vector_type(4)));

// ---------------- K1: QKV projection (tiled SGEMM, f32) ----------------
__global__ __launch_bounds__(256) void qkv_gemm(const float* __restrict__ x,
                                                const float* __restrict__ w,
                                                float* __restrict__ q,
                                                float* __restrict__ k,
                                                float* __restrict__ v) {
    __shared__ float As[16][65];
    __shared__ float Bs[16][65];
    const int tix = threadIdx.x;
    const int tx = tix & 15, ty = tix >> 4;
    const int row0 = blockIdx.y * 64;
    const int col0 = blockIdx.x * 64;
    float acc[4][4] = {};
    for (int k0 = 0; k0 < Cc; k0 += 16) {
#pragma unroll
        for (int r = 0; r < 4; ++r) {
            int idx = tix + r * 256;
            int m = idx >> 4, kk = idx & 15;
            As[kk][m] = x[(size_t)(row0 + m) * Cc + k0 + kk];
            Bs[kk][m] = w[(size_t)(col0 + m) * Cc + k0 + kk];
        }
        __syncthreads();
#pragma unroll
        for (int kk = 0; kk < 16; ++kk) {
            float a[4], b[4];
#pragma unroll
            for (int i = 0; i < 4; ++i) a[i] = As[kk][ty * 4 + i];
#pragma unroll
            for (int j = 0; j < 4; ++j) b[j] = Bs[kk][tx * 4 + j];
#pragma unroll
            for (int i = 0; i < 4; ++i)
#pragma unroll
                for (int j = 0; j < 4; ++j) acc[i][j] = fmaf(a[i], b[j], acc[i][j]);
        }
        __syncthreads();
    }
#pragma unroll
    for (int i = 0; i < 4; ++i) {
        int row = row0 + ty * 4 + i;
        int b = row >> 10, n = row & 1023;
#pragma unroll
        for (int j = 0; j < 4; ++j) {
            int oc = col0 + tx * 4 + j;
            int which = oc >> 8;
            int h = (oc >> 5) & 7;
            int d = oc & 31;
            float* dst = (which == 0) ? q : ((which == 1) ? k : v);
            dst[(((size_t)b * Hh + h) * Nn + n) * HDd + d] = acc[i][j];
        }
    }
}

// ---------------- K2: fused iRPE attention, MFMA f16, 8 waves ----------------
// LDS layout (bytes):
//  sRQ  f16[240][40]  @0       19200  (rpek, then SCALE*LOG2E*rpeq)
//  sTK  f16[64][226]  @19200   28928  (tk table; rvT f16[32][264] aliases post-loop)
//  sA   f32[64][228]  @48128   58368
//  sK   f16[2][64][40]@106496  10240
//  sVT  f16[2][32][72]@116736  9216   (column bit4 XOR-swizzled by (d>>3)&1)
//  sTQT f16[2][64][68]@125952  17408  (per-tile tq window, [slot][j])
//  sP   f16[8][16][72]@143360  18432  (sQ f16[64][40] + sO1 f32[64][36] alias)
//  sM   f32[2][64]    @161792  512
//  sZ   f32[2][64]    @162304  512    total 162816
#define OFF_RQ   0
#define OFF_TK   19200
#define OFF_A    48128
#define OFF_K    106496
#define OFF_VT   116736
#define OFF_TQT  125952
#define OFF_P    143360
#define OFF_M    161792
#define OFF_Z    162304
#define SMEM_BYTES 162816

__device__ __forceinline__ int iclamp7(int x) {
    return x < -7 ? -7 : (x > 7 ? 7 : x);
}

__global__ __launch_bounds__(512, 2) void attn_mfma(
    const float* __restrict__ q, const float* __restrict__ k, const float* __restrict__ v,
    const float* __restrict__ rpek, const float* __restrict__ rpeq, const float* __restrict__ rpev,
    float* __restrict__ ctx)
{
    extern __shared__ char smem[];
    f16*   sRQ  = (f16*)(smem + OFF_RQ);
    f16*   sTK  = (f16*)(smem + OFF_TK);
    float* sA   = (float*)(smem + OFF_A);
    f16*   sK   = (f16*)(smem + OFF_K);
    f16*   sVT  = (f16*)(smem + OFF_VT);
    f16*   sTQT = (f16*)(smem + OFF_TQT);
    f16*   sP   = (f16*)(smem + OFF_P);
    f16*   sQ   = (f16*)(smem + OFF_P);     // alias: prologue only
    float* sO1  = (float*)(smem + OFF_P);   // alias: epilogue only
    f16*   sRVT = (f16*)(smem + OFF_TK);    // alias: epilogue only
    float* sM   = (float*)(smem + OFF_M);
    float* sZ   = (float*)(smem + OFF_Z);

    const int tid = threadIdx.x;
    const int lane = tid & 63;
    const int w = tid >> 6;      // 0..7
    const int wl = w & 3;        // wave within group
    const int g2 = w >> 2;       // j-tile group
    const int li = lane & 15;
    const int g = lane >> 4;
    const int blk = blockIdx.x;
    const int bh = blk >> 4;
    const int h = bh & 7;
    const int i0 = (blk & 15) << 6;
    const int i_local = wl * 16 + li;
    const int i_glob = i0 + i_local;
    const int ri = i_glob >> 5, ci = i_glob & 31;
    const int ciA = ci - 4 * g;
    const int jrb = 4 * g;
    const int Ri = i0 >> 5;
    const size_t kvbase = (size_t)bh * (Nn * HDd);

    // staging ids (512 threads stage 128 rows of K and V)
    const int sg  = tid >> 8;          // staging group
    const int sr  = (tid >> 2) & 63;   // row in tile
    const int sq4 = tid & 3;
    const int sd0 = sq4 * 8;
    const int vswz = (sq4 & 1) << 4;   // sVT column swizzle bit

    // zero sA
    {
        float4v zz = {0.f, 0.f, 0.f, 0.f};
        for (int idx = tid; idx < 64 * 228 / 4; idx += 512)
            ((float4v*)sA)[idx] = zz;
    }
    // stage sQ (f32 -> f16, x LOG2E)
    if (tid < 256) {
        int row = tid >> 2, d0 = (tid & 3) * 8;
        const float4v* src = (const float4v*)(q + kvbase + (size_t)(i0 + row) * HDd + d0);
        float4v x0 = src[0], x1 = src[1];
        union { half8 v8; half2t hh[4]; } u;
        u.hh[0] = __builtin_amdgcn_cvt_pkrtz(x0[0] * LOG2E, x0[1] * LOG2E);
        u.hh[1] = __builtin_amdgcn_cvt_pkrtz(x0[2] * LOG2E, x0[3] * LOG2E);
        u.hh[2] = __builtin_amdgcn_cvt_pkrtz(x1[0] * LOG2E, x1[1] * LOG2E);
        u.hh[3] = __builtin_amdgcn_cvt_pkrtz(x1[2] * LOG2E, x1[3] * LOG2E);
        *(half8*)(sQ + row * 40 + d0) = u.v8;
    }
    // stage sRQ = rpek[h] (plain; zero-pad rows 225..239)
    for (int idx = tid; idx < 960; idx += 512) {
        int row = idx >> 2, d0 = (idx & 3) * 8;
        union { half8 v8; half2t hh[4]; } u;
        if (row < Ll) {
            const float4v* src = (const float4v*)(rpek + ((size_t)h * Ll + row) * HDd + d0);
            float4v x0 = src[0], x1 = src[1];
            u.hh[0] = __builtin_amdgcn_cvt_pkrtz(x0[0], x0[1]);
            u.hh[1] = __builtin_amdgcn_cvt_pkrtz(x0[2], x0[3]);
            u.hh[2] = __builtin_amdgcn_cvt_pkrtz(x1[0], x1[1]);
            u.hh[3] = __builtin_amdgcn_cvt_pkrtz(x1[2], x1[3]);
        } else {
            half2t z2; z2[0] = (f16)0.f; z2[1] = (f16)0.f;
            u.hh[0] = z2; u.hh[1] = z2; u.hh[2] = z2; u.hh[3] = z2;
        }
        *(half8*)(sRQ + row * 40 + d0) = u.v8;
    }
    __syncthreads();

    // Q fragments
    half8 aQ[4];
#pragma unroll
    for (int mt = 0; mt < 4; ++mt)
        aQ[mt] = *(const half8*)(sQ + (mt * 16 + li) * 40 + 8 * g);
    half8 bQ = *(const half8*)(sQ + i_local * 40 + 8 * g);

    // tk prologue: sTK[i][l] = (LOG2E q_i) . rpek_l ; 15 nt tiles over 8 waves
#pragma unroll
    for (int pass = 0; pass < 2; ++pass) {
        int nt = w + pass * 8;
        if (nt <= 14) {
            half8 bR = *(const half8*)(sRQ + (nt * 16 + li) * 40 + 8 * g);
            int l = nt * 16 + li;
#pragma unroll
            for (int mt = 0; mt < 4; ++mt) {
                float4v c = {0.f, 0.f, 0.f, 0.f};
                c = __builtin_amdgcn_mfma_f32_16x16x32_f16(aQ[mt], bR, c, 0, 0, 0);
                if (l < Ll) {
#pragma unroll
                    for (int r = 0; r < 4; ++r)
                        sTK[(mt * 16 + jrb + r) * 226 + l] = (f16)c[r];
                }
            }
        }
    }
    __syncthreads();
    // restage sRQ = SCALE*LOG2E * rpeq[h]
    for (int idx = tid; idx < 960; idx += 512) {
        int row = idx >> 2, d0 = (idx & 3) * 8;
        union { half8 v8; half2t hh[4]; } u;
        if (row < Ll) {
            const float4v* src = (const float4v*)(rpeq + ((size_t)h * Ll + row) * HDd + d0);
            float4v x0 = src[0], x1 = src[1];
            const float sc = SCALE * LOG2E;
            u.hh[0] = __builtin_amdgcn_cvt_pkrtz(x0[0] * sc, x0[1] * sc);
            u.hh[1] = __builtin_amdgcn_cvt_pkrtz(x0[2] * sc, x0[3] * sc);
            u.hh[2] = __builtin_amdgcn_cvt_pkrtz(x1[0] * sc, x1[1] * sc);
            u.hh[3] = __builtin_amdgcn_cvt_pkrtz(x1[2] * sc, x1[3] * sc);
        } else {
            half2t z2; z2[0] = (f16)0.f; z2[1] = (f16)0.f;
            u.hh[0] = z2; u.hh[1] = z2; u.hh[2] = z2; u.hh[3] = z2;
        }
        *(half8*)(sRQ + row * 40 + d0) = u.v8;
    }
    // prefetch tile 0 K/V into regs
    float4v kx0, kx1, vx0, vx1;
    {
        int j = sg * 64 + sr;
        const float4v* ks_ = (const float4v*)(k + kvbase + (size_t)j * HDd + sd0);
        kx0 = ks_[0]; kx1 = ks_[1];
        const float4v* vs_ = (const float4v*)(v + kvbase + (size_t)j * HDd + sd0);
        vx0 = vs_[0]; vx1 = vs_[1];
    }

    float4v o0 = {0.f, 0.f, 0.f, 0.f}, o1 = {0.f, 0.f, 0.f, 0.f};
    float z = 0.f, m_run = -1.0e30f;

    for (int it = 0; it < 8; ++it) {
        __syncthreads();   // #1: previous readers of sK/sVT done; sRQ restage done (it=0)
        // stage K/V from prefetch regs
        {
            union { half8 v8; half2t hh[4]; } uk;
            uk.hh[0] = __builtin_amdgcn_cvt_pkrtz(kx0[0], kx0[1]);
            uk.hh[1] = __builtin_amdgcn_cvt_pkrtz(kx0[2], kx0[3]);
            uk.hh[2] = __builtin_amdgcn_cvt_pkrtz(kx1[0], kx1[1]);
            uk.hh[3] = __builtin_amdgcn_cvt_pkrtz(kx1[2], kx1[3]);
            *(half8*)(sK + sg * 2560 + sr * 40 + sd0) = uk.v8;
            f16* vb = sVT + sg * 2304;
            int colv = sr ^ vswz;
            vb[(sd0 + 0) * 72 + colv] = (f16)vx0[0];
            vb[(sd0 + 1) * 72 + colv] = (f16)vx0[1];
            vb[(sd0 + 2) * 72 + colv] = (f16)vx0[2];
            vb[(sd0 + 3) * 72 + colv] = (f16)vx0[3];
            vb[(sd0 + 4) * 72 + colv] = (f16)vx1[0];
            vb[(sd0 + 5) * 72 + colv] = (f16)vx1[1];
            vb[(sd0 + 6) * 72 + colv] = (f16)vx1[2];
            vb[(sd0 + 7) * 72 + colv] = (f16)vx1[3];
        }
        __syncthreads();   // #2: staging done
        if (it < 7) {      // prefetch next tile (overlaps all compute below)
            int j = (it + 1) * 128 + sg * 64 + sr;
            const float4v* ks_ = (const float4v*)(k + kvbase + (size_t)j * HDd + sd0);
            kx0 = ks_[0]; kx1 = ks_[1];
            const float4v* vs_ = (const float4v*)(v + kvbase + (size_t)j * HDd + sd0);
            vx0 = vs_[0]; vx1 = vs_[1];
        }
        const int j0 = it * 128 + g2 * 64;
        // K frags + S^T = K . Q^T
        half8 aK[4];
        {
            f16* sKg = sK + g2 * 2560;
#pragma unroll
            for (int mt = 0; mt < 4; ++mt)
                aK[mt] = *(const half8*)(sKg + (mt * 16 + li) * 40 + 8 * g);
        }
        float4v sacc[4];
#pragma unroll
        for (int mt = 0; mt < 4; ++mt) {
            float4v c = {0.f, 0.f, 0.f, 0.f};
            sacc[mt] = __builtin_amdgcn_mfma_f32_16x16x32_f16(aK[mt], bQ, c, 0, 0, 0);
        }
        // tq window: only l' in [w0, w0+64) reachable this tile
        const int dC = Ri - (j0 >> 5);
        const int drmax = iclamp7(dC + 1), drmin = iclamp7(dC - 1);
        const int w0 = ((7 - drmax) * 15) & ~15;
        const int lpmax = (7 - drmin) * 15 + 14;
        {
            int nt = (w0 >> 4) + wl;
            if (nt * 16 <= lpmax) {
                half8 bR = *(const half8*)(sRQ + (nt * 16 + li) * 40 + 8 * g);
                int slot = nt * 16 + li - w0;
                f16* tbase = sTQT + g2 * 4352 + slot * 68;
#pragma unroll
                for (int mt = 0; mt < 4; ++mt) {
                    float4v c = {0.f, 0.f, 0.f, 0.f};
                    c = __builtin_amdgcn_mfma_f32_16x16x32_f16(aK[mt], bR, c, 0, 0, 0);
                    union { half4 v4; half2t hh[2]; } u;
                    u.hh[0] = __builtin_amdgcn_cvt_pkrtz(c[0], c[1]);
                    u.hh[1] = __builtin_amdgcn_cvt_pkrtz(c[2], c[3]);
                    *(half4*)(tbase + mt * 16 + jrb) = u.v4;
                }
            }
        }
        // raw-S per-i max (bias folded into THR headroom)
        float mloc = -1.0e30f;
#pragma unroll
        for (int mt = 0; mt < 4; ++mt)
#pragma unroll
            for (int r = 0; r < 4; ++r) mloc = fmaxf(mloc, sacc[mt][r]);
        mloc = fmaxf(mloc, __shfl_xor(mloc, 16));
        mloc = fmaxf(mloc, __shfl_xor(mloc, 32));
        if (g == 0) sM[g2 * 64 + i_local] = mloc;
        __syncthreads();   // #3: sTQT + sM ready
        float mb = fmaxf(sM[i_local], sM[64 + i_local]);
        float f = 1.0f;
        if (mb > m_run + THRr) { f = exp2f(m_run - mb); m_run = mb; }
        z *= f; o0 *= f; o1 *= f;
        // gather biases, finalize s
        const int drA = iclamp7(ri - (j0 >> 5));
        const int drB = iclamp7(ri - (j0 >> 5) - 1);
        int bsv[4][4];
        {
            f16* tqt = sTQT + g2 * 4352;
#pragma unroll
            for (int mt = 0; mt < 4; ++mt) {
                const int dr = (mt < 2) ? drA : drB;
                const int cb = ciA - ((mt & 1) << 4);
#pragma unroll
                for (int r = 0; r < 4; ++r) {
                    int dc = iclamp7(cb - r);
                    int b = dr * 15 + dc + 112;
                    bsv[mt][r] = b;
                    float tkv = (float)sTK[i_local * 226 + b];
                    float tqv = (float)tqt[(224 - b - w0) * 68 + (mt * 16 + jrb + r)];
                    sacc[mt][r] += tkv + tqv;
                }
            }
        }
        // group-0 rescales shared sA rows (f identical across groups)
        if (it > 0 && g2 == 0 && __any(f != 1.0f)) {
#pragma unroll 1
            for (int rr = 0; rr < 16; ++rr) {
                float ff = __shfl(f, rr);
                if (ff != 1.0f) {
                    float* row = sA + (wl * 16 + rr) * 228;
                    for (int c2 = lane; c2 < 228; c2 += 64) row[c2] *= ff;
                }
            }
        }
        __syncthreads();   // #4: sA rescale done before new scatter
        // exp + A-scatter + P pack
        f16* pw = sP + w * 1152;
#pragma unroll
        for (int mt = 0; mt < 4; ++mt) {
            float pp0, pp1, pp2, pp3;
            {
                float p0 = exp2f(sacc[mt][0] - m_run);
                float p1 = exp2f(sacc[mt][1] - m_run);
                float p2 = exp2f(sacc[mt][2] - m_run);
                float p3 = exp2f(sacc[mt][3] - m_run);
                z += p0 + p1 + p2 + p3;
                atomicAdd(sA + i_local * 228 + bsv[mt][0], p0);
                atomicAdd(sA + i_local * 228 + bsv[mt][1], p1);
                atomicAdd(sA + i_local * 228 + bsv[mt][2], p2);
                atomicAdd(sA + i_local * 228 + bsv[mt][3], p3);
                pp0 = p0; pp1 = p1; pp2 = p2; pp3 = p3;
            }
            union { half4 v4; half2t hh[2]; } u;
            u.hh[0] = __builtin_amdgcn_cvt_pkrtz(pp0, pp1);
            u.hh[1] = __builtin_amdgcn_cvt_pkrtz(pp2, pp3);
            *(half4*)(pw + li * 72 + mt * 16 + jrb) = u.v4;
        }
        // PV: O^T += V^T . P^T
        {
            f16* vb = sVT + g2 * 2304;
            const int sw0 = (li >> 3) << 4;
#pragma unroll
            for (int ks = 0; ks < 2; ++ks) {
                half8 bP  = *(const half8*)(pw + li * 72 + ks * 32 + 8 * g);
                half8 aV0 = *(const half8*)(vb + li * 72        + ((ks * 32 + 8 * g) ^ sw0));
                half8 aV1 = *(const half8*)(vb + (16 + li) * 72 + ((ks * 32 + 8 * g) ^ sw0));
                o0 = __builtin_amdgcn_mfma_f32_16x16x32_f16(aV0, bP, o0, 0, 0, 0);
                o1 = __builtin_amdgcn_mfma_f32_16x16x32_f16(aV1, bP, o1, 0, 0, 0);
            }
        }
    }

    // -------- epilogue --------
    // per-i z partial (sum over g lanes)
    z += __shfl_xor(z, 16);
    z += __shfl_xor(z, 32);
    if (g == 0) sZ[g2 * 64 + i_local] = z;
    __syncthreads();   // #E1: last PV reads of sP done; sZ written
    if (g2 == 1) {     // group 1 deposits its partial O
        float* ob = sO1 + i_local * 36;
#pragma unroll
        for (int r = 0; r < 4; ++r) {
            ob[jrb + r] = o0[r];
            ob[16 + jrb + r] = o1[r];
        }
    }
    // stage rvT[d][l] (stride 264, zero-pad l>=225) into sTK area
    {
        int d = tid & 31;
        for (int l = tid >> 5; l < 264; l += 16) {
            float val = (l < Ll) ? rpev[((size_t)h * Ll + l) * HDd + d] : 0.f;
            sRVT[d * 264 + l] = (f16)val;
        }
    }
    __syncthreads();   // #E2
    if (g2 == 0) {
        float Zi = sZ[i_local] + sZ[64 + i_local];
        float rz = 1.0f / Zi;
        const float* ob = sO1 + i_local * 36;
#pragma unroll
        for (int r = 0; r < 4; ++r) {
            o0[r] += ob[jrb + r];
            o1[r] += ob[16 + jrb + r];
        }
        o0 *= rz; o1 *= rz;
#pragma unroll
        for (int ks = 0; ks < 8; ++ks) {
            union { half8 v8; half2t hh[4]; } u;
            if (ks < 7) {
                float4v a0 = *(const float4v*)(sA + i_local * 228 + ks * 32 + 8 * g);
                float4v a1 = *(const float4v*)(sA + i_local * 228 + ks * 32 + 8 * g + 4);
                u.hh[0] = __builtin_amdgcn_cvt_pkrtz(a0[0] * rz, a0[1] * rz);
                u.hh[1] = __builtin_amdgcn_cvt_pkrtz(a0[2] * rz, a0[3] * rz);
                u.hh[2] = __builtin_amdgcn_cvt_pkrtz(a1[0] * rz, a1[1] * rz);
                u.hh[3] = __builtin_amdgcn_cvt_pkrtz(a1[2] * rz, a1[3] * rz);
            } else {
                half2t z2; z2[0] = (f16)0.f; z2[1] = (f16)0.f;
                u.hh[0] = z2; u.hh[1] = z2; u.hh[2] = z2; u.hh[3] = z2;
                if (g == 0) {
                    float4v a0 = *(const float4v*)(sA + i_local * 228 + 224);
                    u.hh[0] = __builtin_amdgcn_cvt_pkrtz(a0[0] * rz, a0[1] * rz);
                    u.hh[1] = __builtin_amdgcn_cvt_pkrtz(a0[2] * rz, a0[3] * rz);
                }
            }
            half8 aR0 = *(const half8*)(sRVT + li * 264 + ks * 32 + 8 * g);
            half8 aR1 = *(const half8*)(sRVT + (16 + li) * 264 + ks * 32 + 8 * g);
            o0 = __builtin_amdgcn_mfma_f32_16x16x32_f16(aR0, u.v8, o0, 0, 0, 0);
            o1 = __builtin_amdgcn_mfma_f32_16x16x32_f16(aR1, u.v8, o1, 0, 0, 0);
        }
        // ctx layout: [bh][d][n]
        float* cbase = ctx + (size_t)bh * 32 * 1024 + i0 + i_local;
#pragma unroll
        for (int r = 0; r < 4; ++r) {
            cbase[(size_t)(jrb + r) * 1024]      = o0[r];
            cbase[(size_t)(16 + jrb + r) * 1024] = o1[r];
        }
    }
}

// ---------------- K3: partial mean over tokens ----------------
__global__ __launch_bounds__(256) void reduce_partial(const float* __restrict__ ctx,
                                                      const float* __restrict__ x,
                                                      float* __restrict__ pcm,
                                                      float* __restrict__ pxm) {
    int b = blockIdx.x >> 4, s = blockIdx.x & 15;
    int c = threadIdx.x;
    const float* crow = ctx + ((size_t)(b * 8 + (c >> 5)) * 32 + (c & 31)) * 1024 + s * 64;
    float sc = 0.f, sx = 0.f;
    for (int n = 0; n < 64; ++n) {
        sc += crow[n];
        sx += x[((size_t)b * Nn + s * 64 + n) * Cc + c];
    }
    pcm[(size_t)blockIdx.x * 256 + c] = sc;
    pxm[(size_t)blockIdx.x * 256 + c] = sx;
}

// ---------------- K4: final proj(mean) + residual-mean + fc ----------------
__global__ __launch_bounds__(256) void final_kernel(const float* __restrict__ pcm,
                                                    const float* __restrict__ pxm,
                                                    const float* __restrict__ pw,
                                                    const float* __restrict__ pb,
                                                    const float* __restrict__ fcw,
                                                    const float* __restrict__ fcb,
                                                    float* __restrict__ out) {
    __shared__ float cm[256], xm[256], mrow[256];
    int b = blockIdx.x;
    int c = threadIdx.x;
    float sc = 0.f, sx = 0.f;
    for (int s2 = 0; s2 < 16; ++s2) {
        sc += pcm[((size_t)b * 16 + s2) * 256 + c];
        sx += pxm[((size_t)b * 16 + s2) * 256 + c];
    }
    cm[c] = sc * (1.f / 1024.f);
    xm[c] = sx * (1.f / 1024.f);
    __syncthreads();
    float acc = pb[c] + xm[c];
    for (int c2 = 0; c2 < 256; ++c2) acc = fmaf(cm[c2], pw[(size_t)c * 256 + c2], acc);
    mrow[c] = acc;
    __syncthreads();
    if (c < 15) {
        float a2 = fcb[c];
        for (int c2 = 0; c2 < 256; ++c2) a2 = fmaf(mrow[c2], fcw[(size_t)c * 256 + c2], a2);
        out[b * 15 + c] = a2;
    }
}

extern "C" void kernel_launch(void* const* d_in, const int* in_sizes, int n_in,
                              void* d_out, int out_size, void* d_ws, size_t ws_size,
                              hipStream_t stream) {
    const float* x     = (const float*)d_in[0];
    const float* qkv_w = (const float*)d_in[1];
    const float* pw    = (const float*)d_in[2];
    const float* pb    = (const float*)d_in[3];
    const float* fcw   = (const float*)d_in[4];
    const float* fcb   = (const float*)d_in[5];
    const float* rpek  = (const float*)d_in[6];
    const float* rpeq  = (const float*)d_in[7];
    const float* rpev  = (const float*)d_in[8];
    float* out = (float*)d_out;

    const size_t QW = (size_t)Bq * Hh * Nn * HDd;  // 2,097,152
    float* wsf = (float*)d_ws;
    float* q   = wsf;
    float* kk  = q + QW;
    float* vv  = kk + QW;
    float* ctx = vv + QW;
    float* pcm = ctx + QW;
    float* pxm = pcm + 32768;

    hipFuncSetAttribute((const void*)attn_mfma,
                        hipFuncAttributeMaxDynamicSharedMemorySize, SMEM_BYTES);

    qkv_gemm<<<dim3(12, 128), 256, 0, stream>>>(x, qkv_w, q, kk, vv);
    attn_mfma<<<1024, 512, SMEM_BYTES, stream>>>(q, kk, vv, rpek, rpeq, rpev, ctx);
    reduce_partial<<<128, 256, 0, stream>>>(ctx, x, pcm, pxm);
    final_kernel<<<8, 256, 0, stream>>>(pcm, pxm, pw, pb, fcw, fcb, out);
}

// Round 5
// 517.669 us; speedup vs baseline: 2.8254x; 1.0585x over previous
//
#include <hip/hip_runtime.h>
#include <math.h>

#define Bq 8
#define Nn 1024
#define Cc 256
#define Hh 8
#define HDd 32
#define Ll 225
#define SCALE 0.17677669529663687f
#define LOG2E 1.44269504088896f
#define THRr 8.0f

typedef __fp16 f16;
typedef __fp16 half8 __attribute__((ext_vector_type(8)));
typedef __fp16 half4 __attribute__((ext_vector_type(4)));
typedef __fp16 half2t __attribute__((ext_vector_type(2)));
typedef float float4v __attribute__((ext_vector_type(4)));

// ---------------- K1: QKV projection (tiled SGEMM, f32) ----------------
__global__ __launch_bounds__(256) void qkv_gemm(const float* __restrict__ x,
                                                const float* __restrict__ w,
                                                float* __restrict__ q,
                                                float* __restrict__ k,
                                                float* __restrict__ v) {
    __shared__ float As[16][65];
    __shared__ float Bs[16][65];
    const int tix = threadIdx.x;
    const int tx = tix & 15, ty = tix >> 4;
    const int row0 = blockIdx.y * 64;
    const int col0 = blockIdx.x * 64;
    float acc[4][4] = {};
    for (int k0 = 0; k0 < Cc; k0 += 16) {
#pragma unroll
        for (int r = 0; r < 4; ++r) {
            int idx = tix + r * 256;
            int m = idx >> 4, kk = idx & 15;
            As[kk][m] = x[(size_t)(row0 + m) * Cc + k0 + kk];
            Bs[kk][m] = w[(size_t)(col0 + m) * Cc + k0 + kk];
        }
        __syncthreads();
#pragma unroll
        for (int kk = 0; kk < 16; ++kk) {
            float a[4], b[4];
#pragma unroll
            for (int i = 0; i < 4; ++i) a[i] = As[kk][ty * 4 + i];
#pragma unroll
            for (int j = 0; j < 4; ++j) b[j] = Bs[kk][tx * 4 + j];
#pragma unroll
            for (int i = 0; i < 4; ++i)
#pragma unroll
                for (int j = 0; j < 4; ++j) acc[i][j] = fmaf(a[i], b[j], acc[i][j]);
        }
        __syncthreads();
    }
#pragma unroll
    for (int i = 0; i < 4; ++i) {
        int row = row0 + ty * 4 + i;
        int b = row >> 10, n = row & 1023;
#pragma unroll
        for (int j = 0; j < 4; ++j) {
            int oc = col0 + tx * 4 + j;
            int which = oc >> 8;
            int h = (oc >> 5) & 7;
            int d = oc & 31;
            float* dst = (which == 0) ? q : ((which == 1) ? k : v);
            dst[(((size_t)b * Hh + h) * Nn + n) * HDd + d] = acc[i][j];
        }
    }
}

// ---------------- K2: fused iRPE attention, MFMA f16, 8 waves ----------------
// LDS layout (bytes):
//  sRQ  f16[240][40]  @0       19200  (rpek, then SCALE*LOG2E*rpeq)
//  sTK  f16[64][226]  @19200   28928  (tk table; rvT f16[32][264] aliases post-loop)
//  sA   f32[64][228]  @48128   58368  (absolute-scale exp2(S) accumulation)
//  sK   f16[2][64][40]@106496  10240
//  sVT  f16[2][32][72]@116736  9216   (column bit4 XOR-swizzled by (d>>3)&1)
//  sTQT f16[2][64][68]@125952  17408  (per-tile tq window, [slot][j])
//  sP   f16[8][16][72]@143360  18432  (sQ f16[64][40] + sO1 f32[64][36] alias)
//  sM   f32[2][64]    @161792  512    (epilogue m exchange)
//  sZ   f32[2][64]    @162304  512    total 162816
#define OFF_RQ   0
#define OFF_TK   19200
#define OFF_A    48128
#define OFF_K    106496
#define OFF_VT   116736
#define OFF_TQT  125952
#define OFF_P    143360
#define OFF_M    161792
#define OFF_Z    162304
#define SMEM_BYTES 162816

__device__ __forceinline__ int iclamp7(int x) {
    return x < -7 ? -7 : (x > 7 ? 7 : x);
}

__global__ __launch_bounds__(512, 2) void attn_mfma(
    const float* __restrict__ q, const float* __restrict__ k, const float* __restrict__ v,
    const float* __restrict__ rpek, const float* __restrict__ rpeq, const float* __restrict__ rpev,
    float* __restrict__ ctx)
{
    extern __shared__ char smem[];
    f16*   sRQ  = (f16*)(smem + OFF_RQ);
    f16*   sTK  = (f16*)(smem + OFF_TK);
    float* sA   = (float*)(smem + OFF_A);
    f16*   sK   = (f16*)(smem + OFF_K);
    f16*   sVT  = (f16*)(smem + OFF_VT);
    f16*   sTQT = (f16*)(smem + OFF_TQT);
    f16*   sP   = (f16*)(smem + OFF_P);
    f16*   sQ   = (f16*)(smem + OFF_P);     // alias: prologue only
    float* sO1  = (float*)(smem + OFF_P);   // alias: epilogue only
    f16*   sRVT = (f16*)(smem + OFF_TK);    // alias: epilogue only
    float* sM   = (float*)(smem + OFF_M);
    float* sZ   = (float*)(smem + OFF_Z);

    const int tid = threadIdx.x;
    const int lane = tid & 63;
    const int w = tid >> 6;      // 0..7
    const int wl = w & 3;        // wave within group
    const int g2 = w >> 2;       // j-tile group
    const int li = lane & 15;
    const int g = lane >> 4;
    const int blk = blockIdx.x;
    const int bh = blk >> 4;
    const int h = bh & 7;
    const int i0 = (blk & 15) << 6;
    const int i_local = wl * 16 + li;
    const int i_glob = i0 + i_local;
    const int ri = i_glob >> 5, ci = i_glob & 31;
    const int ciA = ci - 4 * g;
    const int jrb = 4 * g;
    const int Ri = i0 >> 5;
    const size_t kvbase = (size_t)bh * (Nn * HDd);

    // staging ids (512 threads stage 128 rows of K and V)
    const int sg  = tid >> 8;          // staging group
    const int sr  = (tid >> 2) & 63;   // row in tile
    const int sq4 = tid & 3;
    const int sd0 = sq4 * 8;
    const int vswz = (sq4 & 1) << 4;   // sVT column swizzle bit

    // zero sA
    {
        float4v zz = {0.f, 0.f, 0.f, 0.f};
        for (int idx = tid; idx < 64 * 228 / 4; idx += 512)
            ((float4v*)sA)[idx] = zz;
    }
    // stage sQ (f32 -> f16, x LOG2E)
    if (tid < 256) {
        int row = tid >> 2, d0 = (tid & 3) * 8;
        const float4v* src = (const float4v*)(q + kvbase + (size_t)(i0 + row) * HDd + d0);
        float4v x0 = src[0], x1 = src[1];
        union { half8 v8; half2t hh[4]; } u;
        u.hh[0] = __builtin_amdgcn_cvt_pkrtz(x0[0] * LOG2E, x0[1] * LOG2E);
        u.hh[1] = __builtin_amdgcn_cvt_pkrtz(x0[2] * LOG2E, x0[3] * LOG2E);
        u.hh[2] = __builtin_amdgcn_cvt_pkrtz(x1[0] * LOG2E, x1[1] * LOG2E);
        u.hh[3] = __builtin_amdgcn_cvt_pkrtz(x1[2] * LOG2E, x1[3] * LOG2E);
        *(half8*)(sQ + row * 40 + d0) = u.v8;
    }
    // stage sRQ = rpek[h] (plain; zero-pad rows 225..239)
    for (int idx = tid; idx < 960; idx += 512) {
        int row = idx >> 2, d0 = (idx & 3) * 8;
        union { half8 v8; half2t hh[4]; } u;
        if (row < Ll) {
            const float4v* src = (const float4v*)(rpek + ((size_t)h * Ll + row) * HDd + d0);
            float4v x0 = src[0], x1 = src[1];
            u.hh[0] = __builtin_amdgcn_cvt_pkrtz(x0[0], x0[1]);
            u.hh[1] = __builtin_amdgcn_cvt_pkrtz(x0[2], x0[3]);
            u.hh[2] = __builtin_amdgcn_cvt_pkrtz(x1[0], x1[1]);
            u.hh[3] = __builtin_amdgcn_cvt_pkrtz(x1[2], x1[3]);
        } else {
            half2t z2; z2[0] = (f16)0.f; z2[1] = (f16)0.f;
            u.hh[0] = z2; u.hh[1] = z2; u.hh[2] = z2; u.hh[3] = z2;
        }
        *(half8*)(sRQ + row * 40 + d0) = u.v8;
    }
    __syncthreads();

    // Q fragments
    half8 aQ[4];
#pragma unroll
    for (int mt = 0; mt < 4; ++mt)
        aQ[mt] = *(const half8*)(sQ + (mt * 16 + li) * 40 + 8 * g);
    half8 bQ = *(const half8*)(sQ + i_local * 40 + 8 * g);

    // tk prologue: sTK[i][l] = (LOG2E q_i) . rpek_l ; 15 nt tiles over 8 waves
#pragma unroll
    for (int pass = 0; pass < 2; ++pass) {
        int nt = w + pass * 8;
        if (nt <= 14) {
            half8 bR = *(const half8*)(sRQ + (nt * 16 + li) * 40 + 8 * g);
            int l = nt * 16 + li;
#pragma unroll
            for (int mt = 0; mt < 4; ++mt) {
                float4v c = {0.f, 0.f, 0.f, 0.f};
                c = __builtin_amdgcn_mfma_f32_16x16x32_f16(aQ[mt], bR, c, 0, 0, 0);
                if (l < Ll) {
#pragma unroll
                    for (int r = 0; r < 4; ++r)
                        sTK[(mt * 16 + jrb + r) * 226 + l] = (f16)c[r];
                }
            }
        }
    }
    __syncthreads();
    // restage sRQ = SCALE*LOG2E * rpeq[h]
    for (int idx = tid; idx < 960; idx += 512) {
        int row = idx >> 2, d0 = (idx & 3) * 8;
        union { half8 v8; half2t hh[4]; } u;
        if (row < Ll) {
            const float4v* src = (const float4v*)(rpeq + ((size_t)h * Ll + row) * HDd + d0);
            float4v x0 = src[0], x1 = src[1];
            const float sc = SCALE * LOG2E;
            u.hh[0] = __builtin_amdgcn_cvt_pkrtz(x0[0] * sc, x0[1] * sc);
            u.hh[1] = __builtin_amdgcn_cvt_pkrtz(x0[2] * sc, x0[3] * sc);
            u.hh[2] = __builtin_amdgcn_cvt_pkrtz(x1[0] * sc, x1[1] * sc);
            u.hh[3] = __builtin_amdgcn_cvt_pkrtz(x1[2] * sc, x1[3] * sc);
        } else {
            half2t z2; z2[0] = (f16)0.f; z2[1] = (f16)0.f;
            u.hh[0] = z2; u.hh[1] = z2; u.hh[2] = z2; u.hh[3] = z2;
        }
        *(half8*)(sRQ + row * 40 + d0) = u.v8;
    }
    // prefetch tile 0 K/V into regs
    float4v kx0, kx1, vx0, vx1;
    {
        int j = sg * 64 + sr;
        const float4v* ks_ = (const float4v*)(k + kvbase + (size_t)j * HDd + sd0);
        kx0 = ks_[0]; kx1 = ks_[1];
        const float4v* vs_ = (const float4v*)(v + kvbase + (size_t)j * HDd + sd0);
        vx0 = vs_[0]; vx1 = vs_[1];
    }

    float4v o0 = {0.f, 0.f, 0.f, 0.f}, o1 = {0.f, 0.f, 0.f, 0.f};
    float z = 0.f, m_run = -1.0e30f, pw2m = 0.f;

    for (int it = 0; it < 8; ++it) {
        __syncthreads();   // #1: previous readers of sK/sVT/sTQT done; sRQ restage done (it=0)
        // stage K/V from prefetch regs
        {
            union { half8 v8; half2t hh[4]; } uk;
            uk.hh[0] = __builtin_amdgcn_cvt_pkrtz(kx0[0], kx0[1]);
            uk.hh[1] = __builtin_amdgcn_cvt_pkrtz(kx0[2], kx0[3]);
            uk.hh[2] = __builtin_amdgcn_cvt_pkrtz(kx1[0], kx1[1]);
            uk.hh[3] = __builtin_amdgcn_cvt_pkrtz(kx1[2], kx1[3]);
            *(half8*)(sK + sg * 2560 + sr * 40 + sd0) = uk.v8;
            f16* vb = sVT + sg * 2304;
            int colv = sr ^ vswz;
            vb[(sd0 + 0) * 72 + colv] = (f16)vx0[0];
            vb[(sd0 + 1) * 72 + colv] = (f16)vx0[1];
            vb[(sd0 + 2) * 72 + colv] = (f16)vx0[2];
            vb[(sd0 + 3) * 72 + colv] = (f16)vx0[3];
            vb[(sd0 + 4) * 72 + colv] = (f16)vx1[0];
            vb[(sd0 + 5) * 72 + colv] = (f16)vx1[1];
            vb[(sd0 + 6) * 72 + colv] = (f16)vx1[2];
            vb[(sd0 + 7) * 72 + colv] = (f16)vx1[3];
        }
        __syncthreads();   // #2: staging done
        if (it < 7) {      // prefetch next tile (overlaps all compute below)
            int j = (it + 1) * 128 + sg * 64 + sr;
            const float4v* ks_ = (const float4v*)(k + kvbase + (size_t)j * HDd + sd0);
            kx0 = ks_[0]; kx1 = ks_[1];
            const float4v* vs_ = (const float4v*)(v + kvbase + (size_t)j * HDd + sd0);
            vx0 = vs_[0]; vx1 = vs_[1];
        }
        const int j0 = it * 128 + g2 * 64;
        // K frags + S^T = K . Q^T
        half8 aK[4];
        {
            f16* sKg = sK + g2 * 2560;
#pragma unroll
            for (int mt = 0; mt < 4; ++mt)
                aK[mt] = *(const half8*)(sKg + (mt * 16 + li) * 40 + 8 * g);
        }
        float4v sacc[4];
#pragma unroll
        for (int mt = 0; mt < 4; ++mt) {
            float4v c = {0.f, 0.f, 0.f, 0.f};
            sacc[mt] = __builtin_amdgcn_mfma_f32_16x16x32_f16(aK[mt], bQ, c, 0, 0, 0);
        }
        // tq window: only l' in [w0, w0+64) reachable this tile
        const int dC = Ri - (j0 >> 5);
        const int drmax = iclamp7(dC + 1), drmin = iclamp7(dC - 1);
        const int w0 = ((7 - drmax) * 15) & ~15;
        const int lpmax = (7 - drmin) * 15 + 14;
        {
            int nt = (w0 >> 4) + wl;
            if (nt * 16 <= lpmax) {
                half8 bR = *(const half8*)(sRQ + (nt * 16 + li) * 40 + 8 * g);
                int slot = nt * 16 + li - w0;
                f16* tbase = sTQT + g2 * 4352 + slot * 68;
#pragma unroll
                for (int mt = 0; mt < 4; ++mt) {
                    float4v c = {0.f, 0.f, 0.f, 0.f};
                    c = __builtin_amdgcn_mfma_f32_16x16x32_f16(aK[mt], bR, c, 0, 0, 0);
                    union { half4 v4; half2t hh[2]; } u;
                    u.hh[0] = __builtin_amdgcn_cvt_pkrtz(c[0], c[1]);
                    u.hh[1] = __builtin_amdgcn_cvt_pkrtz(c[2], c[3]);
                    *(half4*)(tbase + mt * 16 + jrb) = u.v4;
                }
            }
        }
        // group-local raw-S per-i max (bias folded into THR headroom)
        float mloc = -1.0e30f;
#pragma unroll
        for (int mt = 0; mt < 4; ++mt)
#pragma unroll
            for (int r = 0; r < 4; ++r) mloc = fmaxf(mloc, sacc[mt][r]);
        mloc = fmaxf(mloc, __shfl_xor(mloc, 16));
        mloc = fmaxf(mloc, __shfl_xor(mloc, 32));
        // defer-max update (no cross-group coupling; A is absolute-scale)
        if (mloc > m_run + THRr) {
            float f = exp2f(m_run - mloc);
            m_run = mloc;
            pw2m = exp2f(m_run);
            z *= f; o0 *= f; o1 *= f;
        }
        __syncthreads();   // #3: sTQT ready
        // gather biases, finalize s
        const int drA = iclamp7(ri - (j0 >> 5));
        const int drB = iclamp7(ri - (j0 >> 5) - 1);
        int bsv[4][4];
        {
            f16* tqt = sTQT + g2 * 4352;
            const f16* tkrow = sTK + i_local * 226;
#pragma unroll
            for (int mt = 0; mt < 4; ++mt) {
                const int dr = (mt < 2) ? drA : drB;
                const int cb = ciA - ((mt & 1) << 4);
#pragma unroll
                for (int r = 0; r < 4; ++r) {
                    int dc = iclamp7(cb - r);
                    int b = dr * 15 + dc + 112;
                    bsv[mt][r] = b;
                    float tkv = (float)tkrow[b];
                    float tqv = (float)tqt[(224 - b - w0) * 68 + (mt * 16 + jrb + r)];
                    sacc[mt][r] += tkv + tqv;
                }
            }
        }
        // exp + absolute-scale A-scatter (native ds_add_f32) + P pack
        f16* pw = sP + w * 1152;
#pragma unroll
        for (int mt = 0; mt < 4; ++mt) {
            float p0 = exp2f(sacc[mt][0] - m_run);
            float p1 = exp2f(sacc[mt][1] - m_run);
            float p2 = exp2f(sacc[mt][2] - m_run);
            float p3 = exp2f(sacc[mt][3] - m_run);
            z += p0 + p1 + p2 + p3;
            float* arow = sA + i_local * 228;
            unsafeAtomicAdd(arow + bsv[mt][0], p0 * pw2m);
            unsafeAtomicAdd(arow + bsv[mt][1], p1 * pw2m);
            unsafeAtomicAdd(arow + bsv[mt][2], p2 * pw2m);
            unsafeAtomicAdd(arow + bsv[mt][3], p3 * pw2m);
            union { half4 v4; half2t hh[2]; } u;
            u.hh[0] = __builtin_amdgcn_cvt_pkrtz(p0, p1);
            u.hh[1] = __builtin_amdgcn_cvt_pkrtz(p2, p3);
            *(half4*)(pw + li * 72 + mt * 16 + jrb) = u.v4;
        }
        // PV: O^T += V^T . P^T
        {
            f16* vb = sVT + g2 * 2304;
            const int sw0 = (li >> 3) << 4;
#pragma unroll
            for (int ks = 0; ks < 2; ++ks) {
                half8 bP  = *(const half8*)(pw + li * 72 + ks * 32 + 8 * g);
                half8 aV0 = *(const half8*)(vb + li * 72        + ((ks * 32 + 8 * g) ^ sw0));
                half8 aV1 = *(const half8*)(vb + (16 + li) * 72 + ((ks * 32 + 8 * g) ^ sw0));
                o0 = __builtin_amdgcn_mfma_f32_16x16x32_f16(aV0, bP, o0, 0, 0, 0);
                o1 = __builtin_amdgcn_mfma_f32_16x16x32_f16(aV1, bP, o1, 0, 0, 0);
            }
        }
    }

    // -------- epilogue --------
    // per-i z partial (sum over g lanes); exchange per-group (m, z)
    z += __shfl_xor(z, 16);
    z += __shfl_xor(z, 32);
    if (g == 0) {
        sM[g2 * 64 + i_local] = m_run;
        sZ[g2 * 64 + i_local] = z;
    }
    __syncthreads();   // #E1: last PV reads of sP done; sM/sZ written
    if (g2 == 1) {     // group 1 deposits its partial O (own-m scale)
        float* ob = sO1 + i_local * 36;
#pragma unroll
        for (int r = 0; r < 4; ++r) {
            ob[jrb + r] = o0[r];
            ob[16 + jrb + r] = o1[r];
        }
    }
    // stage rvT[d][l] (stride 264, zero-pad l>=225) into sTK area
    {
        int d = tid & 31;
        for (int l = tid >> 5; l < 264; l += 16) {
            float val = (l < Ll) ? rpev[((size_t)h * Ll + l) * HDd + d] : 0.f;
            sRVT[d * 264 + l] = (f16)val;
        }
    }
    __syncthreads();   // #E2
    if (g2 == 0) {
        float m0 = sM[i_local], m1 = sM[64 + i_local];
        float ms = fmaxf(m0, m1);
        float f0 = exp2f(m0 - ms), f1 = exp2f(m1 - ms);
        float zst = sZ[i_local] * f0 + sZ[64 + i_local] * f1;
        float rz = 1.0f / zst;
        float rzA = rz * exp2f(-ms);
        const float* ob = sO1 + i_local * 36;
#pragma unroll
        for (int r = 0; r < 4; ++r) {
            o0[r] = (o0[r] * f0 + ob[jrb + r] * f1) * rz;
            o1[r] = (o1[r] * f0 + ob[16 + jrb + r] * f1) * rz;
        }
#pragma unroll
        for (int ks = 0; ks < 8; ++ks) {
            union { half8 v8; half2t hh[4]; } u;
            if (ks < 7) {
                float4v a0 = *(const float4v*)(sA + i_local * 228 + ks * 32 + 8 * g);
                float4v a1 = *(const float4v*)(sA + i_local * 228 + ks * 32 + 8 * g + 4);
                u.hh[0] = __builtin_amdgcn_cvt_pkrtz(a0[0] * rzA, a0[1] * rzA);
                u.hh[1] = __builtin_amdgcn_cvt_pkrtz(a0[2] * rzA, a0[3] * rzA);
                u.hh[2] = __builtin_amdgcn_cvt_pkrtz(a1[0] * rzA, a1[1] * rzA);
                u.hh[3] = __builtin_amdgcn_cvt_pkrtz(a1[2] * rzA, a1[3] * rzA);
            } else {
                half2t z2; z2[0] = (f16)0.f; z2[1] = (f16)0.f;
                u.hh[0] = z2; u.hh[1] = z2; u.hh[2] = z2; u.hh[3] = z2;
                if (g == 0) {
                    float4v a0 = *(const float4v*)(sA + i_local * 228 + 224);
                    u.hh[0] = __builtin_amdgcn_cvt_pkrtz(a0[0] * rzA, a0[1] * rzA);
                    u.hh[1] = __builtin_amdgcn_cvt_pkrtz(a0[2] * rzA, a0[3] * rzA);
                }
            }
            half8 aR0 = *(const half8*)(sRVT + li * 264 + ks * 32 + 8 * g);
            half8 aR1 = *(const half8*)(sRVT + (16 + li) * 264 + ks * 32 + 8 * g);
            o0 = __builtin_amdgcn_mfma_f32_16x16x32_f16(aR0, u.v8, o0, 0, 0, 0);
            o1 = __builtin_amdgcn_mfma_f32_16x16x32_f16(aR1, u.v8, o1, 0, 0, 0);
        }
        // ctx layout: [bh][d][n]
        float* cbase = ctx + (size_t)bh * 32 * 1024 + i0 + i_local;
#pragma unroll
        for (int r = 0; r < 4; ++r) {
            cbase[(size_t)(jrb + r) * 1024]      = o0[r];
            cbase[(size_t)(16 + jrb + r) * 1024] = o1[r];
        }
    }
}

// ---------------- K3: partial mean over tokens ----------------
__global__ __launch_bounds__(256) void reduce_partial(const float* __restrict__ ctx,
                                                      const float* __restrict__ x,
                                                      float* __restrict__ pcm,
                                                      float* __restrict__ pxm) {
    int b = blockIdx.x >> 4, s = blockIdx.x & 15;
    int c = threadIdx.x;
    const float* crow = ctx + ((size_t)(b * 8 + (c >> 5)) * 32 + (c & 31)) * 1024 + s * 64;
    float sc = 0.f, sx = 0.f;
    for (int n = 0; n < 64; ++n) {
        sc += crow[n];
        sx += x[((size_t)b * Nn + s * 64 + n) * Cc + c];
    }
    pcm[(size_t)blockIdx.x * 256 + c] = sc;
    pxm[(size_t)blockIdx.x * 256 + c] = sx;
}

// ---------------- K4: final proj(mean) + residual-mean + fc ----------------
__global__ __launch_bounds__(256) void final_kernel(const float* __restrict__ pcm,
                                                    const float* __restrict__ pxm,
                                                    const float* __restrict__ pw,
                                                    const float* __restrict__ pb,
                                                    const float* __restrict__ fcw,
                                                    const float* __restrict__ fcb,
                                                    float* __restrict__ out) {
    __shared__ float cm[256], xm[256], mrow[256];
    int b = blockIdx.x;
    int c = threadIdx.x;
    float sc = 0.f, sx = 0.f;
    for (int s2 = 0; s2 < 16; ++s2) {
        sc += pcm[((size_t)b * 16 + s2) * 256 + c];
        sx += pxm[((size_t)b * 16 + s2) * 256 + c];
    }
    cm[c] = sc * (1.f / 1024.f);
    xm[c] = sx * (1.f / 1024.f);
    __syncthreads();
    float acc = pb[c] + xm[c];
    for (int c2 = 0; c2 < 256; ++c2) acc = fmaf(cm[c2], pw[(size_t)c * 256 + c2], acc);
    mrow[c] = acc;
    __syncthreads();
    if (c < 15) {
        float a2 = fcb[c];
        for (int c2 = 0; c2 < 256; ++c2) a2 = fmaf(mrow[c2], fcw[(size_t)c * 256 + c2], a2);
        out[b * 15 + c] = a2;
    }
}

extern "C" void kernel_launch(void* const* d_in, const int* in_sizes, int n_in,
                              void* d_out, int out_size, void* d_ws, size_t ws_size,
                              hipStream_t stream) {
    const float* x     = (const float*)d_in[0];
    const float* qkv_w = (const float*)d_in[1];
    const float* pw    = (const float*)d_in[2];
    const float* pb    = (const float*)d_in[3];
    const float* fcw   = (const float*)d_in[4];
    const float* fcb   = (const float*)d_in[5];
    const float* rpek  = (const float*)d_in[6];
    const float* rpeq  = (const float*)d_in[7];
    const float* rpev  = (const float*)d_in[8];
    float* out = (float*)d_out;

    const size_t QW = (size_t)Bq * Hh * Nn * HDd;  // 2,097,152
    float* wsf = (float*)d_ws;
    float* q   = wsf;
    float* kk  = q + QW;
    float* vv  = kk + QW;
    float* ctx = vv + QW;
    float* pcm = ctx + QW;
    float* pxm = pcm + 32768;

    hipFuncSetAttribute((const void*)attn_mfma,
                        hipFuncAttributeMaxDynamicSharedMemorySize, SMEM_BYTES);

    qkv_gemm<<<dim3(12, 128), 256, 0, stream>>>(x, qkv_w, q, kk, vv);
    attn_mfma<<<1024, 512, SMEM_BYTES, stream>>>(q, kk, vv, rpek, rpeq, rpev, ctx);
    reduce_partial<<<128, 256, 0, stream>>>(ctx, x, pcm, pxm);
    final_kernel<<<8, 256, 0, stream>>>(pcm, pxm, pw, pb, fcw, fcb, out);
}

// Round 6
// 515.892 us; speedup vs baseline: 2.8351x; 1.0034x over previous
//
#include <hip/hip_runtime.h>
#include <math.h>

#define Bq 8
#define Nn 1024
#define Cc 256
#define Hh 8
#define HDd 32
#define Ll 225
#define SCALE 0.17677669529663687f
#define LOG2E 1.44269504088896f
#define THRr 8.0f

typedef __fp16 f16;
typedef __fp16 half8 __attribute__((ext_vector_type(8)));
typedef __fp16 half4 __attribute__((ext_vector_type(4)));
typedef __fp16 half2t __attribute__((ext_vector_type(2)));
typedef float float4v __attribute__((ext_vector_type(4)));

// ---------------- K1: QKV projection (tiled SGEMM, f32) ----------------
__global__ __launch_bounds__(256) void qkv_gemm(const float* __restrict__ x,
                                                const float* __restrict__ w,
                                                float* __restrict__ q,
                                                float* __restrict__ k,
                                                float* __restrict__ v) {
    __shared__ float As[16][65];
    __shared__ float Bs[16][65];
    const int tix = threadIdx.x;
    const int tx = tix & 15, ty = tix >> 4;
    const int row0 = blockIdx.y * 64;
    const int col0 = blockIdx.x * 64;
    float acc[4][4] = {};
    for (int k0 = 0; k0 < Cc; k0 += 16) {
#pragma unroll
        for (int r = 0; r < 4; ++r) {
            int idx = tix + r * 256;
            int m = idx >> 4, kk = idx & 15;
            As[kk][m] = x[(size_t)(row0 + m) * Cc + k0 + kk];
            Bs[kk][m] = w[(size_t)(col0 + m) * Cc + k0 + kk];
        }
        __syncthreads();
#pragma unroll
        for (int kk = 0; kk < 16; ++kk) {
            float a[4], b[4];
#pragma unroll
            for (int i = 0; i < 4; ++i) a[i] = As[kk][ty * 4 + i];
#pragma unroll
            for (int j = 0; j < 4; ++j) b[j] = Bs[kk][tx * 4 + j];
#pragma unroll
            for (int i = 0; i < 4; ++i)
#pragma unroll
                for (int j = 0; j < 4; ++j) acc[i][j] = fmaf(a[i], b[j], acc[i][j]);
        }
        __syncthreads();
    }
#pragma unroll
    for (int i = 0; i < 4; ++i) {
        int row = row0 + ty * 4 + i;
        int b = row >> 10, n = row & 1023;
#pragma unroll
        for (int j = 0; j < 4; ++j) {
            int oc = col0 + tx * 4 + j;
            int which = oc >> 8;
            int h = (oc >> 5) & 7;
            int d = oc & 31;
            float* dst = (which == 0) ? q : ((which == 1) ? k : v);
            dst[(((size_t)b * Hh + h) * Nn + n) * HDd + d] = acc[i][j];
        }
    }
}

// ---------------- K2: fused iRPE attention, MFMA f16, 8 waves ----------------
#define OFF_RQ   0
#define OFF_TK   19200
#define OFF_A    48128
#define OFF_K    106496
#define OFF_VT   116736
#define OFF_TQT  125952
#define OFF_P    143360
#define OFF_M    161792
#define OFF_Z    162304
#define SMEM_BYTES 162816

__device__ __forceinline__ int iclamp7(int x) {
    return x < -7 ? -7 : (x > 7 ? 7 : x);
}

__global__ __launch_bounds__(512, 2) __attribute__((amdgpu_waves_per_eu(2, 2)))
void attn_mfma(
    const float* __restrict__ q, const float* __restrict__ k, const float* __restrict__ v,
    const float* __restrict__ rpek, const float* __restrict__ rpeq, const float* __restrict__ rpev,
    float* __restrict__ ctx)
{
    extern __shared__ char smem[];
    f16*   sRQ  = (f16*)(smem + OFF_RQ);
    f16*   sTK  = (f16*)(smem + OFF_TK);
    float* sA   = (float*)(smem + OFF_A);
    f16*   sK   = (f16*)(smem + OFF_K);
    f16*   sVT  = (f16*)(smem + OFF_VT);
    f16*   sTQT = (f16*)(smem + OFF_TQT);
    f16*   sP   = (f16*)(smem + OFF_P);
    f16*   sQ   = (f16*)(smem + OFF_P);     // alias: prologue only
    float* sO1  = (float*)(smem + OFF_P);   // alias: epilogue only
    f16*   sRVT = (f16*)(smem + OFF_TK);    // alias: epilogue only
    float* sM   = (float*)(smem + OFF_M);
    float* sZ   = (float*)(smem + OFF_Z);

    const int tid = threadIdx.x;
    const int lane = tid & 63;
    const int w = tid >> 6;      // 0..7
    const int wl = w & 3;        // wave within group
    const int g2 = w >> 2;       // j-tile group
    const int li = lane & 15;
    const int g = lane >> 4;
    const int blk = blockIdx.x;
    const int bh = blk >> 4;
    const int h = bh & 7;
    const int i0 = (blk & 15) << 6;
    const int i_local = wl * 16 + li;
    const int i_glob = i0 + i_local;
    const int ri = i_glob >> 5, ci = i_glob & 31;
    const int ciA = ci - 4 * g;
    const int jrb = 4 * g;
    const int Ri = i0 >> 5;
    const size_t kvbase = (size_t)bh * (Nn * HDd);

    // staging ids (512 threads stage 128 rows of K and V)
    const int sg  = tid >> 8;
    const int sr  = (tid >> 2) & 63;
    const int sq4 = tid & 3;
    const int sd0 = sq4 * 8;
    const int vswz = (sq4 & 1) << 4;

    // per-lane constant dc clamps (bucket = dr*15 + dcc + 112)
    int dcc[4][4];
#pragma unroll
    for (int mt = 0; mt < 4; ++mt) {
        const int cb = ciA - ((mt & 1) << 4);
#pragma unroll
        for (int r = 0; r < 4; ++r) dcc[mt][r] = iclamp7(cb - r);
    }

    // zero sA
    {
        float4v zz = {0.f, 0.f, 0.f, 0.f};
        for (int idx = tid; idx < 64 * 228 / 4; idx += 512)
            ((float4v*)sA)[idx] = zz;
    }
    // stage sQ (f32 -> f16, x LOG2E)
    if (tid < 256) {
        int row = tid >> 2, d0 = (tid & 3) * 8;
        const float4v* src = (const float4v*)(q + kvbase + (size_t)(i0 + row) * HDd + d0);
        float4v x0 = src[0], x1 = src[1];
        union { half8 v8; half2t hh[4]; } u;
        u.hh[0] = __builtin_amdgcn_cvt_pkrtz(x0[0] * LOG2E, x0[1] * LOG2E);
        u.hh[1] = __builtin_amdgcn_cvt_pkrtz(x0[2] * LOG2E, x0[3] * LOG2E);
        u.hh[2] = __builtin_amdgcn_cvt_pkrtz(x1[0] * LOG2E, x1[1] * LOG2E);
        u.hh[3] = __builtin_amdgcn_cvt_pkrtz(x1[2] * LOG2E, x1[3] * LOG2E);
        *(half8*)(sQ + row * 40 + d0) = u.v8;
    }
    // stage sRQ = rpek[h]
    for (int idx = tid; idx < 960; idx += 512) {
        int row = idx >> 2, d0 = (idx & 3) * 8;
        union { half8 v8; half2t hh[4]; } u;
        if (row < Ll) {
            const float4v* src = (const float4v*)(rpek + ((size_t)h * Ll + row) * HDd + d0);
            float4v x0 = src[0], x1 = src[1];
            u.hh[0] = __builtin_amdgcn_cvt_pkrtz(x0[0], x0[1]);
            u.hh[1] = __builtin_amdgcn_cvt_pkrtz(x0[2], x0[3]);
            u.hh[2] = __builtin_amdgcn_cvt_pkrtz(x1[0], x1[1]);
            u.hh[3] = __builtin_amdgcn_cvt_pkrtz(x1[2], x1[3]);
        } else {
            half2t z2; z2[0] = (f16)0.f; z2[1] = (f16)0.f;
            u.hh[0] = z2; u.hh[1] = z2; u.hh[2] = z2; u.hh[3] = z2;
        }
        *(half8*)(sRQ + row * 40 + d0) = u.v8;
    }
    __syncthreads();

    // Q fragments
    half8 aQ[4];
#pragma unroll
    for (int mt = 0; mt < 4; ++mt)
        aQ[mt] = *(const half8*)(sQ + (mt * 16 + li) * 40 + 8 * g);
    half8 bQ = *(const half8*)(sQ + i_local * 40 + 8 * g);

    // tk prologue
#pragma unroll
    for (int pass = 0; pass < 2; ++pass) {
        int nt = w + pass * 8;
        if (nt <= 14) {
            half8 bR = *(const half8*)(sRQ + (nt * 16 + li) * 40 + 8 * g);
            int l = nt * 16 + li;
#pragma unroll
            for (int mt = 0; mt < 4; ++mt) {
                float4v c = {0.f, 0.f, 0.f, 0.f};
                c = __builtin_amdgcn_mfma_f32_16x16x32_f16(aQ[mt], bR, c, 0, 0, 0);
                if (l < Ll) {
#pragma unroll
                    for (int r = 0; r < 4; ++r)
                        sTK[(mt * 16 + jrb + r) * 226 + l] = (f16)c[r];
                }
            }
        }
    }
    __syncthreads();
    // restage sRQ = SCALE*LOG2E * rpeq[h]
    for (int idx = tid; idx < 960; idx += 512) {
        int row = idx >> 2, d0 = (idx & 3) * 8;
        union { half8 v8; half2t hh[4]; } u;
        if (row < Ll) {
            const float4v* src = (const float4v*)(rpeq + ((size_t)h * Ll + row) * HDd + d0);
            float4v x0 = src[0], x1 = src[1];
            const float sc = SCALE * LOG2E;
            u.hh[0] = __builtin_amdgcn_cvt_pkrtz(x0[0] * sc, x0[1] * sc);
            u.hh[1] = __builtin_amdgcn_cvt_pkrtz(x0[2] * sc, x0[3] * sc);
            u.hh[2] = __builtin_amdgcn_cvt_pkrtz(x1[0] * sc, x1[1] * sc);
            u.hh[3] = __builtin_amdgcn_cvt_pkrtz(x1[2] * sc, x1[3] * sc);
        } else {
            half2t z2; z2[0] = (f16)0.f; z2[1] = (f16)0.f;
            u.hh[0] = z2; u.hh[1] = z2; u.hh[2] = z2; u.hh[3] = z2;
        }
        *(half8*)(sRQ + row * 40 + d0) = u.v8;
    }
    // prefetch tile 0 K/V into regs
    float4v kx0, kx1, vx0, vx1;
    {
        int j = sg * 64 + sr;
        const float4v* ks_ = (const float4v*)(k + kvbase + (size_t)j * HDd + sd0);
        kx0 = ks_[0]; kx1 = ks_[1];
        const float4v* vs_ = (const float4v*)(v + kvbase + (size_t)j * HDd + sd0);
        vx0 = vs_[0]; vx1 = vs_[1];
    }

    float4v o0 = {0.f, 0.f, 0.f, 0.f}, o1 = {0.f, 0.f, 0.f, 0.f};
    float z = 0.f, m_run = -1.0e30f, pw2m = 0.f;

    for (int it = 0; it < 8; ++it) {
        __syncthreads();   // #1
        // stage K/V from prefetch regs
        {
            union { half8 v8; half2t hh[4]; } uk;
            uk.hh[0] = __builtin_amdgcn_cvt_pkrtz(kx0[0], kx0[1]);
            uk.hh[1] = __builtin_amdgcn_cvt_pkrtz(kx0[2], kx0[3]);
            uk.hh[2] = __builtin_amdgcn_cvt_pkrtz(kx1[0], kx1[1]);
            uk.hh[3] = __builtin_amdgcn_cvt_pkrtz(kx1[2], kx1[3]);
            *(half8*)(sK + sg * 2560 + sr * 40 + sd0) = uk.v8;
            f16* vb = sVT + sg * 2304;
            int colv = sr ^ vswz;
            vb[(sd0 + 0) * 72 + colv] = (f16)vx0[0];
            vb[(sd0 + 1) * 72 + colv] = (f16)vx0[1];
            vb[(sd0 + 2) * 72 + colv] = (f16)vx0[2];
            vb[(sd0 + 3) * 72 + colv] = (f16)vx0[3];
            vb[(sd0 + 4) * 72 + colv] = (f16)vx1[0];
            vb[(sd0 + 5) * 72 + colv] = (f16)vx1[1];
            vb[(sd0 + 6) * 72 + colv] = (f16)vx1[2];
            vb[(sd0 + 7) * 72 + colv] = (f16)vx1[3];
        }
        __syncthreads();   // #2
        const int j0 = it * 128 + g2 * 64;
        // K frags + S^T = K . Q^T
        half8 aK[4];
        {
            f16* sKg = sK + g2 * 2560;
#pragma unroll
            for (int mt = 0; mt < 4; ++mt)
                aK[mt] = *(const half8*)(sKg + (mt * 16 + li) * 40 + 8 * g);
        }
        float4v sacc[4];
#pragma unroll
        for (int mt = 0; mt < 4; ++mt) {
            float4v c = {0.f, 0.f, 0.f, 0.f};
            sacc[mt] = __builtin_amdgcn_mfma_f32_16x16x32_f16(aK[mt], bQ, c, 0, 0, 0);
        }
        // tq window
        const int dC = Ri - (j0 >> 5);
        const int drmax = iclamp7(dC + 1), drmin = iclamp7(dC - 1);
        const int w0 = ((7 - drmax) * 15) & ~15;
        const int lpmax = (7 - drmin) * 15 + 14;
        {
            int nt = (w0 >> 4) + wl;
            if (nt * 16 <= lpmax) {
                half8 bR = *(const half8*)(sRQ + (nt * 16 + li) * 40 + 8 * g);
                int slot = nt * 16 + li - w0;
                f16* tbase = sTQT + g2 * 4352 + slot * 68;
#pragma unroll
                for (int mt = 0; mt < 4; ++mt) {
                    float4v c = {0.f, 0.f, 0.f, 0.f};
                    c = __builtin_amdgcn_mfma_f32_16x16x32_f16(aK[mt], bR, c, 0, 0, 0);
                    union { half4 v4; half2t hh[2]; } u;
                    u.hh[0] = __builtin_amdgcn_cvt_pkrtz(c[0], c[1]);
                    u.hh[1] = __builtin_amdgcn_cvt_pkrtz(c[2], c[3]);
                    *(half4*)(tbase + mt * 16 + jrb) = u.v4;
                }
            }
        }
        // group-local raw-S per-i max
        float mloc = -1.0e30f;
#pragma unroll
        for (int mt = 0; mt < 4; ++mt)
#pragma unroll
            for (int r = 0; r < 4; ++r) mloc = fmaxf(mloc, sacc[mt][r]);
        mloc = fmaxf(mloc, __shfl_xor(mloc, 16));
        mloc = fmaxf(mloc, __shfl_xor(mloc, 32));
        if (mloc > m_run + THRr) {
            float f = exp2f(m_run - mloc);
            m_run = mloc;
            pw2m = exp2f(m_run);
            z *= f; o0 *= f; o1 *= f;
        }
        __syncthreads();   // #3: sTQT ready
        // prefetch next tile now: crosses NO barrier before its use at loop top
        if (it < 7) {
            int j = (it + 1) * 128 + sg * 64 + sr;
            const float4v* ks_ = (const float4v*)(k + kvbase + (size_t)j * HDd + sd0);
            kx0 = ks_[0]; kx1 = ks_[1];
            const float4v* vs_ = (const float4v*)(v + kvbase + (size_t)j * HDd + sd0);
            vx0 = vs_[0]; vx1 = vs_[1];
        }
        // batched bias gathers
        const int drA = iclamp7(ri - (j0 >> 5));
        const int drB = iclamp7(ri - (j0 >> 5) - 1);
        int bsv[4][4];
        float tkv[4][4], tqv[4][4];
        {
            f16* tqt = sTQT + g2 * 4352;
            const f16* tkrow = sTK + i_local * 226;
#pragma unroll
            for (int mt = 0; mt < 4; ++mt) {
                const int drb = ((mt < 2) ? drA : drB) * 15 + 112;
#pragma unroll
                for (int r = 0; r < 4; ++r) {
                    int b = drb + dcc[mt][r];
                    bsv[mt][r] = b;
                    tkv[mt][r] = (float)tkrow[b];
                    tqv[mt][r] = (float)tqt[(224 - b - w0) * 68 + (mt * 16 + jrb + r)];
                }
            }
        }
#pragma unroll
        for (int mt = 0; mt < 4; ++mt)
#pragma unroll
            for (int r = 0; r < 4; ++r)
                sacc[mt][r] += tkv[mt][r] + tqv[mt][r];
        // exp + absolute-scale A-scatter + P pack
        f16* pwp = sP + w * 1152;
#pragma unroll
        for (int mt = 0; mt < 4; ++mt) {
            float p0 = exp2f(sacc[mt][0] - m_run);
            float p1 = exp2f(sacc[mt][1] - m_run);
            float p2 = exp2f(sacc[mt][2] - m_run);
            float p3 = exp2f(sacc[mt][3] - m_run);
            z += p0 + p1 + p2 + p3;
            float* arow = sA + i_local * 228;
            unsafeAtomicAdd(arow + bsv[mt][0], p0 * pw2m);
            unsafeAtomicAdd(arow + bsv[mt][1], p1 * pw2m);
            unsafeAtomicAdd(arow + bsv[mt][2], p2 * pw2m);
            unsafeAtomicAdd(arow + bsv[mt][3], p3 * pw2m);
            union { half4 v4; half2t hh[2]; } u;
            u.hh[0] = __builtin_amdgcn_cvt_pkrtz(p0, p1);
            u.hh[1] = __builtin_amdgcn_cvt_pkrtz(p2, p3);
            *(half4*)(pwp + li * 72 + mt * 16 + jrb) = u.v4;
        }
        // PV: O^T += V^T . P^T
        {
            f16* vb = sVT + g2 * 2304;
            const int sw0 = (li >> 3) << 4;
#pragma unroll
            for (int ks = 0; ks < 2; ++ks) {
                half8 bP  = *(const half8*)(pwp + li * 72 + ks * 32 + 8 * g);
                half8 aV0 = *(const half8*)(vb + li * 72        + ((ks * 32 + 8 * g) ^ sw0));
                half8 aV1 = *(const half8*)(vb + (16 + li) * 72 + ((ks * 32 + 8 * g) ^ sw0));
                o0 = __builtin_amdgcn_mfma_f32_16x16x32_f16(aV0, bP, o0, 0, 0, 0);
                o1 = __builtin_amdgcn_mfma_f32_16x16x32_f16(aV1, bP, o1, 0, 0, 0);
            }
        }
    }

    // -------- epilogue --------
    z += __shfl_xor(z, 16);
    z += __shfl_xor(z, 32);
    if (g == 0) {
        sM[g2 * 64 + i_local] = m_run;
        sZ[g2 * 64 + i_local] = z;
    }
    __syncthreads();   // #E1
    if (g2 == 1) {
        float* ob = sO1 + i_local * 36;
#pragma unroll
        for (int r = 0; r < 4; ++r) {
            ob[jrb + r] = o0[r];
            ob[16 + jrb + r] = o1[r];
        }
    }
    {
        int d = tid & 31;
        for (int l = tid >> 5; l < 264; l += 16) {
            float val = (l < Ll) ? rpev[((size_t)h * Ll + l) * HDd + d] : 0.f;
            sRVT[d * 264 + l] = (f16)val;
        }
    }
    __syncthreads();   // #E2
    if (g2 == 0) {
        float m0 = sM[i_local], m1 = sM[64 + i_local];
        float ms = fmaxf(m0, m1);
        float f0 = exp2f(m0 - ms), f1 = exp2f(m1 - ms);
        float zst = sZ[i_local] * f0 + sZ[64 + i_local] * f1;
        float rz = 1.0f / zst;
        float rzA = rz * exp2f(-ms);
        const float* ob = sO1 + i_local * 36;
#pragma unroll
        for (int r = 0; r < 4; ++r) {
            o0[r] = (o0[r] * f0 + ob[jrb + r] * f1) * rz;
            o1[r] = (o1[r] * f0 + ob[16 + jrb + r] * f1) * rz;
        }
#pragma unroll
        for (int ks = 0; ks < 8; ++ks) {
            union { half8 v8; half2t hh[4]; } u;
            if (ks < 7) {
                float4v a0 = *(const float4v*)(sA + i_local * 228 + ks * 32 + 8 * g);
                float4v a1 = *(const float4v*)(sA + i_local * 228 + ks * 32 + 8 * g + 4);
                u.hh[0] = __builtin_amdgcn_cvt_pkrtz(a0[0] * rzA, a0[1] * rzA);
                u.hh[1] = __builtin_amdgcn_cvt_pkrtz(a0[2] * rzA, a0[3] * rzA);
                u.hh[2] = __builtin_amdgcn_cvt_pkrtz(a1[0] * rzA, a1[1] * rzA);
                u.hh[3] = __builtin_amdgcn_cvt_pkrtz(a1[2] * rzA, a1[3] * rzA);
            } else {
                half2t z2; z2[0] = (f16)0.f; z2[1] = (f16)0.f;
                u.hh[0] = z2; u.hh[1] = z2; u.hh[2] = z2; u.hh[3] = z2;
                if (g == 0) {
                    float4v a0 = *(const float4v*)(sA + i_local * 228 + 224);
                    u.hh[0] = __builtin_amdgcn_cvt_pkrtz(a0[0] * rzA, a0[1] * rzA);
                    u.hh[1] = __builtin_amdgcn_cvt_pkrtz(a0[2] * rzA, a0[3] * rzA);
                }
            }
            half8 aR0 = *(const half8*)(sRVT + li * 264 + ks * 32 + 8 * g);
            half8 aR1 = *(const half8*)(sRVT + (16 + li) * 264 + ks * 32 + 8 * g);
            o0 = __builtin_amdgcn_mfma_f32_16x16x32_f16(aR0, u.v8, o0, 0, 0, 0);
            o1 = __builtin_amdgcn_mfma_f32_16x16x32_f16(aR1, u.v8, o1, 0, 0, 0);
        }
        float* cbase = ctx + (size_t)bh * 32 * 1024 + i0 + i_local;
#pragma unroll
        for (int r = 0; r < 4; ++r) {
            cbase[(size_t)(jrb + r) * 1024]      = o0[r];
            cbase[(size_t)(16 + jrb + r) * 1024] = o1[r];
        }
    }
}

// ---------------- K3: partial mean over tokens ----------------
__global__ __launch_bounds__(256) void reduce_partial(const float* __restrict__ ctx,
                                                      const float* __restrict__ x,
                                                      float* __restrict__ pcm,
                                                      float* __restrict__ pxm) {
    int b = blockIdx.x >> 4, s = blockIdx.x & 15;
    int c = threadIdx.x;
    const float* crow = ctx + ((size_t)(b * 8 + (c >> 5)) * 32 + (c & 31)) * 1024 + s * 64;
    float sc = 0.f, sx = 0.f;
    for (int n = 0; n < 64; ++n) {
        sc += crow[n];
        sx += x[((size_t)b * Nn + s * 64 + n) * Cc + c];
    }
    pcm[(size_t)blockIdx.x * 256 + c] = sc;
    pxm[(size_t)blockIdx.x * 256 + c] = sx;
}

// ---------------- K4: final proj(mean) + residual-mean + fc ----------------
__global__ __launch_bounds__(256) void final_kernel(const float* __restrict__ pcm,
                                                    const float* __restrict__ pxm,
                                                    const float* __restrict__ pw,
                                                    const float* __restrict__ pb,
                                                    const float* __restrict__ fcw,
                                                    const float* __restrict__ fcb,
                                                    float* __restrict__ out) {
    __shared__ float cm[256], xm[256], mrow[256];
    int b = blockIdx.x;
    int c = threadIdx.x;
    float sc = 0.f, sx = 0.f;
    for (int s2 = 0; s2 < 16; ++s2) {
        sc += pcm[((size_t)b * 16 + s2) * 256 + c];
        sx += pxm[((size_t)b * 16 + s2) * 256 + c];
    }
    cm[c] = sc * (1.f / 1024.f);
    xm[c] = sx * (1.f / 1024.f);
    __syncthreads();
    float acc = pb[c] + xm[c];
    for (int c2 = 0; c2 < 256; ++c2) acc = fmaf(cm[c2], pw[(size_t)c * 256 + c2], acc);
    mrow[c] = acc;
    __syncthreads();
    if (c < 15) {
        float a2 = fcb[c];
        for (int c2 = 0; c2 < 256; ++c2) a2 = fmaf(mrow[c2], fcw[(size_t)c * 256 + c2], a2);
        out[b * 15 + c] = a2;
    }
}

extern "C" void kernel_launch(void* const* d_in, const int* in_sizes, int n_in,
                              void* d_out, int out_size, void* d_ws, size_t ws_size,
                              hipStream_t stream) {
    const float* x     = (const float*)d_in[0];
    const float* qkv_w = (const float*)d_in[1];
    const float* pw    = (const float*)d_in[2];
    const float* pb    = (const float*)d_in[3];
    const float* fcw   = (const float*)d_in[4];
    const float* fcb   = (const float*)d_in[5];
    const float* rpek  = (const float*)d_in[6];
    const float* rpeq  = (const float*)d_in[7];
    const float* rpev  = (const float*)d_in[8];
    float* out = (float*)d_out;

    const size_t QW = (size_t)Bq * Hh * Nn * HDd;  // 2,097,152
    float* wsf = (float*)d_ws;
    float* q   = wsf;
    float* kk  = q + QW;
    float* vv  = kk + QW;
    float* ctx = vv + QW;
    float* pcm = ctx + QW;
    float* pxm = pcm + 32768;

    hipFuncSetAttribute((const void*)attn_mfma,
                        hipFuncAttributeMaxDynamicSharedMemorySize, SMEM_BYTES);

    qkv_gemm<<<dim3(12, 128), 256, 0, stream>>>(x, qkv_w, q, kk, vv);
    attn_mfma<<<1024, 512, SMEM_BYTES, stream>>>(q, kk, vv, rpek, rpeq, rpev, ctx);
    reduce_partial<<<128, 256, 0, stream>>>(ctx, x, pcm, pxm);
    final_kernel<<<8, 256, 0, stream>>>(pcm, pxm, pw, pb, fcw, fcb, out);
}

// Round 8
// 515.510 us; speedup vs baseline: 2.8372x; 1.0007x over previous
//
#include <hip/hip_runtime.h>
#include <math.h>

#define Bq 8
#define Nn 1024
#define Cc 256
#define Hh 8
#define HDd 32
#define Ll 225
#define SCALE 0.17677669529663687f
#define LOG2E 1.44269504088896f
#define THRr 8.0f

typedef __fp16 f16;
typedef __fp16 half8 __attribute__((ext_vector_type(8)));
typedef __fp16 half2t __attribute__((ext_vector_type(2)));
typedef float float4v __attribute__((ext_vector_type(4)));

// ---------------- K1: QKV projection (tiled SGEMM, f32) ----------------
__global__ __launch_bounds__(256) void qkv_gemm(const float* __restrict__ x,
                                                const float* __restrict__ w,
                                                float* __restrict__ q,
                                                float* __restrict__ k,
                                                float* __restrict__ v) {
    __shared__ float As[16][65];
    __shared__ float Bs[16][65];
    const int tix = threadIdx.x;
    const int tx = tix & 15, ty = tix >> 4;
    const int row0 = blockIdx.y * 64;
    const int col0 = blockIdx.x * 64;
    float acc[4][4] = {};
    for (int k0 = 0; k0 < Cc; k0 += 16) {
#pragma unroll
        for (int r = 0; r < 4; ++r) {
            int idx = tix + r * 256;
            int m = idx >> 4, kk = idx & 15;
            As[kk][m] = x[(size_t)(row0 + m) * Cc + k0 + kk];
            Bs[kk][m] = w[(size_t)(col0 + m) * Cc + k0 + kk];
        }
        __syncthreads();
#pragma unroll
        for (int kk = 0; kk < 16; ++kk) {
            float a[4], b[4];
#pragma unroll
            for (int i = 0; i < 4; ++i) a[i] = As[kk][ty * 4 + i];
#pragma unroll
            for (int j = 0; j < 4; ++j) b[j] = Bs[kk][tx * 4 + j];
#pragma unroll
            for (int i = 0; i < 4; ++i)
#pragma unroll
                for (int j = 0; j < 4; ++j) acc[i][j] = fmaf(a[i], b[j], acc[i][j]);
        }
        __syncthreads();
    }
#pragma unroll
    for (int i = 0; i < 4; ++i) {
        int row = row0 + ty * 4 + i;
        int b = row >> 10, n = row & 1023;
#pragma unroll
        for (int j = 0; j < 4; ++j) {
            int oc = col0 + tx * 4 + j;
            int which = oc >> 8;
            int h = (oc >> 5) & 7;
            int d = oc & 31;
            float* dst = (which == 0) ? q : ((which == 1) ? k : v);
            dst[(((size_t)b * Hh + h) * Nn + n) * HDd + d] = acc[i][j];
        }
    }
}

// ---------------- K2: fused iRPE attention, MFMA f16, 4 waves, 2 blocks/CU ----------------
// LDS (bytes):
//  sRQ  f16[240][40] @0      19200  (rpek, then SCALE*LOG2E*rpeq; rvT f16[32][272] alias in epilogue)
//  sTK  f16[32][226] @19200  14464
//  sA   f32[32][228] @33664  29184
//  sK   f16[64][40]  @62848  5120   (sO f32[32][36] alias in epilogue)
//  sVT  f16[32][72]  @67968  4608   (sQ f16[32][40] alias in prologue)
//  sM   f32[2][32]   @72576  256
//  sZ   f32[2][32]   @72832  256    total 73088 -> 2 blocks/CU
#define OFF_RQ 0
#define OFF_TK 19200
#define OFF_A  33664
#define OFF_K  62848
#define OFF_VT 67968
#define OFF_M  72576
#define OFF_Z  72832
#define SMEM_BYTES 73088

__device__ __forceinline__ int iclamp7(int x) {
    return x < -7 ? -7 : (x > 7 ? 7 : x);
}
__device__ __forceinline__ float bperm_f(int addr, float v) {
    int r = __builtin_amdgcn_ds_bpermute(addr, __builtin_bit_cast(int, v));
    return __builtin_bit_cast(float, r);
}

__global__ __launch_bounds__(256, 2) void attn_mfma(
    const float* __restrict__ q, const float* __restrict__ k, const float* __restrict__ v,
    const float* __restrict__ rpek, const float* __restrict__ rpeq, const float* __restrict__ rpev,
    float* __restrict__ ctx)
{
    extern __shared__ char smem[];
    f16*   sRQ  = (f16*)(smem + OFF_RQ);
    f16*   sTK  = (f16*)(smem + OFF_TK);
    float* sA   = (float*)(smem + OFF_A);
    f16*   sK   = (f16*)(smem + OFF_K);
    f16*   sVT  = (f16*)(smem + OFF_VT);
    f16*   sQ   = (f16*)(smem + OFF_VT);   // prologue alias
    float* sO   = (float*)(smem + OFF_K);  // epilogue alias
    f16*   sRVT = (f16*)(smem + OFF_RQ);   // epilogue alias
    float* sM   = (float*)(smem + OFF_M);
    float* sZ   = (float*)(smem + OFF_Z);

    const int tid = threadIdx.x;
    const int lane = tid & 63;
    const int w = tid >> 6;         // 0..3
    const int iw = w & 1;           // i-16-group
    const int jh = w >> 1;          // j-32-half
    const int li = lane & 15;
    const int g = lane >> 4;
    const int blk = blockIdx.x;
    const int bh = blk >> 5;
    const int h = bh & 7;
    const int i0 = (blk & 31) << 5;
    const int ri = blk & 31;        // constant row-band of this 32-query block
    const int i_local = iw * 16 + li;
    const size_t kvbase = (size_t)bh * (Nn * HDd);

    // staging ids: 256 threads cover 64 rows x 4 d-quarters
    const int sr  = tid >> 2;
    const int sq4 = tid & 3;
    const int sd0 = sq4 * 8;
    const int vswz = (sq4 & 1) << 4;

    // lane-constant dc clamps, bpermute addresses for the tq gather
    int dcc0[4], dcc1[4], tqa0[4], tqa1[4];
#pragma unroll
    for (int r = 0; r < 4; ++r) {
        dcc0[r] = iclamp7(i_local - (4 * g + r));
        dcc1[r] = iclamp7(i_local - (16 + 4 * g + r));
        tqa0[r] = (g * 16 + (7 - dcc0[r])) * 4;
        tqa1[r] = (g * 16 + (7 - dcc1[r])) * 4;
    }
    // P-exchange bpermute addresses (dest-side selection; see derivation)
    const int pa0 = (((2 * g) & 3) * 16 + li) * 4;
    const int pa1 = (((2 * g + 1) & 3) * 16 + li) * 4;
    const bool glow = (g < 2);

    // zero sA
    {
        float4v zz = {0.f, 0.f, 0.f, 0.f};
        for (int idx = tid; idx < 32 * 228 / 4; idx += 256)
            ((float4v*)sA)[idx] = zz;
    }
    // stage sQ (32 rows, f32 -> f16 x LOG2E)
    if (tid < 128) {
        int row = tid >> 2, d0 = (tid & 3) * 8;
        const float4v* src = (const float4v*)(q + kvbase + (size_t)(i0 + row) * HDd + d0);
        float4v x0 = src[0], x1 = src[1];
        union { half8 v8; half2t hh[4]; } u;
        u.hh[0] = __builtin_amdgcn_cvt_pkrtz(x0[0] * LOG2E, x0[1] * LOG2E);
        u.hh[1] = __builtin_amdgcn_cvt_pkrtz(x0[2] * LOG2E, x0[3] * LOG2E);
        u.hh[2] = __builtin_amdgcn_cvt_pkrtz(x1[0] * LOG2E, x1[1] * LOG2E);
        u.hh[3] = __builtin_amdgcn_cvt_pkrtz(x1[2] * LOG2E, x1[3] * LOG2E);
        *(half8*)(sQ + row * 40 + d0) = u.v8;
    }
    // stage sRQ = rpek[h] (240 rows, zero-pad >=225)
    for (int idx = tid; idx < 960; idx += 256) {
        int row = idx >> 2, d0 = (idx & 3) * 8;
        union { half8 v8; half2t hh[4]; } u;
        if (row < Ll) {
            const float4v* src = (const float4v*)(rpek + ((size_t)h * Ll + row) * HDd + d0);
            float4v x0 = src[0], x1 = src[1];
            u.hh[0] = __builtin_amdgcn_cvt_pkrtz(x0[0], x0[1]);
            u.hh[1] = __builtin_amdgcn_cvt_pkrtz(x0[2], x0[3]);
            u.hh[2] = __builtin_amdgcn_cvt_pkrtz(x1[0], x1[1]);
            u.hh[3] = __builtin_amdgcn_cvt_pkrtz(x1[2], x1[3]);
        } else {
            half2t z2; z2[0] = (f16)0.f; z2[1] = (f16)0.f;
            u.hh[0] = z2; u.hh[1] = z2; u.hh[2] = z2; u.hh[3] = z2;
        }
        *(half8*)(sRQ + row * 40 + d0) = u.v8;
    }
    __syncthreads();

    // Q fragments
    half8 aQ0 = *(const half8*)(sQ + li * 40 + 8 * g);
    half8 aQ1 = *(const half8*)(sQ + (16 + li) * 40 + 8 * g);
    half8 bQ  = *(const half8*)(sQ + i_local * 40 + 8 * g);

    // tk prologue: sTK[i][l] = (LOG2E q_i).rpek_l ; 30 MFMA units over 4 waves
#pragma unroll
    for (int p = 0; p < 8; ++p) {
        int u2 = w + 4 * p;
        if (u2 < 30) {
            int nt = u2 % 15, itile = u2 / 15;
            half8 bR = *(const half8*)(sRQ + (nt * 16 + li) * 40 + 8 * g);
            float4v c = {0.f, 0.f, 0.f, 0.f};
            c = __builtin_amdgcn_mfma_f32_16x16x32_f16(itile ? aQ1 : aQ0, bR, c, 0, 0, 0);
            int l = nt * 16 + li;
            if (l < Ll) {
#pragma unroll
                for (int r = 0; r < 4; ++r)
                    sTK[(itile * 16 + 4 * g + r) * 226 + l] = (f16)c[r];
            }
        }
    }
    __syncthreads();
    // restage sRQ = SCALE*LOG2E * rpeq[h]
    for (int idx = tid; idx < 960; idx += 256) {
        int row = idx >> 2, d0 = (idx & 3) * 8;
        union { half8 v8; half2t hh[4]; } u;
        if (row < Ll) {
            const float4v* src = (const float4v*)(rpeq + ((size_t)h * Ll + row) * HDd + d0);
            float4v x0 = src[0], x1 = src[1];
            const float sc = SCALE * LOG2E;
            u.hh[0] = __builtin_amdgcn_cvt_pkrtz(x0[0] * sc, x0[1] * sc);
            u.hh[1] = __builtin_amdgcn_cvt_pkrtz(x0[2] * sc, x0[3] * sc);
            u.hh[2] = __builtin_amdgcn_cvt_pkrtz(x1[0] * sc, x1[1] * sc);
            u.hh[3] = __builtin_amdgcn_cvt_pkrtz(x1[2] * sc, x1[3] * sc);
        } else {
            half2t z2; z2[0] = (f16)0.f; z2[1] = (f16)0.f;
            u.hh[0] = z2; u.hh[1] = z2; u.hh[2] = z2; u.hh[3] = z2;
        }
        *(half8*)(sRQ + row * 40 + d0) = u.v8;
    }
    // prefetch tile 0 K/V
    float4v kx0, kx1, vx0, vx1;
    {
        const float4v* ks_ = (const float4v*)(k + kvbase + (size_t)sr * HDd + sd0);
        kx0 = ks_[0]; kx1 = ks_[1];
        const float4v* vs_ = (const float4v*)(v + kvbase + (size_t)sr * HDd + sd0);
        vx0 = vs_[0]; vx1 = vs_[1];
    }

    float4v o0 = {0.f, 0.f, 0.f, 0.f}, o1 = {0.f, 0.f, 0.f, 0.f};
    float z = 0.f, m_run = -1.0e30f, pw2m = 0.f;

    for (int it = 0; it < 16; ++it) {
        __syncthreads();   // #1: sK/sVT free (it=0: sQ reads + restage done)
        {
            union { half8 v8; half2t hh[4]; } uk;
            uk.hh[0] = __builtin_amdgcn_cvt_pkrtz(kx0[0], kx0[1]);
            uk.hh[1] = __builtin_amdgcn_cvt_pkrtz(kx0[2], kx0[3]);
            uk.hh[2] = __builtin_amdgcn_cvt_pkrtz(kx1[0], kx1[1]);
            uk.hh[3] = __builtin_amdgcn_cvt_pkrtz(kx1[2], kx1[3]);
            *(half8*)(sK + sr * 40 + sd0) = uk.v8;
            int colv = sr ^ vswz;
            sVT[(sd0 + 0) * 72 + colv] = (f16)vx0[0];
            sVT[(sd0 + 1) * 72 + colv] = (f16)vx0[1];
            sVT[(sd0 + 2) * 72 + colv] = (f16)vx0[2];
            sVT[(sd0 + 3) * 72 + colv] = (f16)vx0[3];
            sVT[(sd0 + 4) * 72 + colv] = (f16)vx1[0];
            sVT[(sd0 + 5) * 72 + colv] = (f16)vx1[1];
            sVT[(sd0 + 6) * 72 + colv] = (f16)vx1[2];
            sVT[(sd0 + 7) * 72 + colv] = (f16)vx1[3];
        }
        __syncthreads();   // #2: staging done
        if (it < 15) {
            int j = (it + 1) * 64 + sr;
            const float4v* ks_ = (const float4v*)(k + kvbase + (size_t)j * HDd + sd0);
            kx0 = ks_[0]; kx1 = ks_[1];
            const float4v* vs_ = (const float4v*)(v + kvbase + (size_t)j * HDd + sd0);
            vx0 = vs_[0]; vx1 = vs_[1];
        }
        // K frags (own 32-j half) + S^T = K.Q^T
        half8 aK0 = *(const half8*)(sK + (jh * 32 + li) * 40 + 8 * g);
        half8 aK1 = *(const half8*)(sK + (jh * 32 + 16 + li) * 40 + 8 * g);
        float4v c0 = {0.f, 0.f, 0.f, 0.f};
        float4v s0 = __builtin_amdgcn_mfma_f32_16x16x32_f16(aK0, bQ, c0, 0, 0, 0);
        float4v s1 = __builtin_amdgcn_mfma_f32_16x16x32_f16(aK1, bQ, c0, 0, 0, 0);
        // tq (redundant per wave): single dr per wave-iter
        const int dr = iclamp7(ri - it * 2 - jh);
        const int w0 = (7 - dr) * 15;
        const int drb = dr * 15 + 112;
        half8 bR = *(const half8*)(sRQ + (w0 + li) * 40 + 8 * g);
        float4v t0 = __builtin_amdgcn_mfma_f32_16x16x32_f16(aK0, bR, c0, 0, 0, 0);
        float4v t1 = __builtin_amdgcn_mfma_f32_16x16x32_f16(aK1, bR, c0, 0, 0, 0);
        // raw-S max (bias absorbed by THR headroom)
        float mloc = fmaxf(fmaxf(fmaxf(s0[0], s0[1]), fmaxf(s0[2], s0[3])),
                           fmaxf(fmaxf(s1[0], s1[1]), fmaxf(s1[2], s1[3])));
        mloc = fmaxf(mloc, __shfl_xor(mloc, 16));
        mloc = fmaxf(mloc, __shfl_xor(mloc, 32));
        if (mloc > m_run + THRr) {
            float f = exp2f(m_run - mloc);
            m_run = mloc;
            pw2m = exp2f(m_run);
            z *= f; o0 *= f; o1 *= f;
        }
        // bias gathers: tq via in-wave bpermute, tk via LDS scalar reads
        const f16* tkrow = sTK + i_local * 226;
        float p0a[4], p1a[4];
        float* arow = sA + i_local * 228;
#pragma unroll
        for (int r = 0; r < 4; ++r) {
            float tqv = bperm_f(tqa0[r], t0[r]);
            float tkv = (float)tkrow[drb + dcc0[r]];
            float sv = s0[r] + tkv + tqv;
            float p = exp2f(sv - m_run);
            z += p;
            unsafeAtomicAdd(arow + drb + dcc0[r], p * pw2m);
            p0a[r] = p;
        }
#pragma unroll
        for (int r = 0; r < 4; ++r) {
            float tqv = bperm_f(tqa1[r], t1[r]);
            float tkv = (float)tkrow[drb + dcc1[r]];
            float sv = s1[r] + tkv + tqv;
            float p = exp2f(sv - m_run);
            z += p;
            unsafeAtomicAdd(arow + drb + dcc1[r], p * pw2m);
            p1a[r] = p;
        }
        // P exchange in-wave -> B-frag (P^T[j][i]).
        // Dest (g,li) needs key-pair (2t,2t+1), t=4g+j2, query li:
        //   value pw[2*(g>=2)+(j2&1)] from source group (2g+(j2>>1))&3.
        // 8 unconditional bpermutes (values fixed per op), dest-side cndmask select.
        int pw0 = __builtin_bit_cast(int, __builtin_amdgcn_cvt_pkrtz(p0a[0], p0a[1]));
        int pw1 = __builtin_bit_cast(int, __builtin_amdgcn_cvt_pkrtz(p0a[2], p0a[3]));
        int pw2 = __builtin_bit_cast(int, __builtin_amdgcn_cvt_pkrtz(p1a[0], p1a[1]));
        int pw3 = __builtin_bit_cast(int, __builtin_amdgcn_cvt_pkrtz(p1a[2], p1a[3]));
        int rA0 = __builtin_amdgcn_ds_bpermute(pa0, pw0);
        int rA1 = __builtin_amdgcn_ds_bpermute(pa0, pw1);
        int rA2 = __builtin_amdgcn_ds_bpermute(pa0, pw2);
        int rA3 = __builtin_amdgcn_ds_bpermute(pa0, pw3);
        int rB0 = __builtin_amdgcn_ds_bpermute(pa1, pw0);
        int rB1 = __builtin_amdgcn_ds_bpermute(pa1, pw1);
        int rB2 = __builtin_amdgcn_ds_bpermute(pa1, pw2);
        int rB3 = __builtin_amdgcn_ds_bpermute(pa1, pw3);
        union { half8 v8; int w4[4]; } bp;
        bp.w4[0] = glow ? rA0 : rA2;
        bp.w4[1] = glow ? rA1 : rA3;
        bp.w4[2] = glow ? rB0 : rB2;
        bp.w4[3] = glow ? rB1 : rB3;
        // PV over own 32-j half: O^T += V^T . P^T
        const int sw0 = ((li >> 3) & 1) << 4;
        half8 aV0 = *(const half8*)(sVT + li * 72        + ((jh * 32 + 8 * g) ^ sw0));
        half8 aV1 = *(const half8*)(sVT + (16 + li) * 72 + ((jh * 32 + 8 * g) ^ sw0));
        o0 = __builtin_amdgcn_mfma_f32_16x16x32_f16(aV0, bp.v8, o0, 0, 0, 0);
        o1 = __builtin_amdgcn_mfma_f32_16x16x32_f16(aV1, bp.v8, o1, 0, 0, 0);
    }

    // -------- epilogue --------
    z += __shfl_xor(z, 16);
    z += __shfl_xor(z, 32);
    if (g == 0) {
        sM[jh * 32 + i_local] = m_run;
        sZ[jh * 32 + i_local] = z;
    }
    __syncthreads();   // E1: loop LDS traffic done
    if (jh == 1) {
        float* ob = sO + i_local * 36;
#pragma unroll
        for (int r = 0; r < 4; ++r) {
            ob[4 * g + r] = o0[r];
            ob[16 + 4 * g + r] = o1[r];
        }
    }
    // stage rvT [32 d][272 l] (zero-pad l>=225)
    {
        int d = tid & 31;
        for (int l = tid >> 5; l < 272; l += 8) {
            float val = (l < Ll) ? rpev[((size_t)h * Ll + l) * HDd + d] : 0.f;
            sRVT[d * 272 + l] = (f16)val;
        }
    }
    __syncthreads();   // E2
    if (jh == 0) {
        float m0 = sM[i_local], m1 = sM[32 + i_local];
        float ms = fmaxf(m0, m1);
        float f0 = exp2f(m0 - ms), f1 = exp2f(m1 - ms);
        float zst = sZ[i_local] * f0 + sZ[32 + i_local] * f1;
        float rz = 1.0f / zst;
        float rzA = rz * exp2f(-ms);
        const float* ob = sO + i_local * 36;
#pragma unroll
        for (int r = 0; r < 4; ++r) {
            o0[r] = (o0[r] * f0 + ob[4 * g + r] * f1) * rz;
            o1[r] = (o1[r] * f0 + ob[16 + 4 * g + r] * f1) * rz;
        }
#pragma unroll
        for (int ks = 0; ks < 8; ++ks) {
            union { half8 v8; half2t hh[4]; } u;
            if (ks < 7) {
                float4v a0 = *(const float4v*)(sA + i_local * 228 + ks * 32 + 8 * g);
                float4v a1 = *(const float4v*)(sA + i_local * 228 + ks * 32 + 8 * g + 4);
                u.hh[0] = __builtin_amdgcn_cvt_pkrtz(a0[0] * rzA, a0[1] * rzA);
                u.hh[1] = __builtin_amdgcn_cvt_pkrtz(a0[2] * rzA, a0[3] * rzA);
                u.hh[2] = __builtin_amdgcn_cvt_pkrtz(a1[0] * rzA, a1[1] * rzA);
                u.hh[3] = __builtin_amdgcn_cvt_pkrtz(a1[2] * rzA, a1[3] * rzA);
            } else {
                half2t z2; z2[0] = (f16)0.f; z2[1] = (f16)0.f;
                u.hh[0] = z2; u.hh[1] = z2; u.hh[2] = z2; u.hh[3] = z2;
                if (g == 0) {
                    float4v a0 = *(const float4v*)(sA + i_local * 228 + 224);
                    u.hh[0] = __builtin_amdgcn_cvt_pkrtz(a0[0] * rzA, a0[1] * rzA);
                    u.hh[1] = __builtin_amdgcn_cvt_pkrtz(a0[2] * rzA, a0[3] * rzA);
                }
            }
            half8 aR0 = *(const half8*)(sRVT + li * 272 + ks * 32 + 8 * g);
            half8 aR1 = *(const half8*)(sRVT + (16 + li) * 272 + ks * 32 + 8 * g);
            o0 = __builtin_amdgcn_mfma_f32_16x16x32_f16(aR0, u.v8, o0, 0, 0, 0);
            o1 = __builtin_amdgcn_mfma_f32_16x16x32_f16(aR1, u.v8, o1, 0, 0, 0);
        }
        float* cbase = ctx + (size_t)bh * 32 * 1024 + i0 + i_local;
#pragma unroll
        for (int r = 0; r < 4; ++r) {
            cbase[(size_t)(4 * g + r) * 1024]      = o0[r];
            cbase[(size_t)(16 + 4 * g + r) * 1024] = o1[r];
        }
    }
}

// ---------------- K3: partial mean over tokens ----------------
__global__ __launch_bounds__(256) void reduce_partial(const float* __restrict__ ctx,
                                                      const float* __restrict__ x,
                                                      float* __restrict__ pcm,
                                                      float* __restrict__ pxm) {
    int b = blockIdx.x >> 4, s = blockIdx.x & 15;
    int c = threadIdx.x;
    const float* crow = ctx + ((size_t)(b * 8 + (c >> 5)) * 32 + (c & 31)) * 1024 + s * 64;
    float sc = 0.f, sx = 0.f;
    for (int n = 0; n < 64; ++n) {
        sc += crow[n];
        sx += x[((size_t)b * Nn + s * 64 + n) * Cc + c];
    }
    pcm[(size_t)blockIdx.x * 256 + c] = sc;
    pxm[(size_t)blockIdx.x * 256 + c] = sx;
}

// ---------------- K4: final proj(mean) + residual-mean + fc ----------------
__global__ __launch_bounds__(256) void final_kernel(const float* __restrict__ pcm,
                                                    const float* __restrict__ pxm,
                                                    const float* __restrict__ pw,
                                                    const float* __restrict__ pb,
                                                    const float* __restrict__ fcw,
                                                    const float* __restrict__ fcb,
                                                    float* __restrict__ out) {
    __shared__ float cm[256], xm[256], mrow[256];
    int b = blockIdx.x;
    int c = threadIdx.x;
    float sc = 0.f, sx = 0.f;
    for (int s2 = 0; s2 < 16; ++s2) {
        sc += pcm[((size_t)b * 16 + s2) * 256 + c];
        sx += pxm[((size_t)b * 16 + s2) * 256 + c];
    }
    cm[c] = sc * (1.f / 1024.f);
    xm[c] = sx * (1.f / 1024.f);
    __syncthreads();
    float acc = pb[c] + xm[c];
    for (int c2 = 0; c2 < 256; ++c2) acc = fmaf(cm[c2], pw[(size_t)c * 256 + c2], acc);
    mrow[c] = acc;
    __syncthreads();
    if (c < 15) {
        float a2 = fcb[c];
        for (int c2 = 0; c2 < 256; ++c2) a2 = fmaf(mrow[c2], fcw[(size_t)c * 256 + c2], a2);
        out[b * 15 + c] = a2;
    }
}

extern "C" void kernel_launch(void* const* d_in, const int* in_sizes, int n_in,
                              void* d_out, int out_size, void* d_ws, size_t ws_size,
                              hipStream_t stream) {
    const float* x     = (const float*)d_in[0];
    const float* qkv_w = (const float*)d_in[1];
    const float* pw    = (const float*)d_in[2];
    const float* pb    = (const float*)d_in[3];
    const float* fcw   = (const float*)d_in[4];
    const float* fcb   = (const float*)d_in[5];
    const float* rpek  = (const float*)d_in[6];
    const float* rpeq  = (const float*)d_in[7];
    const float* rpev  = (const float*)d_in[8];
    float* out = (float*)d_out;

    const size_t QW = (size_t)Bq * Hh * Nn * HDd;  // 2,097,152
    float* wsf = (float*)d_ws;
    float* q   = wsf;
    float* kk  = q + QW;
    float* vv  = kk + QW;
    float* ctx = vv + QW;
    float* pcm = ctx + QW;
    float* pxm = pcm + 32768;

    hipFuncSetAttribute((const void*)attn_mfma,
                        hipFuncAttributeMaxDynamicSharedMemorySize, SMEM_BYTES);

    qkv_gemm<<<dim3(12, 128), 256, 0, stream>>>(x, qkv_w, q, kk, vv);
    attn_mfma<<<2048, 256, SMEM_BYTES, stream>>>(q, kk, vv, rpek, rpeq, rpev, ctx);
    reduce_partial<<<128, 256, 0, stream>>>(ctx, x, pcm, pxm);
    final_kernel<<<8, 256, 0, stream>>>(pcm, pxm, pw, pb, fcw, fcb, out);
}

// Round 10
// 489.976 us; speedup vs baseline: 2.9851x; 1.0521x over previous
//
#include <hip/hip_runtime.h>
#include <math.h>

#define Bq 8
#define Nn 1024
#define Cc 256
#define Hh 8
#define HDd 32
#define Ll 225
#define SCALE 0.17677669529663687f
#define LOG2E 1.44269504088896f
#define THRr 8.0f

typedef __fp16 f16;
typedef __fp16 half8 __attribute__((ext_vector_type(8)));
typedef __fp16 half2t __attribute__((ext_vector_type(2)));
typedef float float4v __attribute__((ext_vector_type(4)));

// ---------------- K1: QKV projection (tiled SGEMM, f32) ----------------
__global__ __launch_bounds__(256) void qkv_gemm(const float* __restrict__ x,
                                                const float* __restrict__ w,
                                                float* __restrict__ q,
                                                float* __restrict__ k,
                                                float* __restrict__ v) {
    __shared__ float As[16][65];
    __shared__ float Bs[16][65];
    const int tix = threadIdx.x;
    const int tx = tix & 15, ty = tix >> 4;
    const int row0 = blockIdx.y * 64;
    const int col0 = blockIdx.x * 64;
    float acc[4][4] = {};
    for (int k0 = 0; k0 < Cc; k0 += 16) {
#pragma unroll
        for (int r = 0; r < 4; ++r) {
            int idx = tix + r * 256;
            int m = idx >> 4, kk = idx & 15;
            As[kk][m] = x[(size_t)(row0 + m) * Cc + k0 + kk];
            Bs[kk][m] = w[(size_t)(col0 + m) * Cc + k0 + kk];
        }
        __syncthreads();
#pragma unroll
        for (int kk = 0; kk < 16; ++kk) {
            float a[4], b[4];
#pragma unroll
            for (int i = 0; i < 4; ++i) a[i] = As[kk][ty * 4 + i];
#pragma unroll
            for (int j = 0; j < 4; ++j) b[j] = Bs[kk][tx * 4 + j];
#pragma unroll
            for (int i = 0; i < 4; ++i)
#pragma unroll
                for (int j = 0; j < 4; ++j) acc[i][j] = fmaf(a[i], b[j], acc[i][j]);
        }
        __syncthreads();
    }
#pragma unroll
    for (int i = 0; i < 4; ++i) {
        int row = row0 + ty * 4 + i;
        int b = row >> 10, n = row & 1023;
#pragma unroll
        for (int j = 0; j < 4; ++j) {
            int oc = col0 + tx * 4 + j;
            int which = oc >> 8;
            int h = (oc >> 5) & 7;
            int d = oc & 31;
            float* dst = (which == 0) ? q : ((which == 1) ? k : v);
            dst[(((size_t)b * Hh + h) * Nn + n) * HDd + d] = acc[i][j];
        }
    }
}

// ---------------- K2: barrier-free fused iRPE attention ----------------
// LDS (bytes):
//  sRQ f16[256][40] @0      20480 (rpek -> SCALE*LOG2E*rpeq -> rpe_v)
//  sTK f16[32][226] @20480  14464 (tk table; sO f32[3][32][36] alias in epilogue)
//  sA  f32[32][260] @34944  33280 (absolute-scale exp2(S))
//  sM4 f32[4][64]   @68224  1024
//  sZ4 f32[4][64]   @69248  1024  total 70272 -> 2 blocks/CU
#define OFF_RQ 0
#define OFF_TK 20480
#define OFF_A  34944
#define OFF_M  68224
#define OFF_Z  69248
#define SMEM_BYTES 70272
#define ASTR 260

__device__ __forceinline__ int iclamp7(int x) {
    return x < -7 ? -7 : (x > 7 ? 7 : x);
}
__device__ __forceinline__ float bperm_f(int addr, float v) {
    int r = __builtin_amdgcn_ds_bpermute(addr, __builtin_bit_cast(int, v));
    return __builtin_bit_cast(float, r);
}
__device__ __forceinline__ half8 pack8(float4v a, float4v b) {
    union { half8 v8; half2t hh[4]; } u;
    u.hh[0] = __builtin_amdgcn_cvt_pkrtz(a[0], a[1]);
    u.hh[1] = __builtin_amdgcn_cvt_pkrtz(a[2], a[3]);
    u.hh[2] = __builtin_amdgcn_cvt_pkrtz(b[0], b[1]);
    u.hh[3] = __builtin_amdgcn_cvt_pkrtz(b[2], b[3]);
    return u.v8;
}

__global__ __launch_bounds__(256, 2) void attn_mfma(
    const float* __restrict__ q, const float* __restrict__ k, const float* __restrict__ v,
    const float* __restrict__ rpek, const float* __restrict__ rpeq, const float* __restrict__ rpev,
    float* __restrict__ ctx)
{
    extern __shared__ char smem[];
    f16*   sRQ = (f16*)(smem + OFF_RQ);
    f16*   sTK = (f16*)(smem + OFF_TK);
    float* sA  = (float*)(smem + OFF_A);
    float* sO  = (float*)(smem + OFF_TK);   // epilogue alias
    float* sM4 = (float*)(smem + OFF_M);
    float* sZ4 = (float*)(smem + OFF_Z);

    const int tid = threadIdx.x;
    const int lane = tid & 63;
    const int w = tid >> 6;         // 0..3 (independent j-streams)
    const int li = lane & 15;
    const int g = lane >> 4;
    const int blk = blockIdx.x;
    const int bh = blk >> 5;
    const int h = bh & 7;
    const int i0 = (blk & 31) << 5;
    const int ri = blk & 31;
    const size_t kvbase = (size_t)bh * (Nn * HDd);

    // lane-constant dc clamps for the 4 quadrants (i in {li,16+li} x j-local in {4g+r,16+4g+r})
    int dcc00[4], dcc01[4], dcc10[4], dcc11[4];
#pragma unroll
    for (int r = 0; r < 4; ++r) {
        dcc00[r] = iclamp7(li - (4 * g + r));
        dcc01[r] = iclamp7(16 + li - (4 * g + r));
        dcc10[r] = iclamp7(li - (16 + 4 * g + r));
        dcc11[r] = iclamp7(16 + li - (16 + 4 * g + r));
    }
    const int g16c = (g * 16 + 7) * 4;   // tq bperm base: addr = g16c - 4*dcc
    // P-exchange addresses (dest-side select)
    const int paA = (((2 * g) & 3) * 16 + li) * 4;
    const int paB = (((2 * g + 1) & 3) * 16 + li) * 4;
    const bool glow = (g < 2);

    // zero sA
    {
        float4v zz = {0.f, 0.f, 0.f, 0.f};
        for (int idx = tid; idx < 32 * ASTR / 4; idx += 256)
            ((float4v*)sA)[idx] = zz;
    }
    // Q fragments directly from global (coalesced 16B/lane)
    half8 bQ0, bQ1, aQ0, aQ1;
    {
        const float4v* q0 = (const float4v*)(q + kvbase + (size_t)(i0 + li) * HDd + 8 * g);
        float4v a = q0[0] * LOG2E, b = q0[1] * LOG2E;
        aQ0 = pack8(a, b);
        const float4v* q1 = (const float4v*)(q + kvbase + (size_t)(i0 + 16 + li) * HDd + 8 * g);
        float4v c = q1[0] * LOG2E, d = q1[1] * LOG2E;
        aQ1 = pack8(c, d);
        bQ0 = aQ0; bQ1 = aQ1;
    }
    // stage sRQ = rpek[h] (rows 0..255, zero-pad >=225)
    for (int idx = tid; idx < 1024; idx += 256) {
        int row = idx >> 2, d0 = (idx & 3) * 8;
        half8 val;
        if (row < Ll) {
            const float4v* src = (const float4v*)(rpek + ((size_t)h * Ll + row) * HDd + d0);
            val = pack8(src[0], src[1]);
        } else {
            float4v z4 = {0.f, 0.f, 0.f, 0.f};
            val = pack8(z4, z4);
        }
        *(half8*)(sRQ + row * 40 + d0) = val;
    }
    __syncthreads();   // P1: sRQ(rpek) ready

    // tk prologue: sTK[i][l] = (LOG2E q_i).rpek_l ; 30 MFMA units over 4 waves
#pragma unroll
    for (int p = 0; p < 8; ++p) {
        int u2 = w + 4 * p;
        if (u2 < 30) {
            int nt = u2 % 15, itile = u2 / 15;
            half8 bR = *(const half8*)(sRQ + (nt * 16 + li) * 40 + 8 * g);
            float4v c = {0.f, 0.f, 0.f, 0.f};
            c = __builtin_amdgcn_mfma_f32_16x16x32_f16(itile ? aQ1 : aQ0, bR, c, 0, 0, 0);
            int l = nt * 16 + li;
            if (l < Ll) {
#pragma unroll
                for (int r = 0; r < 4; ++r)
                    sTK[(itile * 16 + 4 * g + r) * 226 + l] = (f16)c[r];
            }
        }
    }
    __syncthreads();   // P2: tk built, sRQ free
    // restage sRQ = SCALE*LOG2E * rpeq[h]
    for (int idx = tid; idx < 1024; idx += 256) {
        int row = idx >> 2, d0 = (idx & 3) * 8;
        half8 val;
        if (row < Ll) {
            const float4v* src = (const float4v*)(rpeq + ((size_t)h * Ll + row) * HDd + d0);
            const float sc = SCALE * LOG2E;
            val = pack8(src[0] * sc, src[1] * sc);
        } else {
            float4v z4 = {0.f, 0.f, 0.f, 0.f};
            val = pack8(z4, z4);
        }
        *(half8*)(sRQ + row * 40 + d0) = val;
    }
    __syncthreads();   // P3: loop tables ready. No more barriers until epilogue.

    // K prefetch for tile 0 (own wave's 32-j tile)
    float4v ka, kb, kc, kd;
    {
        int jt = w * 32;
        const float4v* p0 = (const float4v*)(k + kvbase + (size_t)(jt + li) * HDd + 8 * g);
        ka = p0[0]; kb = p0[1];
        const float4v* p1 = (const float4v*)(k + kvbase + (size_t)(jt + 16 + li) * HDd + 8 * g);
        kc = p1[0]; kd = p1[1];
    }

    // O accumulators: o00 = O^T[d=4g+r][i=li], o10 = O^T[16+4g+r][li],
    //                 o01 = O^T[4g+r][16+li],  o11 = O^T[16+4g+r][16+li]
    float4v o00 = {0,0,0,0}, o01 = {0,0,0,0}, o10 = {0,0,0,0}, o11 = {0,0,0,0};
    float z_lo = 0.f, z_hi = 0.f;
    float m_lo = -1.0e30f, m_hi = -1.0e30f, pw_lo = 0.f, pw_hi = 0.f;

    for (int it = 0; it < 8; ++it) {
        const int jt = it * 128 + w * 32;
        half8 aK0 = pack8(ka, kb);
        half8 aK1 = pack8(kc, kd);
        if (it < 7) {
            int jn = (it + 1) * 128 + w * 32;
            const float4v* p0 = (const float4v*)(k + kvbase + (size_t)(jn + li) * HDd + 8 * g);
            ka = p0[0]; kb = p0[1];
            const float4v* p1 = (const float4v*)(k + kvbase + (size_t)(jn + 16 + li) * HDd + 8 * g);
            kc = p1[0]; kd = p1[1];
        }
        // V loads (V^T A-frag gather; latency hidden under softmax below)
        float vx[8], vy[8];
#pragma unroll
        for (int e = 0; e < 8; ++e) {
            vx[e] = v[kvbase + (size_t)(jt + 8 * g + e) * HDd + li];
            vy[e] = v[kvbase + (size_t)(jt + 8 * g + e) * HDd + 16 + li];
        }
        // S^T = K.Q^T (S^T[j][i]) and tq = K.rq'^T
        float4v c0 = {0,0,0,0};
        float4v s00 = __builtin_amdgcn_mfma_f32_16x16x32_f16(aK0, bQ0, c0, 0, 0, 0);
        float4v s01 = __builtin_amdgcn_mfma_f32_16x16x32_f16(aK0, bQ1, c0, 0, 0, 0);
        float4v s10 = __builtin_amdgcn_mfma_f32_16x16x32_f16(aK1, bQ0, c0, 0, 0, 0);
        float4v s11 = __builtin_amdgcn_mfma_f32_16x16x32_f16(aK1, bQ1, c0, 0, 0, 0);
        const int dr = iclamp7(ri - (4 * it + w));
        const int w0 = (7 - dr) * 15;
        const int drb = dr * 15 + 112;
        half8 bR = *(const half8*)(sRQ + (w0 + li) * 40 + 8 * g);
        float4v t0 = __builtin_amdgcn_mfma_f32_16x16x32_f16(aK0, bR, c0, 0, 0, 0);
        float4v t1 = __builtin_amdgcn_mfma_f32_16x16x32_f16(aK1, bR, c0, 0, 0, 0);
        // per-i raw-S max (biases absorbed in THR headroom)
        float ml = fmaxf(fmaxf(fmaxf(s00[0], s00[1]), fmaxf(s00[2], s00[3])),
                         fmaxf(fmaxf(s10[0], s10[1]), fmaxf(s10[2], s10[3])));
        float mh = fmaxf(fmaxf(fmaxf(s01[0], s01[1]), fmaxf(s01[2], s01[3])),
                         fmaxf(fmaxf(s11[0], s11[1]), fmaxf(s11[2], s11[3])));
        ml = fmaxf(ml, __shfl_xor(ml, 16)); ml = fmaxf(ml, __shfl_xor(ml, 32));
        mh = fmaxf(mh, __shfl_xor(mh, 16)); mh = fmaxf(mh, __shfl_xor(mh, 32));
        if (ml > m_lo + THRr) {
            float f = exp2f(m_lo - ml); m_lo = ml; pw_lo = exp2f(m_lo);
            z_lo *= f; o00 *= f; o10 *= f;   // o00,o10 carry i = li  -> m_lo rows
        }
        if (mh > m_hi + THRr) {
            float f = exp2f(m_hi - mh); m_hi = mh; pw_hi = exp2f(m_hi);
            z_hi *= f; o01 *= f; o11 *= f;   // o01,o11 carry i = 16+li
        }
        // softmax + gathers + absolute-scale A-scatter, 4 quadrants
        const f16* tkL = sTK + li * 226;
        const f16* tkH = sTK + (16 + li) * 226;
        float* aL = sA + li * ASTR;
        float* aH = sA + (16 + li) * ASTR;
        float p00[4], p01[4], p10[4], p11[4];
#pragma unroll
        for (int r = 0; r < 4; ++r) {
            float tq0 = bperm_f(g16c - 4 * dcc00[r], t0[r]);
            float s = s00[r] + (float)tkL[drb + dcc00[r]] + tq0;
            float p = exp2f(s - m_lo); z_lo += p; p00[r] = p;
            unsafeAtomicAdd(aL + drb + dcc00[r], p * pw_lo);
        }
#pragma unroll
        for (int r = 0; r < 4; ++r) {
            float tq0 = bperm_f(g16c - 4 * dcc10[r], t1[r]);
            float s = s10[r] + (float)tkL[drb + dcc10[r]] + tq0;
            float p = exp2f(s - m_lo); z_lo += p; p10[r] = p;
            unsafeAtomicAdd(aL + drb + dcc10[r], p * pw_lo);
        }
#pragma unroll
        for (int r = 0; r < 4; ++r) {
            float tq0 = bperm_f(g16c - 4 * dcc01[r], t0[r]);
            float s = s01[r] + (float)tkH[drb + dcc01[r]] + tq0;
            float p = exp2f(s - m_hi); z_hi += p; p01[r] = p;
            unsafeAtomicAdd(aH + drb + dcc01[r], p * pw_hi);
        }
#pragma unroll
        for (int r = 0; r < 4; ++r) {
            float tq0 = bperm_f(g16c - 4 * dcc11[r], t1[r]);
            float s = s11[r] + (float)tkH[drb + dcc11[r]] + tq0;
            float p = exp2f(s - m_hi); z_hi += p; p11[r] = p;
            unsafeAtomicAdd(aH + drb + dcc11[r], p * pw_hi);
        }
        // P exchange -> P^T B-frags: dest lane (li,g) gets P[li][8g+e] (and P[16+li][8g+e])
        int pl01 = __builtin_bit_cast(int, __builtin_amdgcn_cvt_pkrtz(p00[0], p00[1]));
        int pl23 = __builtin_bit_cast(int, __builtin_amdgcn_cvt_pkrtz(p00[2], p00[3]));
        int ph01 = __builtin_bit_cast(int, __builtin_amdgcn_cvt_pkrtz(p10[0], p10[1]));
        int ph23 = __builtin_bit_cast(int, __builtin_amdgcn_cvt_pkrtz(p10[2], p10[3]));
        int ql01 = __builtin_bit_cast(int, __builtin_amdgcn_cvt_pkrtz(p01[0], p01[1]));
        int ql23 = __builtin_bit_cast(int, __builtin_amdgcn_cvt_pkrtz(p01[2], p01[3]));
        int qh01 = __builtin_bit_cast(int, __builtin_amdgcn_cvt_pkrtz(p11[0], p11[1]));
        int qh23 = __builtin_bit_cast(int, __builtin_amdgcn_cvt_pkrtz(p11[2], p11[3]));
        union { half8 v8; int w4[4]; } pAlo, pAhi;
        {
            int rA0 = __builtin_amdgcn_ds_bpermute(paA, pl01);
            int rA1 = __builtin_amdgcn_ds_bpermute(paA, pl23);
            int rA2 = __builtin_amdgcn_ds_bpermute(paA, ph01);
            int rA3 = __builtin_amdgcn_ds_bpermute(paA, ph23);
            int rB0 = __builtin_amdgcn_ds_bpermute(paB, pl01);
            int rB1 = __builtin_amdgcn_ds_bpermute(paB, pl23);
            int rB2 = __builtin_amdgcn_ds_bpermute(paB, ph01);
            int rB3 = __builtin_amdgcn_ds_bpermute(paB, ph23);
            pAlo.w4[0] = glow ? rA0 : rA2;
            pAlo.w4[1] = glow ? rA1 : rA3;
            pAlo.w4[2] = glow ? rB0 : rB2;
            pAlo.w4[3] = glow ? rB1 : rB3;
        }
        {
            int rA0 = __builtin_amdgcn_ds_bpermute(paA, ql01);
            int rA1 = __builtin_amdgcn_ds_bpermute(paA, ql23);
            int rA2 = __builtin_amdgcn_ds_bpermute(paA, qh01);
            int rA3 = __builtin_amdgcn_ds_bpermute(paA, qh23);
            int rB0 = __builtin_amdgcn_ds_bpermute(paB, ql01);
            int rB1 = __builtin_amdgcn_ds_bpermute(paB, ql23);
            int rB2 = __builtin_amdgcn_ds_bpermute(paB, qh01);
            int rB3 = __builtin_amdgcn_ds_bpermute(paB, qh23);
            pAhi.w4[0] = glow ? rA0 : rA2;
            pAhi.w4[1] = glow ? rA1 : rA3;
            pAhi.w4[2] = glow ? rB0 : rB2;
            pAhi.w4[3] = glow ? rB1 : rB3;
        }
        // V^T A-frags (lane (li,g) holds V[jt+8g+e][li] = V^T[d=li][j=8g+e])
        union { half8 v8; half2t hh[4]; } aV0, aV1;
        aV0.hh[0] = __builtin_amdgcn_cvt_pkrtz(vx[0], vx[1]);
        aV0.hh[1] = __builtin_amdgcn_cvt_pkrtz(vx[2], vx[3]);
        aV0.hh[2] = __builtin_amdgcn_cvt_pkrtz(vx[4], vx[5]);
        aV0.hh[3] = __builtin_amdgcn_cvt_pkrtz(vx[6], vx[7]);
        aV1.hh[0] = __builtin_amdgcn_cvt_pkrtz(vy[0], vy[1]);
        aV1.hh[1] = __builtin_amdgcn_cvt_pkrtz(vy[2], vy[3]);
        aV1.hh[2] = __builtin_amdgcn_cvt_pkrtz(vy[4], vy[5]);
        aV1.hh[3] = __builtin_amdgcn_cvt_pkrtz(vy[6], vy[7]);
        // PV (transposed): O^T = V^T . P^T  -> D[m=d][n=i], i on li (matches m/z!)
        o00 = __builtin_amdgcn_mfma_f32_16x16x32_f16(aV0.v8, pAlo.v8, o00, 0, 0, 0);
        o01 = __builtin_amdgcn_mfma_f32_16x16x32_f16(aV0.v8, pAhi.v8, o01, 0, 0, 0);
        o10 = __builtin_amdgcn_mfma_f32_16x16x32_f16(aV1.v8, pAlo.v8, o10, 0, 0, 0);
        o11 = __builtin_amdgcn_mfma_f32_16x16x32_f16(aV1.v8, pAhi.v8, o11, 0, 0, 0);
    }

    // -------- epilogue --------
    z_lo += __shfl_xor(z_lo, 16); z_lo += __shfl_xor(z_lo, 32);
    z_hi += __shfl_xor(z_hi, 16); z_hi += __shfl_xor(z_hi, 32);
    if (g == 0) {
        sM4[w * 64 + li] = m_lo;  sM4[w * 64 + 32 + li] = m_hi;
        sZ4[w * 64 + li] = z_lo;  sZ4[w * 64 + 32 + li] = z_hi;
    }
    __syncthreads();   // E1: loop done everywhere; sTK free
    if (w > 0) {       // deposit partial O into sO[3][32(i)][36(d)]
        float* ob = sO + (w - 1) * 1152;
#pragma unroll
        for (int r = 0; r < 4; ++r) {
            ob[li * 36 + 4 * g + r]             = o00[r];
            ob[li * 36 + 16 + 4 * g + r]        = o10[r];
            ob[(16 + li) * 36 + 4 * g + r]      = o01[r];
            ob[(16 + li) * 36 + 16 + 4 * g + r] = o11[r];
        }
    }
    // stage rpe_v into sRQ region (rows l, cols d; rows>=225 zero)
    for (int idx = tid; idx < 1024; idx += 256) {
        int row = idx >> 2, d0 = (idx & 3) * 8;
        half8 val;
        if (row < Ll) {
            const float4v* src = (const float4v*)(rpev + ((size_t)h * Ll + row) * HDd + d0);
            val = pack8(src[0], src[1]);
        } else {
            float4v z4 = {0.f, 0.f, 0.f, 0.f};
            val = pack8(z4, z4);
        }
        *(half8*)(sRQ + row * 40 + d0) = val;
    }
    __syncthreads();   // E2
    if (w == 0) {
        // per-li merge factors: lo (i = li), hi (i = 16+li)
        float fL0, fL1, fL2, fL3, rzL, rzAL;
        {
            float m0 = sM4[li], m1 = sM4[64 + li], m2 = sM4[128 + li], m3 = sM4[192 + li];
            float ms = fmaxf(fmaxf(m0, m1), fmaxf(m2, m3));
            fL0 = exp2f(m0 - ms); fL1 = exp2f(m1 - ms); fL2 = exp2f(m2 - ms); fL3 = exp2f(m3 - ms);
            float zt = sZ4[li] * fL0 + sZ4[64 + li] * fL1 + sZ4[128 + li] * fL2 + sZ4[192 + li] * fL3;
            rzL = 1.0f / zt;
            rzAL = exp2f(-ms) * rzL;
        }
        float fH0, fH1, fH2, fH3, rzH, rzAH;
        {
            int ih = 32 + li;
            float m0 = sM4[ih], m1 = sM4[64 + ih], m2 = sM4[128 + ih], m3 = sM4[192 + ih];
            float ms = fmaxf(fmaxf(m0, m1), fmaxf(m2, m3));
            fH0 = exp2f(m0 - ms); fH1 = exp2f(m1 - ms); fH2 = exp2f(m2 - ms); fH3 = exp2f(m3 - ms);
            float zt = sZ4[ih] * fH0 + sZ4[64 + ih] * fH1 + sZ4[128 + ih] * fH2 + sZ4[192 + ih] * fH3;
            rzH = 1.0f / zt;
            rzAH = exp2f(-ms) * rzH;
        }
#pragma unroll
        for (int r = 0; r < 4; ++r) {
            int dlo = 4 * g + r, dhi = 16 + 4 * g + r;
            o00[r] = (o00[r] * fL0 + sO[li * 36 + dlo] * fL1
                      + sO[1152 + li * 36 + dlo] * fL2 + sO[2304 + li * 36 + dlo] * fL3) * rzL;
            o10[r] = (o10[r] * fL0 + sO[li * 36 + dhi] * fL1
                      + sO[1152 + li * 36 + dhi] * fL2 + sO[2304 + li * 36 + dhi] * fL3) * rzL;
            o01[r] = (o01[r] * fH0 + sO[(16 + li) * 36 + dlo] * fH1
                      + sO[1152 + (16 + li) * 36 + dlo] * fH2 + sO[2304 + (16 + li) * 36 + dlo] * fH3) * rzH;
            o11[r] = (o11[r] * fH0 + sO[(16 + li) * 36 + dhi] * fH1
                      + sO[1152 + (16 + li) * 36 + dhi] * fH2 + sO[2304 + (16 + li) * 36 + dhi] * fH3) * rzH;
        }
        // A-term (transposed): O^T += rpev^T . (A*rzA)^T
#pragma unroll
        for (int ks = 0; ks < 8; ++ks) {
            const int kbase = ks * 32 + 8 * g;
            float4v aL0 = *(const float4v*)(sA + li * ASTR + kbase);
            float4v aL1 = *(const float4v*)(sA + li * ASTR + kbase + 4);
            float4v aH0 = *(const float4v*)(sA + (16 + li) * ASTR + kbase);
            float4v aH1 = *(const float4v*)(sA + (16 + li) * ASTR + kbase + 4);
            union { half8 v8; half2t hh[4]; } fAL, fAH;
            fAL.hh[0] = __builtin_amdgcn_cvt_pkrtz(aL0[0] * rzAL, aL0[1] * rzAL);
            fAL.hh[1] = __builtin_amdgcn_cvt_pkrtz(aL0[2] * rzAL, aL0[3] * rzAL);
            fAL.hh[2] = __builtin_amdgcn_cvt_pkrtz(aL1[0] * rzAL, aL1[1] * rzAL);
            fAL.hh[3] = __builtin_amdgcn_cvt_pkrtz(aL1[2] * rzAL, aL1[3] * rzAL);
            fAH.hh[0] = __builtin_amdgcn_cvt_pkrtz(aH0[0] * rzAH, aH0[1] * rzAH);
            fAH.hh[1] = __builtin_amdgcn_cvt_pkrtz(aH0[2] * rzAH, aH0[3] * rzAH);
            fAH.hh[2] = __builtin_amdgcn_cvt_pkrtz(aH1[0] * rzAH, aH1[1] * rzAH);
            fAH.hh[3] = __builtin_amdgcn_cvt_pkrtz(aH1[2] * rzAH, aH1[3] * rzAH);
            union { half8 v8; f16 e[8]; } BL, BH;
#pragma unroll
            for (int e = 0; e < 8; ++e) {
                BL.e[e] = sRQ[(kbase + e) * 40 + li];        // rpev^T[d=li][l]
                BH.e[e] = sRQ[(kbase + e) * 40 + 16 + li];   // rpev^T[d=16+li][l]
            }
            o00 = __builtin_amdgcn_mfma_f32_16x16x32_f16(BL.v8, fAL.v8, o00, 0, 0, 0);
            o01 = __builtin_amdgcn_mfma_f32_16x16x32_f16(BL.v8, fAH.v8, o01, 0, 0, 0);
            o10 = __builtin_amdgcn_mfma_f32_16x16x32_f16(BH.v8, fAL.v8, o10, 0, 0, 0);
            o11 = __builtin_amdgcn_mfma_f32_16x16x32_f16(BH.v8, fAH.v8, o11, 0, 0, 0);
        }
        // write ctx [bh][d][n]
        float* cb = ctx + (size_t)bh * 32 * 1024 + i0;
#pragma unroll
        for (int r = 0; r < 4; ++r) {
            cb[(size_t)(4 * g + r) * 1024 + li]           = o00[r];
            cb[(size_t)(4 * g + r) * 1024 + 16 + li]      = o01[r];
            cb[(size_t)(16 + 4 * g + r) * 1024 + li]      = o10[r];
            cb[(size_t)(16 + 4 * g + r) * 1024 + 16 + li] = o11[r];
        }
    }
}

// ---------------- K3: partial mean over tokens ----------------
__global__ __launch_bounds__(256) void reduce_partial(const float* __restrict__ ctx,
                                                      const float* __restrict__ x,
                                                      float* __restrict__ pcm,
                                                      float* __restrict__ pxm) {
    int b = blockIdx.x >> 4, s = blockIdx.x & 15;
    int c = threadIdx.x;
    const float* crow = ctx + ((size_t)(b * 8 + (c >> 5)) * 32 + (c & 31)) * 1024 + s * 64;
    float sc = 0.f, sx = 0.f;
    for (int n = 0; n < 64; ++n) {
        sc += crow[n];
        sx += x[((size_t)b * Nn + s * 64 + n) * Cc + c];
    }
    pcm[(size_t)blockIdx.x * 256 + c] = sc;
    pxm[(size_t)blockIdx.x * 256 + c] = sx;
}

// ---------------- K4: final proj(mean) + residual-mean + fc ----------------
__global__ __launch_bounds__(256) void final_kernel(const float* __restrict__ pcm,
                                                    const float* __restrict__ pxm,
                                                    const float* __restrict__ pw,
                                                    const float* __restrict__ pb,
                                                    const float* __restrict__ fcw,
                                                    const float* __restrict__ fcb,
                                                    float* __restrict__ out) {
    __shared__ float cm[256], xm[256], mrow[256];
    int b = blockIdx.x;
    int c = threadIdx.x;
    float sc = 0.f, sx = 0.f;
    for (int s2 = 0; s2 < 16; ++s2) {
        sc += pcm[((size_t)b * 16 + s2) * 256 + c];
        sx += pxm[((size_t)b * 16 + s2) * 256 + c];
    }
    cm[c] = sc * (1.f / 1024.f);
    xm[c] = sx * (1.f / 1024.f);
    __syncthreads();
    float acc = pb[c] + xm[c];
    for (int c2 = 0; c2 < 256; ++c2) acc = fmaf(cm[c2], pw[(size_t)c * 256 + c2], acc);
    mrow[c] = acc;
    __syncthreads();
    if (c < 15) {
        float a2 = fcb[c];
        for (int c2 = 0; c2 < 256; ++c2) a2 = fmaf(mrow[c2], fcw[(size_t)c * 256 + c2], a2);
        out[b * 15 + c] = a2;
    }
}

extern "C" void kernel_launch(void* const* d_in, const int* in_sizes, int n_in,
                              void* d_out, int out_size, void* d_ws, size_t ws_size,
                              hipStream_t stream) {
    const float* x     = (const float*)d_in[0];
    const float* qkv_w = (const float*)d_in[1];
    const float* pw    = (const float*)d_in[2];
    const float* pb    = (const float*)d_in[3];
    const float* fcw   = (const float*)d_in[4];
    const float* fcb   = (const float*)d_in[5];
    const float* rpek  = (const float*)d_in[6];
    const float* rpeq  = (const float*)d_in[7];
    const float* rpev  = (const float*)d_in[8];
    float* out = (float*)d_out;

    const size_t QW = (size_t)Bq * Hh * Nn * HDd;  // 2,097,152
    float* wsf = (float*)d_ws;
    float* q   = wsf;
    float* kk  = q + QW;
    float* vv  = kk + QW;
    float* ctx = vv + QW;
    float* pcm = ctx + QW;
    float* pxm = pcm + 32768;

    hipFuncSetAttribute((const void*)attn_mfma,
                        hipFuncAttributeMaxDynamicSharedMemorySize, SMEM_BYTES);

    qkv_gemm<<<dim3(12, 128), 256, 0, stream>>>(x, qkv_w, q, kk, vv);
    attn_mfma<<<2048, 256, SMEM_BYTES, stream>>>(q, kk, vv, rpek, rpeq, rpev, ctx);
    reduce_partial<<<128, 256, 0, stream>>>(ctx, x, pcm, pxm);
    final_kernel<<<8, 256, 0, stream>>>(pcm, pxm, pw, pb, fcw, fcb, out);
}

// Round 12
// 489.585 us; speedup vs baseline: 2.9875x; 1.0008x over previous
//
#include <hip/hip_runtime.h>
#include <math.h>

#define Bq 8
#define Nn 1024
#define Cc 256
#define Hh 8
#define HDd 32
#define Ll 225
#define SCALE 0.17677669529663687f
#define LOG2E 1.44269504088896f
#define THRr 8.0f

typedef __fp16 f16;
typedef __fp16 half8 __attribute__((ext_vector_type(8)));
typedef __fp16 half2t __attribute__((ext_vector_type(2)));
typedef float float4v __attribute__((ext_vector_type(4)));

// ---------------- K1: QKV projection (tiled SGEMM, f32) ----------------
__global__ __launch_bounds__(256) void qkv_gemm(const float* __restrict__ x,
                                                const float* __restrict__ w,
                                                float* __restrict__ q,
                                                float* __restrict__ k,
                                                float* __restrict__ v) {
    __shared__ float As[16][65];
    __shared__ float Bs[16][65];
    const int tix = threadIdx.x;
    const int tx = tix & 15, ty = tix >> 4;
    const int row0 = blockIdx.y * 64;
    const int col0 = blockIdx.x * 64;
    float acc[4][4] = {};
    for (int k0 = 0; k0 < Cc; k0 += 16) {
#pragma unroll
        for (int r = 0; r < 4; ++r) {
            int idx = tix + r * 256;
            int m = idx >> 4, kk = idx & 15;
            As[kk][m] = x[(size_t)(row0 + m) * Cc + k0 + kk];
            Bs[kk][m] = w[(size_t)(col0 + m) * Cc + k0 + kk];
        }
        __syncthreads();
#pragma unroll
        for (int kk = 0; kk < 16; ++kk) {
            float a[4], b[4];
#pragma unroll
            for (int i = 0; i < 4; ++i) a[i] = As[kk][ty * 4 + i];
#pragma unroll
            for (int j = 0; j < 4; ++j) b[j] = Bs[kk][tx * 4 + j];
#pragma unroll
            for (int i = 0; i < 4; ++i)
#pragma unroll
                for (int j = 0; j < 4; ++j) acc[i][j] = fmaf(a[i], b[j], acc[i][j]);
        }
        __syncthreads();
    }
#pragma unroll
    for (int i = 0; i < 4; ++i) {
        int row = row0 + ty * 4 + i;
        int b = row >> 10, n = row & 1023;
#pragma unroll
        for (int j = 0; j < 4; ++j) {
            int oc = col0 + tx * 4 + j;
            int which = oc >> 8;
            int h = (oc >> 5) & 7;
            int d = oc & 31;
            float* dst = (which == 0) ? q : ((which == 1) ? k : v);
            dst[(((size_t)b * Hh + h) * Nn + n) * HDd + d] = acc[i][j];
        }
    }
}

// ---------------- K2: barrier-free fused iRPE attention, phase-batched LDS ----------------
#define OFF_RQ 0
#define OFF_TK 20480
#define OFF_A  34944
#define OFF_M  68224
#define OFF_Z  69248
#define SMEM_BYTES 70272
#define ASTR 260

__device__ __forceinline__ int iclamp7(int x) {
    return x < -7 ? -7 : (x > 7 ? 7 : x);
}
__device__ __forceinline__ float bperm_f(int addr, float v) {
    int r = __builtin_amdgcn_ds_bpermute(addr, __builtin_bit_cast(int, v));
    return __builtin_bit_cast(float, r);
}
__device__ __forceinline__ half8 pack8(float4v a, float4v b) {
    union { half8 v8; half2t hh[4]; } u;
    u.hh[0] = __builtin_amdgcn_cvt_pkrtz(a[0], a[1]);
    u.hh[1] = __builtin_amdgcn_cvt_pkrtz(a[2], a[3]);
    u.hh[2] = __builtin_amdgcn_cvt_pkrtz(b[0], b[1]);
    u.hh[3] = __builtin_amdgcn_cvt_pkrtz(b[2], b[3]);
    return u.v8;
}

__global__ __launch_bounds__(256, 2) __attribute__((amdgpu_waves_per_eu(2, 2)))
void attn_mfma(
    const float* __restrict__ q, const float* __restrict__ k, const float* __restrict__ v,
    const float* __restrict__ rpek, const float* __restrict__ rpeq, const float* __restrict__ rpev,
    float* __restrict__ ctx)
{
    extern __shared__ char smem[];
    f16*   sRQ = (f16*)(smem + OFF_RQ);
    f16*   sTK = (f16*)(smem + OFF_TK);
    float* sA  = (float*)(smem + OFF_A);
    float* sO  = (float*)(smem + OFF_TK);   // epilogue alias
    float* sM4 = (float*)(smem + OFF_M);
    float* sZ4 = (float*)(smem + OFF_Z);

    const int tid = threadIdx.x;
    const int lane = tid & 63;
    const int w = tid >> 6;
    const int li = lane & 15;
    const int g = lane >> 4;
    const int blk = blockIdx.x;
    const int bh = blk >> 5;
    const int h = bh & 7;
    const int i0 = (blk & 31) << 5;
    const int ri = blk & 31;
    const size_t kvbase = (size_t)bh * (Nn * HDd);

    int dcc00[4], dcc01[4], dcc10[4], dcc11[4];
#pragma unroll
    for (int r = 0; r < 4; ++r) {
        dcc00[r] = iclamp7(li - (4 * g + r));
        dcc01[r] = iclamp7(16 + li - (4 * g + r));
        dcc10[r] = iclamp7(li - (16 + 4 * g + r));
        dcc11[r] = iclamp7(16 + li - (16 + 4 * g + r));
    }
    const int g16c = (g * 16 + 7) * 4;
    const int paA = (((2 * g) & 3) * 16 + li) * 4;
    const int paB = (((2 * g + 1) & 3) * 16 + li) * 4;
    const bool glow = (g < 2);

    // zero sA
    {
        float4v zz = {0.f, 0.f, 0.f, 0.f};
        for (int idx = tid; idx < 32 * ASTR / 4; idx += 256)
            ((float4v*)sA)[idx] = zz;
    }
    // Q fragments directly from global
    half8 bQ0, bQ1, aQ0, aQ1;
    {
        const float4v* q0 = (const float4v*)(q + kvbase + (size_t)(i0 + li) * HDd + 8 * g);
        float4v a = q0[0] * LOG2E, b = q0[1] * LOG2E;
        aQ0 = pack8(a, b);
        const float4v* q1 = (const float4v*)(q + kvbase + (size_t)(i0 + 16 + li) * HDd + 8 * g);
        float4v c = q1[0] * LOG2E, d = q1[1] * LOG2E;
        aQ1 = pack8(c, d);
        bQ0 = aQ0; bQ1 = aQ1;
    }
    // stage sRQ = rpek[h]
    for (int idx = tid; idx < 1024; idx += 256) {
        int row = idx >> 2, d0 = (idx & 3) * 8;
        half8 val;
        if (row < Ll) {
            const float4v* src = (const float4v*)(rpek + ((size_t)h * Ll + row) * HDd + d0);
            val = pack8(src[0], src[1]);
        } else {
            float4v z4 = {0.f, 0.f, 0.f, 0.f};
            val = pack8(z4, z4);
        }
        *(half8*)(sRQ + row * 40 + d0) = val;
    }
    __syncthreads();   // P1

    // tk prologue
#pragma unroll
    for (int p = 0; p < 8; ++p) {
        int u2 = w + 4 * p;
        if (u2 < 30) {
            int nt = u2 % 15, itile = u2 / 15;
            half8 bR = *(const half8*)(sRQ + (nt * 16 + li) * 40 + 8 * g);
            float4v c = {0.f, 0.f, 0.f, 0.f};
            c = __builtin_amdgcn_mfma_f32_16x16x32_f16(itile ? aQ1 : aQ0, bR, c, 0, 0, 0);
            int l = nt * 16 + li;
            if (l < Ll) {
#pragma unroll
                for (int r = 0; r < 4; ++r)
                    sTK[(itile * 16 + 4 * g + r) * 226 + l] = (f16)c[r];
            }
        }
    }
    __syncthreads();   // P2
    // restage sRQ = SCALE*LOG2E * rpeq[h]
    for (int idx = tid; idx < 1024; idx += 256) {
        int row = idx >> 2, d0 = (idx & 3) * 8;
        half8 val;
        if (row < Ll) {
            const float4v* src = (const float4v*)(rpeq + ((size_t)h * Ll + row) * HDd + d0);
            const float sc = SCALE * LOG2E;
            val = pack8(src[0] * sc, src[1] * sc);
        } else {
            float4v z4 = {0.f, 0.f, 0.f, 0.f};
            val = pack8(z4, z4);
        }
        *(half8*)(sRQ + row * 40 + d0) = val;
    }
    __syncthreads();   // P3: last barrier before epilogue

    float4v ka, kb, kc, kd;
    {
        int jt = w * 32;
        const float4v* p0 = (const float4v*)(k + kvbase + (size_t)(jt + li) * HDd + 8 * g);
        ka = p0[0]; kb = p0[1];
        const float4v* p1 = (const float4v*)(k + kvbase + (size_t)(jt + 16 + li) * HDd + 8 * g);
        kc = p1[0]; kd = p1[1];
    }

    float4v o00 = {0,0,0,0}, o01 = {0,0,0,0}, o10 = {0,0,0,0}, o11 = {0,0,0,0};
    float z_lo = 0.f, z_hi = 0.f;
    float m_lo = -1.0e30f, m_hi = -1.0e30f, pw_lo = 0.f, pw_hi = 0.f;

    for (int it = 0; it < 8; ++it) {
        const int jt = it * 128 + w * 32;
        half8 aK0 = pack8(ka, kb);
        half8 aK1 = pack8(kc, kd);
        if (it < 7) {
            int jn = (it + 1) * 128 + w * 32;
            const float4v* p0 = (const float4v*)(k + kvbase + (size_t)(jn + li) * HDd + 8 * g);
            ka = p0[0]; kb = p0[1];
            const float4v* p1 = (const float4v*)(k + kvbase + (size_t)(jn + 16 + li) * HDd + 8 * g);
            kc = p1[0]; kd = p1[1];
        }
        // V gather (vmcnt pipe; consumed at PV)
        float vx[8], vy[8];
#pragma unroll
        for (int e = 0; e < 8; ++e) {
            vx[e] = v[kvbase + (size_t)(jt + 8 * g + e) * HDd + li];
            vy[e] = v[kvbase + (size_t)(jt + 8 * g + e) * HDd + 16 + li];
        }
        // MFMAs
        float4v c0 = {0,0,0,0};
        float4v s00 = __builtin_amdgcn_mfma_f32_16x16x32_f16(aK0, bQ0, c0, 0, 0, 0);
        float4v s01 = __builtin_amdgcn_mfma_f32_16x16x32_f16(aK0, bQ1, c0, 0, 0, 0);
        float4v s10 = __builtin_amdgcn_mfma_f32_16x16x32_f16(aK1, bQ0, c0, 0, 0, 0);
        float4v s11 = __builtin_amdgcn_mfma_f32_16x16x32_f16(aK1, bQ1, c0, 0, 0, 0);
        const int dr = iclamp7(ri - (4 * it + w));
        const int w0 = (7 - dr) * 15;
        const int drb = dr * 15 + 112;
        half8 bR = *(const half8*)(sRQ + (w0 + li) * 40 + 8 * g);
        float4v t0 = __builtin_amdgcn_mfma_f32_16x16x32_f16(aK0, bR, c0, 0, 0, 0);
        float4v t1 = __builtin_amdgcn_mfma_f32_16x16x32_f16(aK1, bR, c0, 0, 0, 0);

        // ---- per-row local max (VALU) + hop1 issued before gather batch ----
        float ml = fmaxf(fmaxf(fmaxf(s00[0], s00[1]), fmaxf(s00[2], s00[3])),
                         fmaxf(fmaxf(s10[0], s10[1]), fmaxf(s10[2], s10[3])));
        float mh = fmaxf(fmaxf(fmaxf(s01[0], s01[1]), fmaxf(s01[2], s01[3])),
                         fmaxf(fmaxf(s11[0], s11[1]), fmaxf(s11[2], s11[3])));
        float ml1 = __shfl_xor(ml, 16);
        float mh1 = __shfl_xor(mh, 16);
        // ---- batched tk reads (hop1 completes in-order before these drain) ----
        const f16* tkL = sTK + li * 226;
        const f16* tkH = sTK + (16 + li) * 226;
        float tk00[4], tk10[4], tk01[4], tk11[4];
#pragma unroll
        for (int r = 0; r < 4; ++r) {
            tk00[r] = (float)tkL[drb + dcc00[r]];
            tk10[r] = (float)tkL[drb + dcc10[r]];
            tk01[r] = (float)tkH[drb + dcc01[r]];
            tk11[r] = (float)tkH[drb + dcc11[r]];
        }
        ml = fmaxf(ml, ml1);
        mh = fmaxf(mh, mh1);
        float ml2 = __shfl_xor(ml, 32);
        float mh2 = __shfl_xor(mh, 32);
        // ---- batched tq bpermutes (hop2 rides this batch) ----
        float tq00[4], tq10[4], tq01[4], tq11[4];
#pragma unroll
        for (int r = 0; r < 4; ++r) {
            tq00[r] = bperm_f(g16c - 4 * dcc00[r], t0[r]);
            tq10[r] = bperm_f(g16c - 4 * dcc10[r], t1[r]);
            tq01[r] = bperm_f(g16c - 4 * dcc01[r], t0[r]);
            tq11[r] = bperm_f(g16c - 4 * dcc11[r], t1[r]);
        }
        ml = fmaxf(ml, ml2);
        mh = fmaxf(mh, mh2);
        // per-row defer-max (P bounded in [2^-8, 2^8] -> f16-normal)
        if (ml > m_lo + THRr) {
            float f = exp2f(m_lo - ml); m_lo = ml; pw_lo = exp2f(m_lo);
            z_lo *= f; o00 *= f; o10 *= f;
        }
        if (mh > m_hi + THRr) {
            float f = exp2f(m_hi - mh); m_hi = mh; pw_hi = exp2f(m_hi);
            z_hi *= f; o01 *= f; o11 *= f;
        }
        // ---- VALU phase: biased s, exp2, z ----
        float p00[4], p01[4], p10[4], p11[4];
#pragma unroll
        for (int r = 0; r < 4; ++r) {
            p00[r] = exp2f(s00[r] + tk00[r] + tq00[r] - m_lo);
            p10[r] = exp2f(s10[r] + tk10[r] + tq10[r] - m_lo);
            p01[r] = exp2f(s01[r] + tk01[r] + tq01[r] - m_hi);
            p11[r] = exp2f(s11[r] + tk11[r] + tq11[r] - m_hi);
        }
#pragma unroll
        for (int r = 0; r < 4; ++r) {
            z_lo += p00[r] + p10[r];
            z_hi += p01[r] + p11[r];
        }
        // pack P words
        int pl01 = __builtin_bit_cast(int, __builtin_amdgcn_cvt_pkrtz(p00[0], p00[1]));
        int pl23 = __builtin_bit_cast(int, __builtin_amdgcn_cvt_pkrtz(p00[2], p00[3]));
        int ph01 = __builtin_bit_cast(int, __builtin_amdgcn_cvt_pkrtz(p10[0], p10[1]));
        int ph23 = __builtin_bit_cast(int, __builtin_amdgcn_cvt_pkrtz(p10[2], p10[3]));
        int ql01 = __builtin_bit_cast(int, __builtin_amdgcn_cvt_pkrtz(p01[0], p01[1]));
        int ql23 = __builtin_bit_cast(int, __builtin_amdgcn_cvt_pkrtz(p01[2], p01[3]));
        int qh01 = __builtin_bit_cast(int, __builtin_amdgcn_cvt_pkrtz(p11[0], p11[1]));
        int qh23 = __builtin_bit_cast(int, __builtin_amdgcn_cvt_pkrtz(p11[2], p11[3]));
        // ---- P-exchange bpermutes (batched) ----
        int rA0 = __builtin_amdgcn_ds_bpermute(paA, pl01);
        int rA1 = __builtin_amdgcn_ds_bpermute(paA, pl23);
        int rA2 = __builtin_amdgcn_ds_bpermute(paA, ph01);
        int rA3 = __builtin_amdgcn_ds_bpermute(paA, ph23);
        int rB0 = __builtin_amdgcn_ds_bpermute(paB, pl01);
        int rB1 = __builtin_amdgcn_ds_bpermute(paB, pl23);
        int rB2 = __builtin_amdgcn_ds_bpermute(paB, ph01);
        int rB3 = __builtin_amdgcn_ds_bpermute(paB, ph23);
        int uA0 = __builtin_amdgcn_ds_bpermute(paA, ql01);
        int uA1 = __builtin_amdgcn_ds_bpermute(paA, ql23);
        int uA2 = __builtin_amdgcn_ds_bpermute(paA, qh01);
        int uA3 = __builtin_amdgcn_ds_bpermute(paA, qh23);
        int uB0 = __builtin_amdgcn_ds_bpermute(paB, ql01);
        int uB1 = __builtin_amdgcn_ds_bpermute(paB, ql23);
        int uB2 = __builtin_amdgcn_ds_bpermute(paB, qh01);
        int uB3 = __builtin_amdgcn_ds_bpermute(paB, qh23);
        // ---- atomics LAST (fire-and-forget) ----
        {
            float* aL = sA + li * ASTR;
            float* aH = sA + (16 + li) * ASTR;
#pragma unroll
            for (int r = 0; r < 4; ++r) {
                unsafeAtomicAdd(aL + drb + dcc00[r], p00[r] * pw_lo);
                unsafeAtomicAdd(aL + drb + dcc10[r], p10[r] * pw_lo);
                unsafeAtomicAdd(aH + drb + dcc01[r], p01[r] * pw_hi);
                unsafeAtomicAdd(aH + drb + dcc11[r], p11[r] * pw_hi);
            }
        }
        // build fragments + PV
        union { half8 v8; int w4[4]; } pAlo, pAhi;
        pAlo.w4[0] = glow ? rA0 : rA2;
        pAlo.w4[1] = glow ? rA1 : rA3;
        pAlo.w4[2] = glow ? rB0 : rB2;
        pAlo.w4[3] = glow ? rB1 : rB3;
        pAhi.w4[0] = glow ? uA0 : uA2;
        pAhi.w4[1] = glow ? uA1 : uA3;
        pAhi.w4[2] = glow ? uB0 : uB2;
        pAhi.w4[3] = glow ? uB1 : uB3;
        union { half8 v8; half2t hh[4]; } aV0, aV1;
        aV0.hh[0] = __builtin_amdgcn_cvt_pkrtz(vx[0], vx[1]);
        aV0.hh[1] = __builtin_amdgcn_cvt_pkrtz(vx[2], vx[3]);
        aV0.hh[2] = __builtin_amdgcn_cvt_pkrtz(vx[4], vx[5]);
        aV0.hh[3] = __builtin_amdgcn_cvt_pkrtz(vx[6], vx[7]);
        aV1.hh[0] = __builtin_amdgcn_cvt_pkrtz(vy[0], vy[1]);
        aV1.hh[1] = __builtin_amdgcn_cvt_pkrtz(vy[2], vy[3]);
        aV1.hh[2] = __builtin_amdgcn_cvt_pkrtz(vy[4], vy[5]);
        aV1.hh[3] = __builtin_amdgcn_cvt_pkrtz(vy[6], vy[7]);
        o00 = __builtin_amdgcn_mfma_f32_16x16x32_f16(aV0.v8, pAlo.v8, o00, 0, 0, 0);
        o01 = __builtin_amdgcn_mfma_f32_16x16x32_f16(aV0.v8, pAhi.v8, o01, 0, 0, 0);
        o10 = __builtin_amdgcn_mfma_f32_16x16x32_f16(aV1.v8, pAlo.v8, o10, 0, 0, 0);
        o11 = __builtin_amdgcn_mfma_f32_16x16x32_f16(aV1.v8, pAhi.v8, o11, 0, 0, 0);
    }

    // -------- epilogue --------
    z_lo += __shfl_xor(z_lo, 16); z_lo += __shfl_xor(z_lo, 32);
    z_hi += __shfl_xor(z_hi, 16); z_hi += __shfl_xor(z_hi, 32);
    if (g == 0) {
        sM4[w * 64 + li] = m_lo;  sM4[w * 64 + 32 + li] = m_hi;
        sZ4[w * 64 + li] = z_lo;  sZ4[w * 64 + 32 + li] = z_hi;
    }
    __syncthreads();   // E1
    if (w > 0) {
        float* ob = sO + (w - 1) * 1152;
#pragma unroll
        for (int r = 0; r < 4; ++r) {
            ob[li * 36 + 4 * g + r]             = o00[r];
            ob[li * 36 + 16 + 4 * g + r]        = o10[r];
            ob[(16 + li) * 36 + 4 * g + r]      = o01[r];
            ob[(16 + li) * 36 + 16 + 4 * g + r] = o11[r];
        }
    }
    for (int idx = tid; idx < 1024; idx += 256) {
        int row = idx >> 2, d0 = (idx & 3) * 8;
        half8 val;
        if (row < Ll) {
            const float4v* src = (const float4v*)(rpev + ((size_t)h * Ll + row) * HDd + d0);
            val = pack8(src[0], src[1]);
        } else {
            float4v z4 = {0.f, 0.f, 0.f, 0.f};
            val = pack8(z4, z4);
        }
        *(half8*)(sRQ + row * 40 + d0) = val;
    }
    __syncthreads();   // E2
    if (w == 0) {
        float fL0, fL1, fL2, fL3, rzL, rzAL;
        {
            float m0 = sM4[li], m1 = sM4[64 + li], m2 = sM4[128 + li], m3 = sM4[192 + li];
            float ms = fmaxf(fmaxf(m0, m1), fmaxf(m2, m3));
            fL0 = exp2f(m0 - ms); fL1 = exp2f(m1 - ms); fL2 = exp2f(m2 - ms); fL3 = exp2f(m3 - ms);
            float zt = sZ4[li] * fL0 + sZ4[64 + li] * fL1 + sZ4[128 + li] * fL2 + sZ4[192 + li] * fL3;
            rzL = 1.0f / zt;
            rzAL = exp2f(-ms) * rzL;
        }
        float fH0, fH1, fH2, fH3, rzH, rzAH;
        {
            int ih = 32 + li;
            float m0 = sM4[ih], m1 = sM4[64 + ih], m2 = sM4[128 + ih], m3 = sM4[192 + ih];
            float ms = fmaxf(fmaxf(m0, m1), fmaxf(m2, m3));
            fH0 = exp2f(m0 - ms); fH1 = exp2f(m1 - ms); fH2 = exp2f(m2 - ms); fH3 = exp2f(m3 - ms);
            float zt = sZ4[ih] * fH0 + sZ4[64 + ih] * fH1 + sZ4[128 + ih] * fH2 + sZ4[192 + ih] * fH3;
            rzH = 1.0f / zt;
            rzAH = exp2f(-ms) * rzH;
        }
#pragma unroll
        for (int r = 0; r < 4; ++r) {
            int dlo = 4 * g + r, dhi = 16 + 4 * g + r;
            o00[r] = (o00[r] * fL0 + sO[li * 36 + dlo] * fL1
                      + sO[1152 + li * 36 + dlo] * fL2 + sO[2304 + li * 36 + dlo] * fL3) * rzL;
            o10[r] = (o10[r] * fL0 + sO[li * 36 + dhi] * fL1
                      + sO[1152 + li * 36 + dhi] * fL2 + sO[2304 + li * 36 + dhi] * fL3) * rzL;
            o01[r] = (o01[r] * fH0 + sO[(16 + li) * 36 + dlo] * fH1
                      + sO[1152 + (16 + li) * 36 + dlo] * fH2 + sO[2304 + (16 + li) * 36 + dlo] * fH3) * rzH;
            o11[r] = (o11[r] * fH0 + sO[(16 + li) * 36 + dhi] * fH1
                      + sO[1152 + (16 + li) * 36 + dhi] * fH2 + sO[2304 + (16 + li) * 36 + dhi] * fH3) * rzH;
        }
#pragma unroll
        for (int ks = 0; ks < 8; ++ks) {
            const int kbase = ks * 32 + 8 * g;
            float4v aL0 = *(const float4v*)(sA + li * ASTR + kbase);
            float4v aL1 = *(const float4v*)(sA + li * ASTR + kbase + 4);
            float4v aH0 = *(const float4v*)(sA + (16 + li) * ASTR + kbase);
            float4v aH1 = *(const float4v*)(sA + (16 + li) * ASTR + kbase + 4);
            union { half8 v8; half2t hh[4]; } fAL, fAH;
            fAL.hh[0] = __builtin_amdgcn_cvt_pkrtz(aL0[0] * rzAL, aL0[1] * rzAL);
            fAL.hh[1] = __builtin_amdgcn_cvt_pkrtz(aL0[2] * rzAL, aL0[3] * rzAL);
            fAL.hh[2] = __builtin_amdgcn_cvt_pkrtz(aL1[0] * rzAL, aL1[1] * rzAL);
            fAL.hh[3] = __builtin_amdgcn_cvt_pkrtz(aL1[2] * rzAL, aL1[3] * rzAL);
            fAH.hh[0] = __builtin_amdgcn_cvt_pkrtz(aH0[0] * rzAH, aH0[1] * rzAH);
            fAH.hh[1] = __builtin_amdgcn_cvt_pkrtz(aH0[2] * rzAH, aH0[3] * rzAH);
            fAH.hh[2] = __builtin_amdgcn_cvt_pkrtz(aH1[0] * rzAH, aH1[1] * rzAH);
            fAH.hh[3] = __builtin_amdgcn_cvt_pkrtz(aH1[2] * rzAH, aH1[3] * rzAH);
            union { half8 v8; f16 e[8]; } BL, BH;
#pragma unroll
            for (int e = 0; e < 8; ++e) {
                BL.e[e] = sRQ[(kbase + e) * 40 + li];
                BH.e[e] = sRQ[(kbase + e) * 40 + 16 + li];
            }
            o00 = __builtin_amdgcn_mfma_f32_16x16x32_f16(BL.v8, fAL.v8, o00, 0, 0, 0);
            o01 = __builtin_amdgcn_mfma_f32_16x16x32_f16(BL.v8, fAH.v8, o01, 0, 0, 0);
            o10 = __builtin_amdgcn_mfma_f32_16x16x32_f16(BH.v8, fAL.v8, o10, 0, 0, 0);
            o11 = __builtin_amdgcn_mfma_f32_16x16x32_f16(BH.v8, fAH.v8, o11, 0, 0, 0);
        }
        float* cb = ctx + (size_t)bh * 32 * 1024 + i0;
#pragma unroll
        for (int r = 0; r < 4; ++r) {
            cb[(size_t)(4 * g + r) * 1024 + li]           = o00[r];
            cb[(size_t)(4 * g + r) * 1024 + 16 + li]      = o01[r];
            cb[(size_t)(16 + 4 * g + r) * 1024 + li]      = o10[r];
            cb[(size_t)(16 + 4 * g + r) * 1024 + 16 + li] = o11[r];
        }
    }
}

// ---------------- K3: partial mean over tokens ----------------
__global__ __launch_bounds__(256) void reduce_partial(const float* __restrict__ ctx,
                                                      const float* __restrict__ x,
                                                      float* __restrict__ pcm,
                                                      float* __restrict__ pxm) {
    int b = blockIdx.x >> 4, s = blockIdx.x & 15;
    int c = threadIdx.x;
    const float* crow = ctx + ((size_t)(b * 8 + (c >> 5)) * 32 + (c & 31)) * 1024 + s * 64;
    float sc = 0.f, sx = 0.f;
    for (int n = 0; n < 64; ++n) {
        sc += crow[n];
        sx += x[((size_t)b * Nn + s * 64 + n) * Cc + c];
    }
    pcm[(size_t)blockIdx.x * 256 + c] = sc;
    pxm[(size_t)blockIdx.x * 256 + c] = sx;
}

// ---------------- K4: final proj(mean) + residual-mean + fc ----------------
__global__ __launch_bounds__(256) void final_kernel(const float* __restrict__ pcm,
                                                    const float* __restrict__ pxm,
                                                    const float* __restrict__ pw,
                                                    const float* __restrict__ pb,
                                                    const float* __restrict__ fcw,
                                                    const float* __restrict__ fcb,
                                                    float* __restrict__ out) {
    __shared__ float cm[256], xm[256], mrow[256];
    int b = blockIdx.x;
    int c = threadIdx.x;
    float sc = 0.f, sx = 0.f;
    for (int s2 = 0; s2 < 16; ++s2) {
        sc += pcm[((size_t)b * 16 + s2) * 256 + c];
        sx += pxm[((size_t)b * 16 + s2) * 256 + c];
    }
    cm[c] = sc * (1.f / 1024.f);
    xm[c] = sx * (1.f / 1024.f);
    __syncthreads();
    float acc = pb[c] + xm[c];
    for (int c2 = 0; c2 < 256; ++c2) acc = fmaf(cm[c2], pw[(size_t)c * 256 + c2], acc);
    mrow[c] = acc;
    __syncthreads();
    if (c < 15) {
        float a2 = fcb[c];
        for (int c2 = 0; c2 < 256; ++c2) a2 = fmaf(mrow[c2], fcw[(size_t)c * 256 + c2], a2);
        out[b * 15 + c] = a2;
    }
}

extern "C" void kernel_launch(void* const* d_in, const int* in_sizes, int n_in,
                              void* d_out, int out_size, void* d_ws, size_t ws_size,
                              hipStream_t stream) {
    const float* x     = (const float*)d_in[0];
    const float* qkv_w = (const float*)d_in[1];
    const float* pw    = (const float*)d_in[2];
    const float* pb    = (const float*)d_in[3];
    const float* fcw   = (const float*)d_in[4];
    const float* fcb   = (const float*)d_in[5];
    const float* rpek  = (const float*)d_in[6];
    const float* rpeq  = (const float*)d_in[7];
    const float* rpev  = (const float*)d_in[8];
    float* out = (float*)d_out;

    const size_t QW = (size_t)Bq * Hh * Nn * HDd;  // 2,097,152
    float* wsf = (float*)d_ws;
    float* q   = wsf;
    float* kk  = q + QW;
    float* vv  = kk + QW;
    float* ctx = vv + QW;
    float* pcm = ctx + QW;
    float* pxm = pcm + 32768;

    hipFuncSetAttribute((const void*)attn_mfma,
                        hipFuncAttributeMaxDynamicSharedMemorySize, SMEM_BYTES);

    qkv_gemm<<<dim3(12, 128), 256, 0, stream>>>(x, qkv_w, q, kk, vv);
    attn_mfma<<<2048, 256, SMEM_BYTES, stream>>>(q, kk, vv, rpek, rpeq, rpev, ctx);
    reduce_partial<<<128, 256, 0, stream>>>(ctx, x, pcm, pxm);
    final_kernel<<<8, 256, 0, stream>>>(pcm, pxm, pw, pb, fcw, fcb, out);
}

// Round 13
// 487.591 us; speedup vs baseline: 2.9997x; 1.0041x over previous
//
#include <hip/hip_runtime.h>
#include <math.h>

#define Bq 8
#define Nn 1024
#define Cc 256
#define Hh 8
#define HDd 32
#define Ll 225
#define SCALE 0.17677669529663687f
#define LOG2E 1.44269504088896f
#define THRr 8.0f

typedef __fp16 f16;
typedef __fp16 half8 __attribute__((ext_vector_type(8)));
typedef __fp16 half2t __attribute__((ext_vector_type(2)));
typedef float float4v __attribute__((ext_vector_type(4)));

// ---------------- K1: QKV projection (tiled SGEMM, f32 -> f16 outputs) ----------------
__global__ __launch_bounds__(256) void qkv_gemm(const float* __restrict__ x,
                                                const float* __restrict__ w,
                                                f16* __restrict__ q16,
                                                f16* __restrict__ k16,
                                                f16* __restrict__ v16) {
    __shared__ float As[16][65];
    __shared__ float Bs[16][65];
    const int tix = threadIdx.x;
    const int tx = tix & 15, ty = tix >> 4;
    const int row0 = blockIdx.y * 64;
    const int col0 = blockIdx.x * 64;
    float acc[4][4] = {};
    for (int k0 = 0; k0 < Cc; k0 += 16) {
#pragma unroll
        for (int r = 0; r < 4; ++r) {
            int idx = tix + r * 256;
            int m = idx >> 4, kk = idx & 15;
            As[kk][m] = x[(size_t)(row0 + m) * Cc + k0 + kk];
            Bs[kk][m] = w[(size_t)(col0 + m) * Cc + k0 + kk];
        }
        __syncthreads();
#pragma unroll
        for (int kk = 0; kk < 16; ++kk) {
            float a[4], b[4];
#pragma unroll
            for (int i = 0; i < 4; ++i) a[i] = As[kk][ty * 4 + i];
#pragma unroll
            for (int j = 0; j < 4; ++j) b[j] = Bs[kk][tx * 4 + j];
#pragma unroll
            for (int i = 0; i < 4; ++i)
#pragma unroll
                for (int j = 0; j < 4; ++j) acc[i][j] = fmaf(a[i], b[j], acc[i][j]);
        }
        __syncthreads();
    }
#pragma unroll
    for (int i = 0; i < 4; ++i) {
        int row = row0 + ty * 4 + i;
        int b = row >> 10, n = row & 1023;
#pragma unroll
        for (int j = 0; j < 4; ++j) {
            int oc = col0 + tx * 4 + j;
            int which = oc >> 8;
            int h = (oc >> 5) & 7;
            int d = oc & 31;
            f16* dst = (which == 0) ? q16 : ((which == 1) ? k16 : v16);
            float scl = (which == 0) ? LOG2E : 1.0f;
            dst[(((size_t)b * Hh + h) * Nn + n) * HDd + d] = (f16)(acc[i][j] * scl);
        }
    }
}

// ---------------- K2: barrier-free fused iRPE attention ----------------
#define OFF_RQ 0
#define OFF_TK 20480
#define OFF_A  34944
#define OFF_M  68224
#define OFF_Z  69248
#define SMEM_BYTES 70272
#define ASTR 260

__device__ __forceinline__ int iclamp7(int x) {
    return x < -7 ? -7 : (x > 7 ? 7 : x);
}
__device__ __forceinline__ float bperm_f(int addr, float v) {
    int r = __builtin_amdgcn_ds_bpermute(addr, __builtin_bit_cast(int, v));
    return __builtin_bit_cast(float, r);
}
__device__ __forceinline__ float fexp2(float x) {
    float r;
    asm("v_exp_f32 %0, %1" : "=v"(r) : "v"(x));
    return r;
}
__device__ __forceinline__ half8 pack8(float4v a, float4v b) {
    union { half8 v8; half2t hh[4]; } u;
    u.hh[0] = __builtin_amdgcn_cvt_pkrtz(a[0], a[1]);
    u.hh[1] = __builtin_amdgcn_cvt_pkrtz(a[2], a[3]);
    u.hh[2] = __builtin_amdgcn_cvt_pkrtz(b[0], b[1]);
    u.hh[3] = __builtin_amdgcn_cvt_pkrtz(b[2], b[3]);
    return u.v8;
}

__global__ __launch_bounds__(256, 1) void attn_mfma(
    const f16* __restrict__ q16, const f16* __restrict__ k16, const f16* __restrict__ v16,
    const float* __restrict__ rpek, const float* __restrict__ rpeq, const float* __restrict__ rpev,
    float* __restrict__ ctx)
{
    extern __shared__ char smem[];
    f16*   sRQ = (f16*)(smem + OFF_RQ);
    f16*   sTK = (f16*)(smem + OFF_TK);
    float* sA  = (float*)(smem + OFF_A);
    float* sO  = (float*)(smem + OFF_TK);   // epilogue alias
    float* sM4 = (float*)(smem + OFF_M);
    float* sZ4 = (float*)(smem + OFF_Z);

    const int tid = threadIdx.x;
    const int lane = tid & 63;
    const int w = tid >> 6;
    const int li = lane & 15;
    const int g = lane >> 4;
    const int blk = blockIdx.x;
    const int bh = blk >> 5;
    const int h = bh & 7;
    const int i0 = (blk & 31) << 5;
    const int ri = blk & 31;
    const size_t kvbase = (size_t)bh * (Nn * HDd);

    int dcc00[4], dcc01[4], dcc10[4], dcc11[4];
#pragma unroll
    for (int r = 0; r < 4; ++r) {
        dcc00[r] = iclamp7(li - (4 * g + r));
        dcc01[r] = iclamp7(16 + li - (4 * g + r));
        dcc10[r] = iclamp7(li - (16 + 4 * g + r));
        dcc11[r] = iclamp7(16 + li - (16 + 4 * g + r));
    }
    const int g16c = (g * 16 + 7) * 4;
    const int paA = (((2 * g) & 3) * 16 + li) * 4;
    const int paB = (((2 * g + 1) & 3) * 16 + li) * 4;
    const bool glow = (g < 2);

    // zero sA
    {
        float4v zz = {0.f, 0.f, 0.f, 0.f};
        for (int idx = tid; idx < 32 * ASTR / 4; idx += 256)
            ((float4v*)sA)[idx] = zz;
    }
    // Q fragments directly from global f16 (LOG2E prefolded)
    half8 bQ0, bQ1, aQ0, aQ1;
    {
        aQ0 = *(const half8*)(q16 + kvbase + (size_t)(i0 + li) * HDd + 8 * g);
        aQ1 = *(const half8*)(q16 + kvbase + (size_t)(i0 + 16 + li) * HDd + 8 * g);
        bQ0 = aQ0; bQ1 = aQ1;
    }
    // stage sRQ = rpek[h]
    for (int idx = tid; idx < 1024; idx += 256) {
        int row = idx >> 2, d0 = (idx & 3) * 8;
        half8 val;
        if (row < Ll) {
            const float4v* src = (const float4v*)(rpek + ((size_t)h * Ll + row) * HDd + d0);
            val = pack8(src[0], src[1]);
        } else {
            float4v z4 = {0.f, 0.f, 0.f, 0.f};
            val = pack8(z4, z4);
        }
        *(half8*)(sRQ + row * 40 + d0) = val;
    }
    __syncthreads();   // P1

    // tk prologue
#pragma unroll
    for (int p = 0; p < 8; ++p) {
        int u2 = w + 4 * p;
        if (u2 < 30) {
            int nt = u2 % 15, itile = u2 / 15;
            half8 bR = *(const half8*)(sRQ + (nt * 16 + li) * 40 + 8 * g);
            float4v c = {0.f, 0.f, 0.f, 0.f};
            c = __builtin_amdgcn_mfma_f32_16x16x32_f16(itile ? aQ1 : aQ0, bR, c, 0, 0, 0);
            int l = nt * 16 + li;
            if (l < Ll) {
#pragma unroll
                for (int r = 0; r < 4; ++r)
                    sTK[(itile * 16 + 4 * g + r) * 226 + l] = (f16)c[r];
            }
        }
    }
    __syncthreads();   // P2
    // restage sRQ = SCALE*LOG2E * rpeq[h]
    for (int idx = tid; idx < 1024; idx += 256) {
        int row = idx >> 2, d0 = (idx & 3) * 8;
        half8 val;
        if (row < Ll) {
            const float4v* src = (const float4v*)(rpeq + ((size_t)h * Ll + row) * HDd + d0);
            const float sc = SCALE * LOG2E;
            val = pack8(src[0] * sc, src[1] * sc);
        } else {
            float4v z4 = {0.f, 0.f, 0.f, 0.f};
            val = pack8(z4, z4);
        }
        *(half8*)(sRQ + row * 40 + d0) = val;
    }
    __syncthreads();   // P3: last barrier before epilogue

    // K prefetch for tile 0 (direct f16 fragments)
    half8 aK0c, aK1c;
    {
        int jt = w * 32;
        aK0c = *(const half8*)(k16 + kvbase + (size_t)(jt + li) * HDd + 8 * g);
        aK1c = *(const half8*)(k16 + kvbase + (size_t)(jt + 16 + li) * HDd + 8 * g);
    }
    const unsigned short* v16u = (const unsigned short*)(v16 + kvbase);

    float4v o00 = {0,0,0,0}, o01 = {0,0,0,0}, o10 = {0,0,0,0}, o11 = {0,0,0,0};
    float z_lo = 0.f, z_hi = 0.f;
    float m_lo = -1.0e30f, m_hi = -1.0e30f, pw_lo = 0.f, pw_hi = 0.f;

    for (int it = 0; it < 8; ++it) {
        const int jt = it * 128 + w * 32;
        half8 aK0 = aK0c;
        half8 aK1 = aK1c;
        if (it < 7) {
            int jn = (it + 1) * 128 + w * 32;
            aK0c = *(const half8*)(k16 + kvbase + (size_t)(jn + li) * HDd + 8 * g);
            aK1c = *(const half8*)(k16 + kvbase + (size_t)(jn + 16 + li) * HDd + 8 * g);
        }
        // V gather (u16; consumed at PV)
        union { half8 v8; unsigned short s[8]; } aV0u, aV1u;
#pragma unroll
        for (int e = 0; e < 8; ++e) {
            aV0u.s[e] = v16u[(size_t)(jt + 8 * g + e) * HDd + li];
            aV1u.s[e] = v16u[(size_t)(jt + 8 * g + e) * HDd + 16 + li];
        }
        // MFMAs
        float4v c0 = {0,0,0,0};
        float4v s00 = __builtin_amdgcn_mfma_f32_16x16x32_f16(aK0, bQ0, c0, 0, 0, 0);
        float4v s01 = __builtin_amdgcn_mfma_f32_16x16x32_f16(aK0, bQ1, c0, 0, 0, 0);
        float4v s10 = __builtin_amdgcn_mfma_f32_16x16x32_f16(aK1, bQ0, c0, 0, 0, 0);
        float4v s11 = __builtin_amdgcn_mfma_f32_16x16x32_f16(aK1, bQ1, c0, 0, 0, 0);
        const int dr = iclamp7(ri - (4 * it + w));
        const int w0 = (7 - dr) * 15;
        const int drb = dr * 15 + 112;
        half8 bR = *(const half8*)(sRQ + (w0 + li) * 40 + 8 * g);
        float4v t0 = __builtin_amdgcn_mfma_f32_16x16x32_f16(aK0, bR, c0, 0, 0, 0);
        float4v t1 = __builtin_amdgcn_mfma_f32_16x16x32_f16(aK1, bR, c0, 0, 0, 0);

        // per-row local max + hop1
        float ml = fmaxf(fmaxf(fmaxf(s00[0], s00[1]), fmaxf(s00[2], s00[3])),
                         fmaxf(fmaxf(s10[0], s10[1]), fmaxf(s10[2], s10[3])));
        float mh = fmaxf(fmaxf(fmaxf(s01[0], s01[1]), fmaxf(s01[2], s01[3])),
                         fmaxf(fmaxf(s11[0], s11[1]), fmaxf(s11[2], s11[3])));
        float ml1 = __shfl_xor(ml, 16);
        float mh1 = __shfl_xor(mh, 16);
        // batched tk reads
        const f16* tkL = sTK + li * 226;
        const f16* tkH = sTK + (16 + li) * 226;
        float tk00[4], tk10[4], tk01[4], tk11[4];
#pragma unroll
        for (int r = 0; r < 4; ++r) {
            tk00[r] = (float)tkL[drb + dcc00[r]];
            tk10[r] = (float)tkL[drb + dcc10[r]];
            tk01[r] = (float)tkH[drb + dcc01[r]];
            tk11[r] = (float)tkH[drb + dcc11[r]];
        }
        ml = fmaxf(ml, ml1);
        mh = fmaxf(mh, mh1);
        float ml2 = __shfl_xor(ml, 32);
        float mh2 = __shfl_xor(mh, 32);
        // batched tq bpermutes
        float tq00[4], tq10[4], tq01[4], tq11[4];
#pragma unroll
        for (int r = 0; r < 4; ++r) {
            tq00[r] = bperm_f(g16c - 4 * dcc00[r], t0[r]);
            tq10[r] = bperm_f(g16c - 4 * dcc10[r], t1[r]);
            tq01[r] = bperm_f(g16c - 4 * dcc01[r], t0[r]);
            tq11[r] = bperm_f(g16c - 4 * dcc11[r], t1[r]);
        }
        ml = fmaxf(ml, ml2);
        mh = fmaxf(mh, mh2);
        // per-row defer-max
        if (ml > m_lo + THRr) {
            float f = fexp2(m_lo - ml); m_lo = ml; pw_lo = fexp2(m_lo);
            z_lo *= f; o00 *= f; o10 *= f;
        }
        if (mh > m_hi + THRr) {
            float f = fexp2(m_hi - mh); m_hi = mh; pw_hi = fexp2(m_hi);
            z_hi *= f; o01 *= f; o11 *= f;
        }
        // VALU phase: biased s, exp2, z
        float p00[4], p01[4], p10[4], p11[4];
#pragma unroll
        for (int r = 0; r < 4; ++r) {
            p00[r] = fexp2(s00[r] + tk00[r] + tq00[r] - m_lo);
            p10[r] = fexp2(s10[r] + tk10[r] + tq10[r] - m_lo);
            p01[r] = fexp2(s01[r] + tk01[r] + tq01[r] - m_hi);
            p11[r] = fexp2(s11[r] + tk11[r] + tq11[r] - m_hi);
        }
#pragma unroll
        for (int r = 0; r < 4; ++r) {
            z_lo += p00[r] + p10[r];
            z_hi += p01[r] + p11[r];
        }
        // pack P words
        int pl01 = __builtin_bit_cast(int, __builtin_amdgcn_cvt_pkrtz(p00[0], p00[1]));
        int pl23 = __builtin_bit_cast(int, __builtin_amdgcn_cvt_pkrtz(p00[2], p00[3]));
        int ph01 = __builtin_bit_cast(int, __builtin_amdgcn_cvt_pkrtz(p10[0], p10[1]));
        int ph23 = __builtin_bit_cast(int, __builtin_amdgcn_cvt_pkrtz(p10[2], p10[3]));
        int ql01 = __builtin_bit_cast(int, __builtin_amdgcn_cvt_pkrtz(p01[0], p01[1]));
        int ql23 = __builtin_bit_cast(int, __builtin_amdgcn_cvt_pkrtz(p01[2], p01[3]));
        int qh01 = __builtin_bit_cast(int, __builtin_amdgcn_cvt_pkrtz(p11[0], p11[1]));
        int qh23 = __builtin_bit_cast(int, __builtin_amdgcn_cvt_pkrtz(p11[2], p11[3]));
        // P-exchange bpermutes (batched)
        int rA0 = __builtin_amdgcn_ds_bpermute(paA, pl01);
        int rA1 = __builtin_amdgcn_ds_bpermute(paA, pl23);
        int rA2 = __builtin_amdgcn_ds_bpermute(paA, ph01);
        int rA3 = __builtin_amdgcn_ds_bpermute(paA, ph23);
        int rB0 = __builtin_amdgcn_ds_bpermute(paB, pl01);
        int rB1 = __builtin_amdgcn_ds_bpermute(paB, pl23);
        int rB2 = __builtin_amdgcn_ds_bpermute(paB, ph01);
        int rB3 = __builtin_amdgcn_ds_bpermute(paB, ph23);
        int uA0 = __builtin_amdgcn_ds_bpermute(paA, ql01);
        int uA1 = __builtin_amdgcn_ds_bpermute(paA, ql23);
        int uA2 = __builtin_amdgcn_ds_bpermute(paA, qh01);
        int uA3 = __builtin_amdgcn_ds_bpermute(paA, qh23);
        int uB0 = __builtin_amdgcn_ds_bpermute(paB, ql01);
        int uB1 = __builtin_amdgcn_ds_bpermute(paB, ql23);
        int uB2 = __builtin_amdgcn_ds_bpermute(paB, qh01);
        int uB3 = __builtin_amdgcn_ds_bpermute(paB, qh23);
        // atomics LAST (fire-and-forget)
        {
            float* aL = sA + li * ASTR;
            float* aH = sA + (16 + li) * ASTR;
#pragma unroll
            for (int r = 0; r < 4; ++r) {
                unsafeAtomicAdd(aL + drb + dcc00[r], p00[r] * pw_lo);
                unsafeAtomicAdd(aL + drb + dcc10[r], p10[r] * pw_lo);
                unsafeAtomicAdd(aH + drb + dcc01[r], p01[r] * pw_hi);
                unsafeAtomicAdd(aH + drb + dcc11[r], p11[r] * pw_hi);
            }
        }
        // build fragments + PV
        union { half8 v8; int w4[4]; } pAlo, pAhi;
        pAlo.w4[0] = glow ? rA0 : rA2;
        pAlo.w4[1] = glow ? rA1 : rA3;
        pAlo.w4[2] = glow ? rB0 : rB2;
        pAlo.w4[3] = glow ? rB1 : rB3;
        pAhi.w4[0] = glow ? uA0 : uA2;
        pAhi.w4[1] = glow ? uA1 : uA3;
        pAhi.w4[2] = glow ? uB0 : uB2;
        pAhi.w4[3] = glow ? uB1 : uB3;
        o00 = __builtin_amdgcn_mfma_f32_16x16x32_f16(aV0u.v8, pAlo.v8, o00, 0, 0, 0);
        o01 = __builtin_amdgcn_mfma_f32_16x16x32_f16(aV0u.v8, pAhi.v8, o01, 0, 0, 0);
        o10 = __builtin_amdgcn_mfma_f32_16x16x32_f16(aV1u.v8, pAlo.v8, o10, 0, 0, 0);
        o11 = __builtin_amdgcn_mfma_f32_16x16x32_f16(aV1u.v8, pAhi.v8, o11, 0, 0, 0);
    }

    // -------- epilogue --------
    z_lo += __shfl_xor(z_lo, 16); z_lo += __shfl_xor(z_lo, 32);
    z_hi += __shfl_xor(z_hi, 16); z_hi += __shfl_xor(z_hi, 32);
    if (g == 0) {
        sM4[w * 64 + li] = m_lo;  sM4[w * 64 + 32 + li] = m_hi;
        sZ4[w * 64 + li] = z_lo;  sZ4[w * 64 + 32 + li] = z_hi;
    }
    __syncthreads();   // E1
    if (w > 0) {
        float* ob = sO + (w - 1) * 1152;
#pragma unroll
        for (int r = 0; r < 4; ++r) {
            ob[li * 36 + 4 * g + r]             = o00[r];
            ob[li * 36 + 16 + 4 * g + r]        = o10[r];
            ob[(16 + li) * 36 + 4 * g + r]      = o01[r];
            ob[(16 + li) * 36 + 16 + 4 * g + r] = o11[r];
        }
    }
    for (int idx = tid; idx < 1024; idx += 256) {
        int row = idx >> 2, d0 = (idx & 3) * 8;
        half8 val;
        if (row < Ll) {
            const float4v* src = (const float4v*)(rpev + ((size_t)h * Ll + row) * HDd + d0);
            val = pack8(src[0], src[1]);
        } else {
            float4v z4 = {0.f, 0.f, 0.f, 0.f};
            val = pack8(z4, z4);
        }
        *(half8*)(sRQ + row * 40 + d0) = val;
    }
    __syncthreads();   // E2
    if (w == 0) {
        float fL0, fL1, fL2, fL3, rzL, rzAL;
        {
            float m0 = sM4[li], m1 = sM4[64 + li], m2 = sM4[128 + li], m3 = sM4[192 + li];
            float ms = fmaxf(fmaxf(m0, m1), fmaxf(m2, m3));
            fL0 = fexp2(m0 - ms); fL1 = fexp2(m1 - ms); fL2 = fexp2(m2 - ms); fL3 = fexp2(m3 - ms);
            float zt = sZ4[li] * fL0 + sZ4[64 + li] * fL1 + sZ4[128 + li] * fL2 + sZ4[192 + li] * fL3;
            rzL = 1.0f / zt;
            rzAL = fexp2(-ms) * rzL;
        }
        float fH0, fH1, fH2, fH3, rzH, rzAH;
        {
            int ih = 32 + li;
            float m0 = sM4[ih], m1 = sM4[64 + ih], m2 = sM4[128 + ih], m3 = sM4[192 + ih];
            float ms = fmaxf(fmaxf(m0, m1), fmaxf(m2, m3));
            fH0 = fexp2(m0 - ms); fH1 = fexp2(m1 - ms); fH2 = fexp2(m2 - ms); fH3 = fexp2(m3 - ms);
            float zt = sZ4[ih] * fH0 + sZ4[64 + ih] * fH1 + sZ4[128 + ih] * fH2 + sZ4[192 + ih] * fH3;
            rzH = 1.0f / zt;
            rzAH = fexp2(-ms) * rzH;
        }
#pragma unroll
        for (int r = 0; r < 4; ++r) {
            int dlo = 4 * g + r, dhi = 16 + 4 * g + r;
            o00[r] = (o00[r] * fL0 + sO[li * 36 + dlo] * fL1
                      + sO[1152 + li * 36 + dlo] * fL2 + sO[2304 + li * 36 + dlo] * fL3) * rzL;
            o10[r] = (o10[r] * fL0 + sO[li * 36 + dhi] * fL1
                      + sO[1152 + li * 36 + dhi] * fL2 + sO[2304 + li * 36 + dhi] * fL3) * rzL;
            o01[r] = (o01[r] * fH0 + sO[(16 + li) * 36 + dlo] * fH1
                      + sO[1152 + (16 + li) * 36 + dlo] * fH2 + sO[2304 + (16 + li) * 36 + dlo] * fH3) * rzH;
            o11[r] = (o11[r] * fH0 + sO[(16 + li) * 36 + dhi] * fH1
                      + sO[1152 + (16 + li) * 36 + dhi] * fH2 + sO[2304 + (16 + li) * 36 + dhi] * fH3) * rzH;
        }
#pragma unroll
        for (int ks = 0; ks < 8; ++ks) {
            const int kbase = ks * 32 + 8 * g;
            float4v aL0 = *(const float4v*)(sA + li * ASTR + kbase);
            float4v aL1 = *(const float4v*)(sA + li * ASTR + kbase + 4);
            float4v aH0 = *(const float4v*)(sA + (16 + li) * ASTR + kbase);
            float4v aH1 = *(const float4v*)(sA + (16 + li) * ASTR + kbase + 4);
            union { half8 v8; half2t hh[4]; } fAL, fAH;
            fAL.hh[0] = __builtin_amdgcn_cvt_pkrtz(aL0[0] * rzAL, aL0[1] * rzAL);
            fAL.hh[1] = __builtin_amdgcn_cvt_pkrtz(aL0[2] * rzAL, aL0[3] * rzAL);
            fAL.hh[2] = __builtin_amdgcn_cvt_pkrtz(aL1[0] * rzAL, aL1[1] * rzAL);
            fAL.hh[3] = __builtin_amdgcn_cvt_pkrtz(aL1[2] * rzAL, aL1[3] * rzAL);
            fAH.hh[0] = __builtin_amdgcn_cvt_pkrtz(aH0[0] * rzAH, aH0[1] * rzAH);
            fAH.hh[1] = __builtin_amdgcn_cvt_pkrtz(aH0[2] * rzAH, aH0[3] * rzAH);
            fAH.hh[2] = __builtin_amdgcn_cvt_pkrtz(aH1[0] * rzAH, aH1[1] * rzAH);
            fAH.hh[3] = __builtin_amdgcn_cvt_pkrtz(aH1[2] * rzAH, aH1[3] * rzAH);
            union { half8 v8; f16 e[8]; } BL, BH;
#pragma unroll
            for (int e = 0; e < 8; ++e) {
                BL.e[e] = sRQ[(kbase + e) * 40 + li];
                BH.e[e] = sRQ[(kbase + e) * 40 + 16 + li];
            }
            o00 = __builtin_amdgcn_mfma_f32_16x16x32_f16(BL.v8, fAL.v8, o00, 0, 0, 0);
            o01 = __builtin_amdgcn_mfma_f32_16x16x32_f16(BL.v8, fAH.v8, o01, 0, 0, 0);
            o10 = __builtin_amdgcn_mfma_f32_16x16x32_f16(BH.v8, fAL.v8, o10, 0, 0, 0);
            o11 = __builtin_amdgcn_mfma_f32_16x16x32_f16(BH.v8, fAH.v8, o11, 0, 0, 0);
        }
        float* cb = ctx + (size_t)bh * 32 * 1024 + i0;
#pragma unroll
        for (int r = 0; r < 4; ++r) {
            cb[(size_t)(4 * g + r) * 1024 + li]           = o00[r];
            cb[(size_t)(4 * g + r) * 1024 + 16 + li]      = o01[r];
            cb[(size_t)(16 + 4 * g + r) * 1024 + li]      = o10[r];
            cb[(size_t)(16 + 4 * g + r) * 1024 + 16 + li] = o11[r];
        }
    }
}

// ---------------- K3: partial mean over tokens ----------------
__global__ __launch_bounds__(256) void reduce_partial(const float* __restrict__ ctx,
                                                      const float* __restrict__ x,
                                                      float* __restrict__ pcm,
                                                      float* __restrict__ pxm) {
    int b = blockIdx.x >> 4, s = blockIdx.x & 15;
    int c = threadIdx.x;
    const float* crow = ctx + ((size_t)(b * 8 + (c >> 5)) * 32 + (c & 31)) * 1024 + s * 64;
    float sc = 0.f, sx = 0.f;
    for (int n = 0; n < 64; ++n) {
        sc += crow[n];
        sx += x[((size_t)b * Nn + s * 64 + n) * Cc + c];
    }
    pcm[(size_t)blockIdx.x * 256 + c] = sc;
    pxm[(size_t)blockIdx.x * 256 + c] = sx;
}

// ---------------- K4: final proj(mean) + residual-mean + fc ----------------
__global__ __launch_bounds__(256) void final_kernel(const float* __restrict__ pcm,
                                                    const float* __restrict__ pxm,
                                                    const float* __restrict__ pw,
                                                    const float* __restrict__ pb,
                                                    const float* __restrict__ fcw,
                                                    const float* __restrict__ fcb,
                                                    float* __restrict__ out) {
    __shared__ float cm[256], xm[256], mrow[256];
    int b = blockIdx.x;
    int c = threadIdx.x;
    float sc = 0.f, sx = 0.f;
    for (int s2 = 0; s2 < 16; ++s2) {
        sc += pcm[((size_t)b * 16 + s2) * 256 + c];
        sx += pxm[((size_t)b * 16 + s2) * 256 + c];
    }
    cm[c] = sc * (1.f / 1024.f);
    xm[c] = sx * (1.f / 1024.f);
    __syncthreads();
    float acc = pb[c] + xm[c];
    for (int c2 = 0; c2 < 256; ++c2) acc = fmaf(cm[c2], pw[(size_t)c * 256 + c2], acc);
    mrow[c] = acc;
    __syncthreads();
    if (c < 15) {
        float a2 = fcb[c];
        for (int c2 = 0; c2 < 256; ++c2) a2 = fmaf(mrow[c2], fcw[(size_t)c * 256 + c2], a2);
        out[b * 15 + c] = a2;
    }
}

extern "C" void kernel_launch(void* const* d_in, const int* in_sizes, int n_in,
                              void* d_out, int out_size, void* d_ws, size_t ws_size,
                              hipStream_t stream) {
    const float* x     = (const float*)d_in[0];
    const float* qkv_w = (const float*)d_in[1];
    const float* pw    = (const float*)d_in[2];
    const float* pb    = (const float*)d_in[3];
    const float* fcw   = (const float*)d_in[4];
    const float* fcb   = (const float*)d_in[5];
    const float* rpek  = (const float*)d_in[6];
    const float* rpeq  = (const float*)d_in[7];
    const float* rpev  = (const float*)d_in[8];
    float* out = (float*)d_out;

    const size_t QW = (size_t)Bq * Hh * Nn * HDd;  // 2,097,152
    f16* q16 = (f16*)d_ws;
    f16* k16 = q16 + QW;
    f16* v16 = k16 + QW;
    float* ctx = (float*)(v16 + QW);
    float* pcm = ctx + QW;
    float* pxm = pcm + 32768;

    hipFuncSetAttribute((const void*)attn_mfma,
                        hipFuncAttributeMaxDynamicSharedMemorySize, SMEM_BYTES);

    qkv_gemm<<<dim3(12, 128), 256, 0, stream>>>(x, qkv_w, q16, k16, v16);
    attn_mfma<<<2048, 256, SMEM_BYTES, stream>>>(q16, k16, v16, rpek, rpeq, rpev, ctx);
    reduce_partial<<<128, 256, 0, stream>>>(ctx, x, pcm, pxm);
    final_kernel<<<8, 256, 0, stream>>>(pcm, pxm, pw, pb, fcw, fcb, out);
}